// Round 1
// baseline (9627.652 us; speedup 1.0000x reference)
//
#include <hip/hip_runtime.h>

#define N_NODES 100000
#define N_EDGES 800000
#define DIM 128
#define OUTD 40
#define BN_EPS 1e-5f

// ---------------- CSR build ----------------

__global__ void deg_kernel(const int* __restrict__ dst, int* __restrict__ deg) {
    int e = blockIdx.x * blockDim.x + threadIdx.x;
    if (e < N_EDGES) atomicAdd(&deg[dst[e]], 1);
}

__global__ __launch_bounds__(1024) void scan_kernel(const int* __restrict__ deg,
                                                    int* __restrict__ row_off) {
    __shared__ int sums[1024];
    const int T = 1024;
    const int chunk = (N_NODES + T - 1) / T;  // 98
    int t = threadIdx.x;
    int lo = t * chunk;
    int hi = lo + chunk; if (hi > N_NODES) hi = N_NODES;
    int s = 0;
    for (int i = lo; i < hi; ++i) s += deg[i];
    sums[t] = s;
    __syncthreads();
    // Hillis-Steele inclusive scan
    for (int off = 1; off < T; off <<= 1) {
        int v = (t >= off) ? sums[t - off] : 0;
        __syncthreads();
        sums[t] += v;
        __syncthreads();
    }
    int run = (t == 0) ? 0 : sums[t - 1];
    for (int i = lo; i < hi; ++i) { row_off[i] = run; run += deg[i]; }
    if (t == T - 1) row_off[N_NODES] = run;  // == E
}

__global__ void fill_kernel(const int* __restrict__ src, const int* __restrict__ dst,
                            const int* __restrict__ row_off, int* __restrict__ cursor,
                            int* __restrict__ csr_src) {
    int e = blockIdx.x * blockDim.x + threadIdx.x;
    if (e < N_EDGES) {
        int d = dst[e];
        int p = atomicAdd(&cursor[d], 1);
        csr_src[row_off[d] + p] = src[e];
    }
}

// ---------------- mean aggregation (CSR gather) ----------------
// one wave per node; lane handles 2 consecutive floats (512B/neighbor coalesced)

__global__ __launch_bounds__(256) void agg_kernel(const float* __restrict__ h,
                                                  const int* __restrict__ row_off,
                                                  const int* __restrict__ csr_src,
                                                  float* __restrict__ hn) {
    int wave = threadIdx.x >> 6;
    int lane = threadIdx.x & 63;
    int node = blockIdx.x * 4 + wave;
    if (node >= N_NODES) return;
    int lo = row_off[node], hi = row_off[node + 1];
    float ax = 0.f, ay = 0.f;
    for (int i = lo; i < hi; ++i) {
        int s = csr_src[i];
        float2 v = *reinterpret_cast<const float2*>(&h[(size_t)s * DIM + lane * 2]);
        ax += v.x; ay += v.y;
    }
    float rd = (hi > lo) ? 1.0f / (float)(hi - lo) : 1.0f;  // /max(deg,1)
    float2 o = make_float2(ax * rd, ay * rd);
    *reinterpret_cast<float2*>(&hn[(size_t)node * DIM + lane * 2]) = o;
}

// ---------------- GEMM: C[N][128] = A@Ws + Bn@Wn (K=128 each) ----------------
// 64 rows x 128 cols per block, 256 threads, 8x4 per thread, BK=32

__global__ __launch_bounds__(256) void gemm128_kernel(const float* __restrict__ A,
                                                      const float* __restrict__ Bn,
                                                      const float* __restrict__ Ws,
                                                      const float* __restrict__ Wn,
                                                      float* __restrict__ C) {
    __shared__ float At[64][32];
    __shared__ float Wt[32][128];
    const int tid = threadIdx.x;
    const int row0 = blockIdx.x * 64;
    const int tr = tid >> 5;   // 0..7
    const int tc = tid & 31;   // 0..31

    float acc[8][4];
#pragma unroll
    for (int i = 0; i < 8; ++i)
#pragma unroll
        for (int j = 0; j < 4; ++j) acc[i][j] = 0.f;

#pragma unroll
    for (int kc = 0; kc < 8; ++kc) {
        const int k0 = kc * 32;
        const float* __restrict__ S = (k0 < 128) ? A : Bn;
        const float* __restrict__ W = (k0 < 128) ? Ws : Wn;
        const int kk0 = k0 & 127;
        if (kc) __syncthreads();
        // stage A-tile: 64x32
#pragma unroll
        for (int i = 0; i < 2; ++i) {
            int idx = tid * 2 + i;      // 0..511
            int r = idx >> 3, j = idx & 7;
            int grow = row0 + r; if (grow >= N_NODES) grow = N_NODES - 1;
            float4 v = *reinterpret_cast<const float4*>(&S[(size_t)grow * DIM + kk0 + j * 4]);
            *reinterpret_cast<float4*>(&At[r][j * 4]) = v;
        }
        // stage W-tile: 32x128
#pragma unroll
        for (int i = 0; i < 4; ++i) {
            int idx = i * 256 + tid;    // 0..1023
            int wr = idx >> 5, wj = idx & 31;
            float4 v = *reinterpret_cast<const float4*>(&W[(size_t)(kk0 + wr) * DIM + wj * 4]);
            *reinterpret_cast<float4*>(&Wt[wr][wj * 4]) = v;
        }
        __syncthreads();
#pragma unroll
        for (int kk = 0; kk < 32; kk += 4) {
            float a4[8][4];
#pragma unroll
            for (int i = 0; i < 8; ++i) {
                float4 t = *reinterpret_cast<const float4*>(&At[tr * 8 + i][kk]);
                a4[i][0] = t.x; a4[i][1] = t.y; a4[i][2] = t.z; a4[i][3] = t.w;
            }
#pragma unroll
            for (int q = 0; q < 4; ++q) {
                float4 wv = *reinterpret_cast<const float4*>(&Wt[kk + q][tc * 4]);
#pragma unroll
                for (int i = 0; i < 8; ++i) {
                    acc[i][0] += a4[i][q] * wv.x;
                    acc[i][1] += a4[i][q] * wv.y;
                    acc[i][2] += a4[i][q] * wv.z;
                    acc[i][3] += a4[i][q] * wv.w;
                }
            }
        }
    }
#pragma unroll
    for (int i = 0; i < 8; ++i) {
        int row = row0 + tr * 8 + i;
        if (row < N_NODES) {
            float4 v = make_float4(acc[i][0], acc[i][1], acc[i][2], acc[i][3]);
            *reinterpret_cast<float4*>(&C[(size_t)row * DIM + tc * 4]) = v;
        }
    }
}

// ---------------- BatchNorm stats (sum, sumsq per column) ----------------

__global__ __launch_bounds__(256) void bn_stats_kernel(const float* __restrict__ H,
                                                       float* __restrict__ bnsum,
                                                       float* __restrict__ bnsq) {
    int c = threadIdx.x & 127;
    int half = threadIdx.x >> 7;  // 0..1
    float s = 0.f, q = 0.f;
    for (int r = blockIdx.x * 2 + half; r < N_NODES; r += gridDim.x * 2) {
        float v = H[(size_t)r * DIM + c];
        s += v; q += v * v;
    }
    __shared__ float ls[256], lq[256];
    ls[threadIdx.x] = s; lq[threadIdx.x] = q;
    __syncthreads();
    if (half == 0) {
        s = ls[threadIdx.x] + ls[threadIdx.x + 128];
        q = lq[threadIdx.x] + lq[threadIdx.x + 128];
        atomicAdd(&bnsum[c], s);
        atomicAdd(&bnsq[c], q);
    }
}

// ---------------- BatchNorm apply + ReLU (in place) ----------------

__global__ __launch_bounds__(256) void bn_apply_kernel(float* __restrict__ H,
                                                       const float* __restrict__ bnsum,
                                                       const float* __restrict__ bnsq,
                                                       const float* __restrict__ gamma,
                                                       const float* __restrict__ beta) {
    size_t idx = (size_t)(blockIdx.x * blockDim.x + threadIdx.x) * 4;
    const float invN = 1.0f / (float)N_NODES;
    int c = (int)(idx & (DIM - 1));
    float4 v = *reinterpret_cast<const float4*>(&H[idx]);
    float o[4] = {v.x, v.y, v.z, v.w};
#pragma unroll
    for (int j = 0; j < 4; ++j) {
        int cj = c + j;
        float mean = bnsum[cj] * invN;
        float var = bnsq[cj] * invN - mean * mean;
        float scale = gamma[cj] * rsqrtf(var + BN_EPS);
        float val = (o[j] - mean) * scale + beta[cj];
        o[j] = val > 0.f ? val : 0.f;
    }
    *reinterpret_cast<float4*>(&H[idx]) = make_float4(o[0], o[1], o[2], o[3]);
}

// ---------------- output layer GEMM: C[N][40] = A@Ws + Bn@Wn + b ----------------

__global__ __launch_bounds__(256) void gemm_out_kernel(const float* __restrict__ A,
                                                       const float* __restrict__ Bn,
                                                       const float* __restrict__ Ws,
                                                       const float* __restrict__ Wn,
                                                       const float* __restrict__ bias,
                                                       float* __restrict__ C) {
    __shared__ float Wls[DIM][OUTD];
    __shared__ float Wln[DIM][OUTD];
    for (int i = threadIdx.x; i < DIM * OUTD; i += 256) {
        ((float*)Wls)[i] = Ws[i];
        ((float*)Wln)[i] = Wn[i];
    }
    __syncthreads();
    int r = blockIdx.x * 256 + threadIdx.x;
    if (r >= N_NODES) return;
    float acc[OUTD];
#pragma unroll
    for (int c = 0; c < OUTD; ++c) acc[c] = bias[c];
    const float* __restrict__ ar = &A[(size_t)r * DIM];
    const float* __restrict__ br = &Bn[(size_t)r * DIM];
    for (int k4 = 0; k4 < DIM / 4; ++k4) {
        float4 av = *reinterpret_cast<const float4*>(&ar[k4 * 4]);
        float4 bv = *reinterpret_cast<const float4*>(&br[k4 * 4]);
        float a_[4] = {av.x, av.y, av.z, av.w};
        float b_[4] = {bv.x, bv.y, bv.z, bv.w};
#pragma unroll
        for (int q = 0; q < 4; ++q) {
            int k = k4 * 4 + q;
#pragma unroll
            for (int c4 = 0; c4 < OUTD / 4; ++c4) {
                float4 ws = *reinterpret_cast<const float4*>(&Wls[k][c4 * 4]);
                float4 wn = *reinterpret_cast<const float4*>(&Wln[k][c4 * 4]);
                acc[c4 * 4 + 0] += a_[q] * ws.x + b_[q] * wn.x;
                acc[c4 * 4 + 1] += a_[q] * ws.y + b_[q] * wn.y;
                acc[c4 * 4 + 2] += a_[q] * ws.z + b_[q] * wn.z;
                acc[c4 * 4 + 3] += a_[q] * ws.w + b_[q] * wn.w;
            }
        }
    }
#pragma unroll
    for (int c4 = 0; c4 < OUTD / 4; ++c4) {
        float4 v = make_float4(acc[c4 * 4], acc[c4 * 4 + 1], acc[c4 * 4 + 2], acc[c4 * 4 + 3]);
        *reinterpret_cast<float4*>(&C[(size_t)r * OUTD + c4 * 4]) = v;
    }
}

// ---------------- launch ----------------

extern "C" void kernel_launch(void* const* d_in, const int* in_sizes, int n_in,
                              void* d_out, int out_size, void* d_ws, size_t ws_size,
                              hipStream_t stream) {
    const float* feat = (const float*)d_in[0];
    const int* src = (const int*)d_in[1];
    const int* dst = (const int*)d_in[2];
    const float* Ws0 = (const float*)d_in[3];
    const float* Wn0 = (const float*)d_in[4];
    const float* g0  = (const float*)d_in[5];
    const float* be0 = (const float*)d_in[6];
    const float* Ws1 = (const float*)d_in[7];
    const float* Wn1 = (const float*)d_in[8];
    const float* g1  = (const float*)d_in[9];
    const float* be1 = (const float*)d_in[10];
    const float* Ws2 = (const float*)d_in[11];
    const float* Wn2 = (const float*)d_in[12];
    const float* b2  = (const float*)d_in[13];
    float* out = (float*)d_out;

    char* ws = (char*)d_ws;
    // zeroed region: deg | cursor | bn stats
    int*   deg     = (int*)(ws);                       // 400000 B
    int*   cursor  = (int*)(ws + 400000);              // 400000 B
    float* bn      = (float*)(ws + 800000);            // 4*128*4 = 2048 B
    int*   row_off = (int*)(ws + 802048);              // 400004 B
    int*   csr     = (int*)(ws + 1202176);             // 3200000 B
    float* hn      = (float*)(ws + 4402176);           // 51200000 B
    float* h0      = (float*)(ws + 55602176);          // 51200000 B
    float* h1      = (float*)(ws + 106802176);         // 51200000 B (ends 158002176)

    hipMemsetAsync(ws, 0, 802048, stream);

    const int EB = (N_EDGES + 255) / 256;      // 3125
    const int AB = (N_NODES + 3) / 4;          // 25000
    const int GB = (N_NODES + 63) / 64;        // 1563
    const int OB = (N_NODES + 255) / 256;      // 391
    const int NE = (N_NODES * DIM) / 4 / 256;  // 12500

    deg_kernel<<<EB, 256, 0, stream>>>(dst, deg);
    scan_kernel<<<1, 1024, 0, stream>>>(deg, row_off);
    fill_kernel<<<EB, 256, 0, stream>>>(src, dst, row_off, cursor, csr);

    // layer 0
    agg_kernel<<<AB, 256, 0, stream>>>(feat, row_off, csr, hn);
    gemm128_kernel<<<GB, 256, 0, stream>>>(feat, hn, Ws0, Wn0, h0);
    bn_stats_kernel<<<1024, 256, 0, stream>>>(h0, bn + 0, bn + 128);
    bn_apply_kernel<<<NE, 256, 0, stream>>>(h0, bn + 0, bn + 128, g0, be0);

    // layer 1
    agg_kernel<<<AB, 256, 0, stream>>>(h0, row_off, csr, hn);
    gemm128_kernel<<<GB, 256, 0, stream>>>(h0, hn, Ws1, Wn1, h1);
    bn_stats_kernel<<<1024, 256, 0, stream>>>(h1, bn + 256, bn + 384);
    bn_apply_kernel<<<NE, 256, 0, stream>>>(h1, bn + 256, bn + 384, g1, be1);

    // layer 2
    agg_kernel<<<AB, 256, 0, stream>>>(h1, row_off, csr, hn);
    gemm_out_kernel<<<OB, 256, 0, stream>>>(h1, hn, Ws2, Wn2, b2, out);
}

// Round 2
// 713.049 us; speedup vs baseline: 13.5021x; 13.5021x over previous
//
#include <hip/hip_runtime.h>

#define N_NODES 100000
#define N_EDGES 800000
#define DIM 128
#define OUTD 40
#define BN_EPS 1e-5f

typedef __bf16 bf16x8_t __attribute__((ext_vector_type(8)));
typedef float f32x4_t __attribute__((ext_vector_type(4)));

__device__ __forceinline__ unsigned short f2bf(float f) {
    unsigned int u = __builtin_bit_cast(unsigned int, f);
    u = (u + 0x7FFF + ((u >> 16) & 1)) >> 16;
    return (unsigned short)u;
}
__device__ __forceinline__ float bf2f(unsigned short b) {
    return __builtin_bit_cast(float, (unsigned int)b << 16);
}

// ---------------- CSR build ----------------

__global__ void deg_kernel(const int* __restrict__ dst, int* __restrict__ deg) {
    int e = blockIdx.x * blockDim.x + threadIdx.x;
    if (e < N_EDGES) atomicAdd(&deg[dst[e]], 1);
}

__global__ __launch_bounds__(1024) void scan_kernel(const int* __restrict__ deg,
                                                    int* __restrict__ row_off) {
    __shared__ int sums[1024];
    const int T = 1024;
    const int chunk = (N_NODES + T - 1) / T;
    int t = threadIdx.x;
    int lo = t * chunk;
    int hi = lo + chunk; if (hi > N_NODES) hi = N_NODES;
    int s = 0;
    for (int i = lo; i < hi; ++i) s += deg[i];
    sums[t] = s;
    __syncthreads();
    for (int off = 1; off < T; off <<= 1) {
        int v = (t >= off) ? sums[t - off] : 0;
        __syncthreads();
        sums[t] += v;
        __syncthreads();
    }
    int run = (t == 0) ? 0 : sums[t - 1];
    for (int i = lo; i < hi; ++i) { row_off[i] = run; run += deg[i]; }
    if (t == T - 1) row_off[N_NODES] = run;
}

__global__ void fill_kernel(const int* __restrict__ src, const int* __restrict__ dst,
                            const int* __restrict__ row_off, int* __restrict__ cursor,
                            int* __restrict__ csr_src) {
    int e = blockIdx.x * blockDim.x + threadIdx.x;
    if (e < N_EDGES) {
        int d = dst[e];
        int p = atomicAdd(&cursor[d], 1);
        csr_src[row_off[d] + p] = src[e];
    }
}

// ---------------- fp32 -> bf16 convert (feat) ----------------

__global__ __launch_bounds__(256) void convert_bf16_kernel(const float* __restrict__ in,
                                                           unsigned short* __restrict__ out) {
    size_t i = (size_t)(blockIdx.x * blockDim.x + threadIdx.x) * 4;
    float4 v = *reinterpret_cast<const float4*>(&in[i]);
    ushort4 o;
    o.x = f2bf(v.x); o.y = f2bf(v.y); o.z = f2bf(v.z); o.w = f2bf(v.w);
    *reinterpret_cast<ushort4*>(&out[i]) = o;
}

// ---------------- weight transpose+convert: WT[n][k] = W[k][n], bf16 ----------------
// WT is [128][256]: k<128 from W_self, k>=128 from W_neigh

__global__ __launch_bounds__(256) void wt_build_kernel(const float* __restrict__ Ws0,
                                                       const float* __restrict__ Wn0,
                                                       const float* __restrict__ Ws1,
                                                       const float* __restrict__ Wn1,
                                                       unsigned short* __restrict__ WT0,
                                                       unsigned short* __restrict__ WT1) {
    int e = blockIdx.x * blockDim.x + threadIdx.x;  // 0..65535
    int layer = e >> 15;
    int r = e & 32767;
    int n = r >> 8;
    int k = r & 255;
    const float* Ws = layer ? Ws1 : Ws0;
    const float* Wn = layer ? Wn1 : Wn0;
    float v = (k < DIM) ? Ws[k * DIM + n] : Wn[(k - DIM) * DIM + n];
    unsigned short* WT = layer ? WT1 : WT0;
    WT[n * 256 + k] = f2bf(v);
}

// ---------------- mean aggregation (CSR gather), bf16 in/out ----------------

__global__ __launch_bounds__(256) void agg_bf16_kernel(const unsigned short* __restrict__ h,
                                                       const int* __restrict__ row_off,
                                                       const int* __restrict__ csr_src,
                                                       unsigned short* __restrict__ hn) {
    int wave = threadIdx.x >> 6;
    int lane = threadIdx.x & 63;
    int node = blockIdx.x * 4 + wave;
    if (node >= N_NODES) return;
    int lo = row_off[node], hi = row_off[node + 1];
    float ax = 0.f, ay = 0.f;
    for (int i = lo; i < hi; ++i) {
        int s = csr_src[i];
        unsigned int v = *reinterpret_cast<const unsigned int*>(&h[(size_t)s * DIM + lane * 2]);
        ax += __builtin_bit_cast(float, v << 16);
        ay += __builtin_bit_cast(float, v & 0xFFFF0000u);
    }
    float rd = (hi > lo) ? 1.0f / (float)(hi - lo) : 1.0f;
    unsigned int o = (unsigned int)f2bf(ax * rd) | ((unsigned int)f2bf(ay * rd) << 16);
    *reinterpret_cast<unsigned int*>(&hn[(size_t)node * DIM + lane * 2]) = o;
}

// ---------------- MFMA GEMM: C[N][128] = [Ab|Hb] @ WT^T, fp32 out ----------------
// block: 128 rows x 128 cols, 4 waves (32 rows x 128 cols each), K=256

__global__ __launch_bounds__(256) void gemm_mfma_kernel(const unsigned short* __restrict__ Ab,
                                                        const unsigned short* __restrict__ Hb,
                                                        const unsigned short* __restrict__ WT,
                                                        float* __restrict__ C) {
    __shared__ unsigned short wt[32768];  // 64 KB, [n][k] bf16, XOR-swizzled
    const int tid = threadIdx.x;

    // stage whole weight panel: 4096 x 16B chunks
#pragma unroll
    for (int i = 0; i < 16; ++i) {
        int c = i * 256 + tid;
        int n = c >> 5;                       // row (output col) of this chunk
        unsigned int waddr = ((unsigned int)(c * 16)) ^ (((unsigned int)(n & 7)) << 4);
        uint4 v = *reinterpret_cast<const uint4*>(&WT[c * 8]);
        *reinterpret_cast<uint4*>(reinterpret_cast<char*>(wt) + waddr) = v;
    }
    __syncthreads();

    const int wid = tid >> 6;
    const int lane = tid & 63;
    const int lrow = lane & 15;
    const int g = lane >> 4;
    const int r0 = blockIdx.x * 128 + wid * 32;

    f32x4_t acc[2][8];
#pragma unroll
    for (int mt = 0; mt < 2; ++mt)
#pragma unroll
        for (int nt = 0; nt < 8; ++nt) acc[mt][nt] = (f32x4_t){0.f, 0.f, 0.f, 0.f};

#pragma unroll
    for (int ks = 0; ks < 8; ++ks) {
        const unsigned short* __restrict__ base = (ks < 4) ? Ab : Hb;
        const int kk = (ks & 3) * 32 + g * 8;
        bf16x8_t a[2];
#pragma unroll
        for (int mt = 0; mt < 2; ++mt) {
            int row = r0 + mt * 16 + lrow;
            if (row >= N_NODES) row = N_NODES - 1;
            a[mt] = *reinterpret_cast<const bf16x8_t*>(&base[(size_t)row * DIM + kk]);
        }
#pragma unroll
        for (int nt = 0; nt < 8; ++nt) {
            int n = nt * 16 + lrow;
            unsigned int raddr = ((unsigned int)(n * 512 + ks * 64 + g * 16)) ^ (((unsigned int)(n & 7)) << 4);
            bf16x8_t b = *reinterpret_cast<const bf16x8_t*>(reinterpret_cast<const char*>(wt) + raddr);
            acc[0][nt] = __builtin_amdgcn_mfma_f32_16x16x32_bf16(a[0], b, acc[0][nt], 0, 0, 0);
            acc[1][nt] = __builtin_amdgcn_mfma_f32_16x16x32_bf16(a[1], b, acc[1][nt], 0, 0, 0);
        }
    }

#pragma unroll
    for (int mt = 0; mt < 2; ++mt) {
#pragma unroll
        for (int j = 0; j < 4; ++j) {
            int row = r0 + mt * 16 + g * 4 + j;
            if (row < N_NODES) {
#pragma unroll
                for (int nt = 0; nt < 8; ++nt)
                    C[(size_t)row * DIM + nt * 16 + lrow] = acc[mt][nt][j];
            }
        }
    }
}

// ---------------- BatchNorm stats ----------------

__global__ __launch_bounds__(256) void bn_stats_kernel(const float* __restrict__ H,
                                                       float* __restrict__ bnsum,
                                                       float* __restrict__ bnsq) {
    int c = threadIdx.x & 127;
    int half = threadIdx.x >> 7;
    float s = 0.f, q = 0.f;
    for (int r = blockIdx.x * 2 + half; r < N_NODES; r += gridDim.x * 2) {
        float v = H[(size_t)r * DIM + c];
        s += v; q += v * v;
    }
    __shared__ float ls[256], lq[256];
    ls[threadIdx.x] = s; lq[threadIdx.x] = q;
    __syncthreads();
    if (half == 0) {
        s = ls[threadIdx.x] + ls[threadIdx.x + 128];
        q = lq[threadIdx.x] + lq[threadIdx.x + 128];
        atomicAdd(&bnsum[c], s);
        atomicAdd(&bnsq[c], q);
    }
}

// ---------------- BatchNorm apply + ReLU, fp32 in -> bf16 out ----------------

__global__ __launch_bounds__(256) void bn_apply_bf16_kernel(const float* __restrict__ H,
                                                            const float* __restrict__ bnsum,
                                                            const float* __restrict__ bnsq,
                                                            const float* __restrict__ gamma,
                                                            const float* __restrict__ beta,
                                                            unsigned short* __restrict__ Hb) {
    size_t idx = (size_t)(blockIdx.x * blockDim.x + threadIdx.x) * 4;
    const float invN = 1.0f / (float)N_NODES;
    int c = (int)(idx & (DIM - 1));
    float4 v = *reinterpret_cast<const float4*>(&H[idx]);
    float o[4] = {v.x, v.y, v.z, v.w};
    ushort4 ob;
#pragma unroll
    for (int j = 0; j < 4; ++j) {
        int cj = c + j;
        float mean = bnsum[cj] * invN;
        float var = bnsq[cj] * invN - mean * mean;
        float scale = gamma[cj] * rsqrtf(var + BN_EPS);
        float val = (o[j] - mean) * scale + beta[cj];
        o[j] = val > 0.f ? val : 0.f;
    }
    ob.x = f2bf(o[0]); ob.y = f2bf(o[1]); ob.z = f2bf(o[2]); ob.w = f2bf(o[3]);
    *reinterpret_cast<ushort4*>(&Hb[idx]) = ob;
}

// ---------------- output layer: C[N][40] = A@Ws + Bn@Wn + b (bf16 in, fp32 math) ----------------

__global__ __launch_bounds__(256) void gemm_out_kernel(const unsigned short* __restrict__ A,
                                                       const unsigned short* __restrict__ Bn,
                                                       const float* __restrict__ Ws,
                                                       const float* __restrict__ Wn,
                                                       const float* __restrict__ bias,
                                                       float* __restrict__ C) {
    __shared__ float Wls[DIM][OUTD];
    __shared__ float Wln[DIM][OUTD];
    for (int i = threadIdx.x; i < DIM * OUTD; i += 256) {
        ((float*)Wls)[i] = Ws[i];
        ((float*)Wln)[i] = Wn[i];
    }
    __syncthreads();
    int r = blockIdx.x * 256 + threadIdx.x;
    if (r >= N_NODES) return;
    float acc[OUTD];
#pragma unroll
    for (int c = 0; c < OUTD; ++c) acc[c] = bias[c];
    const unsigned short* __restrict__ ar = &A[(size_t)r * DIM];
    const unsigned short* __restrict__ br = &Bn[(size_t)r * DIM];
    for (int k8 = 0; k8 < DIM / 8; ++k8) {
        uint4 avu = *reinterpret_cast<const uint4*>(&ar[k8 * 8]);
        uint4 bvu = *reinterpret_cast<const uint4*>(&br[k8 * 8]);
        unsigned int aw[4] = {avu.x, avu.y, avu.z, avu.w};
        unsigned int bw[4] = {bvu.x, bvu.y, bvu.z, bvu.w};
        float a_[8], b_[8];
#pragma unroll
        for (int q = 0; q < 4; ++q) {
            a_[q * 2]     = __builtin_bit_cast(float, aw[q] << 16);
            a_[q * 2 + 1] = __builtin_bit_cast(float, aw[q] & 0xFFFF0000u);
            b_[q * 2]     = __builtin_bit_cast(float, bw[q] << 16);
            b_[q * 2 + 1] = __builtin_bit_cast(float, bw[q] & 0xFFFF0000u);
        }
#pragma unroll
        for (int q = 0; q < 8; ++q) {
            int k = k8 * 8 + q;
#pragma unroll
            for (int c4 = 0; c4 < OUTD / 4; ++c4) {
                float4 ws = *reinterpret_cast<const float4*>(&Wls[k][c4 * 4]);
                float4 wn = *reinterpret_cast<const float4*>(&Wln[k][c4 * 4]);
                acc[c4 * 4 + 0] += a_[q] * ws.x + b_[q] * wn.x;
                acc[c4 * 4 + 1] += a_[q] * ws.y + b_[q] * wn.y;
                acc[c4 * 4 + 2] += a_[q] * ws.z + b_[q] * wn.z;
                acc[c4 * 4 + 3] += a_[q] * ws.w + b_[q] * wn.w;
            }
        }
    }
#pragma unroll
    for (int c4 = 0; c4 < OUTD / 4; ++c4) {
        float4 v = make_float4(acc[c4 * 4], acc[c4 * 4 + 1], acc[c4 * 4 + 2], acc[c4 * 4 + 3]);
        *reinterpret_cast<float4*>(&C[(size_t)r * OUTD + c4 * 4]) = v;
    }
}

// ---------------- launch ----------------

extern "C" void kernel_launch(void* const* d_in, const int* in_sizes, int n_in,
                              void* d_out, int out_size, void* d_ws, size_t ws_size,
                              hipStream_t stream) {
    const float* feat = (const float*)d_in[0];
    const int* src = (const int*)d_in[1];
    const int* dst = (const int*)d_in[2];
    const float* Ws0 = (const float*)d_in[3];
    const float* Wn0 = (const float*)d_in[4];
    const float* g0  = (const float*)d_in[5];
    const float* be0 = (const float*)d_in[6];
    const float* Ws1 = (const float*)d_in[7];
    const float* Wn1 = (const float*)d_in[8];
    const float* g1  = (const float*)d_in[9];
    const float* be1 = (const float*)d_in[10];
    const float* Ws2 = (const float*)d_in[11];
    const float* Wn2 = (const float*)d_in[12];
    const float* b2  = (const float*)d_in[13];
    float* out = (float*)d_out;

    char* ws = (char*)d_ws;
    int*   deg     = (int*)(ws);                       // 400000 B (zeroed)
    int*   cursor  = (int*)(ws + 400000);              // 400000 B (zeroed)
    float* bn      = (float*)(ws + 800000);            // 2048 B   (zeroed)
    int*   row_off = (int*)(ws + 802048);              // 400004 B
    int*   csr     = (int*)(ws + 1202176);             // 3200000 B
    unsigned short* featb = (unsigned short*)(ws + 4402176);   // 25.6 MB (reused as h1b)
    unsigned short* hnb   = (unsigned short*)(ws + 30002176);  // 25.6 MB
    unsigned short* h0b   = (unsigned short*)(ws + 55602176);  // 25.6 MB
    float*          hf    = (float*)(ws + 81202176);           // 51.2 MB fp32 gemm out
    unsigned short* WT0   = (unsigned short*)(ws + 132402176); // 65536 B
    unsigned short* WT1   = (unsigned short*)(ws + 132467712); // 65536 B (ends 132533248)
    unsigned short* h1b   = featb;  // featb dead after layer-0 gemm

    hipMemsetAsync(ws, 0, 802048, stream);

    const int EB = (N_EDGES + 255) / 256;        // 3125
    const int AB = (N_NODES + 3) / 4;            // 25000
    const int MB = (N_NODES + 127) / 128;        // 782
    const int OB = (N_NODES + 255) / 256;        // 391
    const int NE = (N_NODES * DIM) / 4 / 256;    // 12500

    deg_kernel<<<EB, 256, 0, stream>>>(dst, deg);
    scan_kernel<<<1, 1024, 0, stream>>>(deg, row_off);
    fill_kernel<<<EB, 256, 0, stream>>>(src, dst, row_off, cursor, csr);

    convert_bf16_kernel<<<NE, 256, 0, stream>>>(feat, featb);
    wt_build_kernel<<<256, 256, 0, stream>>>(Ws0, Wn0, Ws1, Wn1, WT0, WT1);

    // layer 0
    agg_bf16_kernel<<<AB, 256, 0, stream>>>(featb, row_off, csr, hnb);
    gemm_mfma_kernel<<<MB, 256, 0, stream>>>(featb, hnb, WT0, hf);
    bn_stats_kernel<<<1024, 256, 0, stream>>>(hf, bn + 0, bn + 128);
    bn_apply_bf16_kernel<<<NE, 256, 0, stream>>>(hf, bn + 0, bn + 128, g0, be0, h0b);

    // layer 1
    agg_bf16_kernel<<<AB, 256, 0, stream>>>(h0b, row_off, csr, hnb);
    gemm_mfma_kernel<<<MB, 256, 0, stream>>>(h0b, hnb, WT1, hf);
    bn_stats_kernel<<<1024, 256, 0, stream>>>(hf, bn + 256, bn + 384);
    bn_apply_bf16_kernel<<<NE, 256, 0, stream>>>(hf, bn + 256, bn + 384, g1, be1, h1b);

    // layer 2
    agg_bf16_kernel<<<AB, 256, 0, stream>>>(h1b, row_off, csr, hnb);
    gemm_out_kernel<<<OB, 256, 0, stream>>>(h1b, hnb, Ws2, Wn2, b2, out);
}

// Round 3
// 561.977 us; speedup vs baseline: 17.1317x; 1.2688x over previous
//
#include <hip/hip_runtime.h>

#define N_NODES 100000
#define N_EDGES 800000
#define DIM 128
#define OUTD 40
#define BN_EPS 1e-5f
#define SCAN_NB 98  // ceil(100000/1024)

typedef __bf16 bf16x8_t __attribute__((ext_vector_type(8)));
typedef float f32x4_t __attribute__((ext_vector_type(4)));

__device__ __forceinline__ unsigned short f2bf(float f) {
    unsigned int u = __builtin_bit_cast(unsigned int, f);
    u = (u + 0x7FFF + ((u >> 16) & 1)) >> 16;
    return (unsigned short)u;
}

// ---------------- CSR build ----------------

__global__ void deg_kernel(const int* __restrict__ dst, int* __restrict__ deg) {
    int e = blockIdx.x * blockDim.x + threadIdx.x;
    if (e < N_EDGES) atomicAdd(&deg[dst[e]], 1);
}

// phase 1: per-block (1024 elems) partial sums
__global__ __launch_bounds__(256) void scan_partial_kernel(const int* __restrict__ deg,
                                                           int* __restrict__ partials) {
    int b = blockIdx.x;
    int tid = threadIdx.x;
    int base = b * 1024 + tid * 4;
    int t0 = 0, t1 = 0, t2 = 0, t3 = 0;
    if (base + 3 < N_NODES) {
        int4 v = *reinterpret_cast<const int4*>(&deg[base]);
        t0 = v.x; t1 = v.y; t2 = v.z; t3 = v.w;
    } else {
        if (base + 0 < N_NODES) t0 = deg[base + 0];
        if (base + 1 < N_NODES) t1 = deg[base + 1];
        if (base + 2 < N_NODES) t2 = deg[base + 2];
        if (base + 3 < N_NODES) t3 = deg[base + 3];
    }
    int s = t0 + t1 + t2 + t3;
    __shared__ int red[256];
    red[tid] = s;
    __syncthreads();
    for (int o = 128; o; o >>= 1) {
        if (tid < o) red[tid] += red[tid + o];
        __syncthreads();
    }
    if (tid == 0) partials[b] = red[0];
}

// phase 2: exclusive scan of the 98 partials (in place), one tiny block
__global__ __launch_bounds__(128) void scan_partials_kernel(int* __restrict__ partials) {
    __shared__ int s[128];
    int t = threadIdx.x;
    int v = (t < SCAN_NB) ? partials[t] : 0;
    s[t] = v;
    __syncthreads();
    for (int off = 1; off < 128; off <<= 1) {
        int u = (t >= off) ? s[t - off] : 0;
        __syncthreads();
        s[t] += u;
        __syncthreads();
    }
    if (t < SCAN_NB) partials[t] = s[t] - v;  // exclusive
}

// phase 3: in-block exclusive scan + block base -> row_off
__global__ __launch_bounds__(256) void scan_final_kernel(const int* __restrict__ deg,
                                                         const int* __restrict__ partials,
                                                         int* __restrict__ row_off) {
    int b = blockIdx.x;
    int tid = threadIdx.x;
    int base = b * 1024 + tid * 4;
    int t0 = 0, t1 = 0, t2 = 0, t3 = 0;
    if (base + 3 < N_NODES) {
        int4 v = *reinterpret_cast<const int4*>(&deg[base]);
        t0 = v.x; t1 = v.y; t2 = v.z; t3 = v.w;
    } else {
        if (base + 0 < N_NODES) t0 = deg[base + 0];
        if (base + 1 < N_NODES) t1 = deg[base + 1];
        if (base + 2 < N_NODES) t2 = deg[base + 2];
        if (base + 3 < N_NODES) t3 = deg[base + 3];
    }
    int s = t0 + t1 + t2 + t3;
    __shared__ int sc[256];
    sc[tid] = s;
    __syncthreads();
    for (int off = 1; off < 256; off <<= 1) {
        int u = (tid >= off) ? sc[tid - off] : 0;
        __syncthreads();
        sc[tid] += u;
        __syncthreads();
    }
    int run = partials[b] + sc[tid] - s;  // exclusive base for this thread's 4
    if (base + 0 < N_NODES) row_off[base + 0] = run; run += t0;
    if (base + 1 < N_NODES) row_off[base + 1] = run; run += t1;
    if (base + 2 < N_NODES) row_off[base + 2] = run; run += t2;
    if (base + 3 < N_NODES) row_off[base + 3] = run;
    if (b == 0 && tid == 0) row_off[N_NODES] = N_EDGES;
}

__global__ void fill_kernel(const int* __restrict__ src, const int* __restrict__ dst,
                            const int* __restrict__ row_off, int* __restrict__ cursor,
                            int* __restrict__ csr_src) {
    int e = blockIdx.x * blockDim.x + threadIdx.x;
    if (e < N_EDGES) {
        int d = dst[e];
        int p = atomicAdd(&cursor[d], 1);
        csr_src[row_off[d] + p] = src[e];
    }
}

// ---------------- fp32 -> bf16 convert (feat) ----------------

__global__ __launch_bounds__(256) void convert_bf16_kernel(const float* __restrict__ in,
                                                           unsigned short* __restrict__ out) {
    size_t i = (size_t)(blockIdx.x * blockDim.x + threadIdx.x) * 4;
    float4 v = *reinterpret_cast<const float4*>(&in[i]);
    ushort4 o;
    o.x = f2bf(v.x); o.y = f2bf(v.y); o.z = f2bf(v.z); o.w = f2bf(v.w);
    *reinterpret_cast<ushort4*>(&out[i]) = o;
}

// ---------------- weight transpose+convert: WT[n][k] = W[k][n], bf16 ----------------

__global__ __launch_bounds__(256) void wt_build_kernel(const float* __restrict__ Ws0,
                                                       const float* __restrict__ Wn0,
                                                       const float* __restrict__ Ws1,
                                                       const float* __restrict__ Wn1,
                                                       unsigned short* __restrict__ WT0,
                                                       unsigned short* __restrict__ WT1) {
    int e = blockIdx.x * blockDim.x + threadIdx.x;  // 0..65535
    int layer = e >> 15;
    int r = e & 32767;
    int n = r >> 8;
    int k = r & 255;
    const float* Ws = layer ? Ws1 : Ws0;
    const float* Wn = layer ? Wn1 : Wn0;
    float v = (k < DIM) ? Ws[k * DIM + n] : Wn[(k - DIM) * DIM + n];
    unsigned short* WT = layer ? WT1 : WT0;
    WT[n * 256 + k] = f2bf(v);
}

// ---------------- mean aggregation (CSR gather), bf16 in/out ----------------

__global__ __launch_bounds__(256) void agg_bf16_kernel(const unsigned short* __restrict__ h,
                                                       const int* __restrict__ row_off,
                                                       const int* __restrict__ csr_src,
                                                       unsigned short* __restrict__ hn) {
    int wave = threadIdx.x >> 6;
    int lane = threadIdx.x & 63;
    int node = blockIdx.x * 4 + wave;
    if (node >= N_NODES) return;
    int lo = row_off[node], hi = row_off[node + 1];
    float ax = 0.f, ay = 0.f;
    for (int i = lo; i < hi; ++i) {
        int s = csr_src[i];
        unsigned int v = *reinterpret_cast<const unsigned int*>(&h[(size_t)s * DIM + lane * 2]);
        ax += __builtin_bit_cast(float, v << 16);
        ay += __builtin_bit_cast(float, v & 0xFFFF0000u);
    }
    float rd = (hi > lo) ? 1.0f / (float)(hi - lo) : 1.0f;
    unsigned int o = (unsigned int)f2bf(ax * rd) | ((unsigned int)f2bf(ay * rd) << 16);
    *reinterpret_cast<unsigned int*>(&hn[(size_t)node * DIM + lane * 2]) = o;
}

// ---------------- MFMA GEMM: C[N][128] = [Ab|Hb] @ WT^T, fp32 out ----------------

__global__ __launch_bounds__(256) void gemm_mfma_kernel(const unsigned short* __restrict__ Ab,
                                                        const unsigned short* __restrict__ Hb,
                                                        const unsigned short* __restrict__ WT,
                                                        float* __restrict__ C) {
    __shared__ unsigned short wt[32768];  // 64 KB, [n][k] bf16, XOR-swizzled
    const int tid = threadIdx.x;

#pragma unroll
    for (int i = 0; i < 16; ++i) {
        int c = i * 256 + tid;
        int n = c >> 5;
        unsigned int waddr = ((unsigned int)(c * 16)) ^ (((unsigned int)(n & 7)) << 4);
        uint4 v = *reinterpret_cast<const uint4*>(&WT[c * 8]);
        *reinterpret_cast<uint4*>(reinterpret_cast<char*>(wt) + waddr) = v;
    }
    __syncthreads();

    const int wid = tid >> 6;
    const int lane = tid & 63;
    const int lrow = lane & 15;
    const int g = lane >> 4;
    const int r0 = blockIdx.x * 128 + wid * 32;

    f32x4_t acc[2][8];
#pragma unroll
    for (int mt = 0; mt < 2; ++mt)
#pragma unroll
        for (int nt = 0; nt < 8; ++nt) acc[mt][nt] = (f32x4_t){0.f, 0.f, 0.f, 0.f};

#pragma unroll
    for (int ks = 0; ks < 8; ++ks) {
        const unsigned short* __restrict__ base = (ks < 4) ? Ab : Hb;
        const int kk = (ks & 3) * 32 + g * 8;
        bf16x8_t a[2];
#pragma unroll
        for (int mt = 0; mt < 2; ++mt) {
            int row = r0 + mt * 16 + lrow;
            if (row >= N_NODES) row = N_NODES - 1;
            a[mt] = *reinterpret_cast<const bf16x8_t*>(&base[(size_t)row * DIM + kk]);
        }
#pragma unroll
        for (int nt = 0; nt < 8; ++nt) {
            int n = nt * 16 + lrow;
            unsigned int raddr = ((unsigned int)(n * 512 + ks * 64 + g * 16)) ^ (((unsigned int)(n & 7)) << 4);
            bf16x8_t b = *reinterpret_cast<const bf16x8_t*>(reinterpret_cast<const char*>(wt) + raddr);
            acc[0][nt] = __builtin_amdgcn_mfma_f32_16x16x32_bf16(a[0], b, acc[0][nt], 0, 0, 0);
            acc[1][nt] = __builtin_amdgcn_mfma_f32_16x16x32_bf16(a[1], b, acc[1][nt], 0, 0, 0);
        }
    }

#pragma unroll
    for (int mt = 0; mt < 2; ++mt) {
#pragma unroll
        for (int j = 0; j < 4; ++j) {
            int row = r0 + mt * 16 + g * 4 + j;
            if (row < N_NODES) {
#pragma unroll
                for (int nt = 0; nt < 8; ++nt)
                    C[(size_t)row * DIM + nt * 16 + lrow] = acc[mt][nt][j];
            }
        }
    }
}

// ---------------- BatchNorm stats ----------------

__global__ __launch_bounds__(256) void bn_stats_kernel(const float* __restrict__ H,
                                                       float* __restrict__ bnsum,
                                                       float* __restrict__ bnsq) {
    int c = threadIdx.x & 127;
    int half = threadIdx.x >> 7;
    float s = 0.f, q = 0.f;
    for (int r = blockIdx.x * 2 + half; r < N_NODES; r += gridDim.x * 2) {
        float v = H[(size_t)r * DIM + c];
        s += v; q += v * v;
    }
    __shared__ float ls[256], lq[256];
    ls[threadIdx.x] = s; lq[threadIdx.x] = q;
    __syncthreads();
    if (half == 0) {
        s = ls[threadIdx.x] + ls[threadIdx.x + 128];
        q = lq[threadIdx.x] + lq[threadIdx.x + 128];
        atomicAdd(&bnsum[c], s);
        atomicAdd(&bnsq[c], q);
    }
}

// ---------------- BatchNorm apply + ReLU, fp32 in -> bf16 out ----------------

__global__ __launch_bounds__(256) void bn_apply_bf16_kernel(const float* __restrict__ H,
                                                            const float* __restrict__ bnsum,
                                                            const float* __restrict__ bnsq,
                                                            const float* __restrict__ gamma,
                                                            const float* __restrict__ beta,
                                                            unsigned short* __restrict__ Hb) {
    size_t idx = (size_t)(blockIdx.x * blockDim.x + threadIdx.x) * 4;
    const float invN = 1.0f / (float)N_NODES;
    int c = (int)(idx & (DIM - 1));
    float4 v = *reinterpret_cast<const float4*>(&H[idx]);
    float o[4] = {v.x, v.y, v.z, v.w};
    ushort4 ob;
#pragma unroll
    for (int j = 0; j < 4; ++j) {
        int cj = c + j;
        float mean = bnsum[cj] * invN;
        float var = bnsq[cj] * invN - mean * mean;
        float scale = gamma[cj] * rsqrtf(var + BN_EPS);
        float val = (o[j] - mean) * scale + beta[cj];
        o[j] = val > 0.f ? val : 0.f;
    }
    ob.x = f2bf(o[0]); ob.y = f2bf(o[1]); ob.z = f2bf(o[2]); ob.w = f2bf(o[3]);
    *reinterpret_cast<ushort4*>(&Hb[idx]) = ob;
}

// ---------------- output layer: C[N][40] = A@Ws + Bn@Wn + b ----------------

__global__ __launch_bounds__(256) void gemm_out_kernel(const unsigned short* __restrict__ A,
                                                       const unsigned short* __restrict__ Bn,
                                                       const float* __restrict__ Ws,
                                                       const float* __restrict__ Wn,
                                                       const float* __restrict__ bias,
                                                       float* __restrict__ C) {
    __shared__ float Wls[DIM][OUTD];
    __shared__ float Wln[DIM][OUTD];
    for (int i = threadIdx.x; i < DIM * OUTD; i += 256) {
        ((float*)Wls)[i] = Ws[i];
        ((float*)Wln)[i] = Wn[i];
    }
    __syncthreads();
    int r = blockIdx.x * 256 + threadIdx.x;
    if (r >= N_NODES) return;
    float acc[OUTD];
#pragma unroll
    for (int c = 0; c < OUTD; ++c) acc[c] = bias[c];
    const unsigned short* __restrict__ ar = &A[(size_t)r * DIM];
    const unsigned short* __restrict__ br = &Bn[(size_t)r * DIM];
    for (int k8 = 0; k8 < DIM / 8; ++k8) {
        uint4 avu = *reinterpret_cast<const uint4*>(&ar[k8 * 8]);
        uint4 bvu = *reinterpret_cast<const uint4*>(&br[k8 * 8]);
        unsigned int aw[4] = {avu.x, avu.y, avu.z, avu.w};
        unsigned int bw[4] = {bvu.x, bvu.y, bvu.z, bvu.w};
        float a_[8], b_[8];
#pragma unroll
        for (int q = 0; q < 4; ++q) {
            a_[q * 2]     = __builtin_bit_cast(float, aw[q] << 16);
            a_[q * 2 + 1] = __builtin_bit_cast(float, aw[q] & 0xFFFF0000u);
            b_[q * 2]     = __builtin_bit_cast(float, bw[q] << 16);
            b_[q * 2 + 1] = __builtin_bit_cast(float, bw[q] & 0xFFFF0000u);
        }
#pragma unroll
        for (int q = 0; q < 8; ++q) {
            int k = k8 * 8 + q;
#pragma unroll
            for (int c4 = 0; c4 < OUTD / 4; ++c4) {
                float4 ws = *reinterpret_cast<const float4*>(&Wls[k][c4 * 4]);
                float4 wn = *reinterpret_cast<const float4*>(&Wln[k][c4 * 4]);
                acc[c4 * 4 + 0] += a_[q] * ws.x + b_[q] * wn.x;
                acc[c4 * 4 + 1] += a_[q] * ws.y + b_[q] * wn.y;
                acc[c4 * 4 + 2] += a_[q] * ws.z + b_[q] * wn.z;
                acc[c4 * 4 + 3] += a_[q] * ws.w + b_[q] * wn.w;
            }
        }
    }
#pragma unroll
    for (int c4 = 0; c4 < OUTD / 4; ++c4) {
        float4 v = make_float4(acc[c4 * 4], acc[c4 * 4 + 1], acc[c4 * 4 + 2], acc[c4 * 4 + 3]);
        *reinterpret_cast<float4*>(&C[(size_t)r * OUTD + c4 * 4]) = v;
    }
}

// ---------------- launch ----------------

extern "C" void kernel_launch(void* const* d_in, const int* in_sizes, int n_in,
                              void* d_out, int out_size, void* d_ws, size_t ws_size,
                              hipStream_t stream) {
    const float* feat = (const float*)d_in[0];
    const int* src = (const int*)d_in[1];
    const int* dst = (const int*)d_in[2];
    const float* Ws0 = (const float*)d_in[3];
    const float* Wn0 = (const float*)d_in[4];
    const float* g0  = (const float*)d_in[5];
    const float* be0 = (const float*)d_in[6];
    const float* Ws1 = (const float*)d_in[7];
    const float* Wn1 = (const float*)d_in[8];
    const float* g1  = (const float*)d_in[9];
    const float* be1 = (const float*)d_in[10];
    const float* Ws2 = (const float*)d_in[11];
    const float* Wn2 = (const float*)d_in[12];
    const float* b2  = (const float*)d_in[13];
    float* out = (float*)d_out;

    char* ws = (char*)d_ws;
    int*   deg     = (int*)(ws);                       // 400000 B (zeroed)
    int*   cursor  = (int*)(ws + 400000);              // 400000 B (zeroed)
    float* bn      = (float*)(ws + 800000);            // 2048 B   (zeroed)
    int*   row_off = (int*)(ws + 802048);              // 400004 B
    int*   csr     = (int*)(ws + 1202176);             // 3200000 B
    unsigned short* featb = (unsigned short*)(ws + 4402176);   // 25.6 MB (reused as h1b)
    unsigned short* hnb   = (unsigned short*)(ws + 30002176);  // 25.6 MB
    unsigned short* h0b   = (unsigned short*)(ws + 55602176);  // 25.6 MB
    float*          hf    = (float*)(ws + 81202176);           // 51.2 MB fp32 gemm out
    unsigned short* WT0   = (unsigned short*)(ws + 132402176); // 65536 B
    unsigned short* WT1   = (unsigned short*)(ws + 132467712); // 65536 B
    int*   partials = (int*)(ws + 132533248);                  // 512 B
    unsigned short* h1b   = featb;  // featb dead after layer-0 gemm

    hipMemsetAsync(ws, 0, 802048, stream);

    const int EB = (N_EDGES + 255) / 256;        // 3125
    const int AB = (N_NODES + 3) / 4;            // 25000
    const int MB = (N_NODES + 127) / 128;        // 782
    const int OB = (N_NODES + 255) / 256;        // 391
    const int NE = (N_NODES * DIM) / 4 / 256;    // 12500

    deg_kernel<<<EB, 256, 0, stream>>>(dst, deg);
    scan_partial_kernel<<<SCAN_NB, 256, 0, stream>>>(deg, partials);
    scan_partials_kernel<<<1, 128, 0, stream>>>(partials);
    scan_final_kernel<<<SCAN_NB, 256, 0, stream>>>(deg, partials, row_off);
    fill_kernel<<<EB, 256, 0, stream>>>(src, dst, row_off, cursor, csr);

    convert_bf16_kernel<<<NE, 256, 0, stream>>>(feat, featb);
    wt_build_kernel<<<256, 256, 0, stream>>>(Ws0, Wn0, Ws1, Wn1, WT0, WT1);

    // layer 0
    agg_bf16_kernel<<<AB, 256, 0, stream>>>(featb, row_off, csr, hnb);
    gemm_mfma_kernel<<<MB, 256, 0, stream>>>(featb, hnb, WT0, hf);
    bn_stats_kernel<<<1024, 256, 0, stream>>>(hf, bn + 0, bn + 128);
    bn_apply_bf16_kernel<<<NE, 256, 0, stream>>>(hf, bn + 0, bn + 128, g0, be0, h0b);

    // layer 1
    agg_bf16_kernel<<<AB, 256, 0, stream>>>(h0b, row_off, csr, hnb);
    gemm_mfma_kernel<<<MB, 256, 0, stream>>>(h0b, hnb, WT1, hf);
    bn_stats_kernel<<<1024, 256, 0, stream>>>(hf, bn + 256, bn + 384);
    bn_apply_bf16_kernel<<<NE, 256, 0, stream>>>(hf, bn + 256, bn + 384, g1, be1, h1b);

    // layer 2
    agg_bf16_kernel<<<AB, 256, 0, stream>>>(h1b, row_off, csr, hnb);
    gemm_out_kernel<<<OB, 256, 0, stream>>>(h1b, hnb, Ws2, Wn2, b2, out);
}

// Round 4
// 505.321 us; speedup vs baseline: 19.0525x; 1.1121x over previous
//
#include <hip/hip_runtime.h>

#define N_NODES 100000
#define N_EDGES 800000
#define DIM 128
#define OUTD 40
#define OUTP 48  // padded to 3x16 MFMA col-tiles
#define BN_EPS 1e-5f
#define SCAN_NB 98  // ceil(100000/1024)

typedef __bf16 bf16x8_t __attribute__((ext_vector_type(8)));
typedef float f32x4_t __attribute__((ext_vector_type(4)));

__device__ __forceinline__ unsigned short f2bf(float f) {
    unsigned int u = __builtin_bit_cast(unsigned int, f);
    u = (u + 0x7FFF + ((u >> 16) & 1)) >> 16;
    return (unsigned short)u;
}

// ---------------- CSR build ----------------

__global__ void deg_kernel(const int* __restrict__ dst, int* __restrict__ deg) {
    int e = blockIdx.x * blockDim.x + threadIdx.x;
    if (e < N_EDGES) atomicAdd(&deg[dst[e]], 1);
}

__global__ __launch_bounds__(256) void scan_partial_kernel(const int* __restrict__ deg,
                                                           int* __restrict__ partials) {
    int b = blockIdx.x;
    int tid = threadIdx.x;
    int base = b * 1024 + tid * 4;
    int t0 = 0, t1 = 0, t2 = 0, t3 = 0;
    if (base + 3 < N_NODES) {
        int4 v = *reinterpret_cast<const int4*>(&deg[base]);
        t0 = v.x; t1 = v.y; t2 = v.z; t3 = v.w;
    } else {
        if (base + 0 < N_NODES) t0 = deg[base + 0];
        if (base + 1 < N_NODES) t1 = deg[base + 1];
        if (base + 2 < N_NODES) t2 = deg[base + 2];
        if (base + 3 < N_NODES) t3 = deg[base + 3];
    }
    int s = t0 + t1 + t2 + t3;
    __shared__ int red[256];
    red[tid] = s;
    __syncthreads();
    for (int o = 128; o; o >>= 1) {
        if (tid < o) red[tid] += red[tid + o];
        __syncthreads();
    }
    if (tid == 0) partials[b] = red[0];
}

__global__ __launch_bounds__(128) void scan_partials_kernel(int* __restrict__ partials) {
    __shared__ int s[128];
    int t = threadIdx.x;
    int v = (t < SCAN_NB) ? partials[t] : 0;
    s[t] = v;
    __syncthreads();
    for (int off = 1; off < 128; off <<= 1) {
        int u = (t >= off) ? s[t - off] : 0;
        __syncthreads();
        s[t] += u;
        __syncthreads();
    }
    if (t < SCAN_NB) partials[t] = s[t] - v;  // exclusive
}

__global__ __launch_bounds__(256) void scan_final_kernel(const int* __restrict__ deg,
                                                         const int* __restrict__ partials,
                                                         int* __restrict__ row_off) {
    int b = blockIdx.x;
    int tid = threadIdx.x;
    int base = b * 1024 + tid * 4;
    int t0 = 0, t1 = 0, t2 = 0, t3 = 0;
    if (base + 3 < N_NODES) {
        int4 v = *reinterpret_cast<const int4*>(&deg[base]);
        t0 = v.x; t1 = v.y; t2 = v.z; t3 = v.w;
    } else {
        if (base + 0 < N_NODES) t0 = deg[base + 0];
        if (base + 1 < N_NODES) t1 = deg[base + 1];
        if (base + 2 < N_NODES) t2 = deg[base + 2];
        if (base + 3 < N_NODES) t3 = deg[base + 3];
    }
    int s = t0 + t1 + t2 + t3;
    __shared__ int sc[256];
    sc[tid] = s;
    __syncthreads();
    for (int off = 1; off < 256; off <<= 1) {
        int u = (tid >= off) ? sc[tid - off] : 0;
        __syncthreads();
        sc[tid] += u;
        __syncthreads();
    }
    int run = partials[b] + sc[tid] - s;
    if (base + 0 < N_NODES) row_off[base + 0] = run; run += t0;
    if (base + 1 < N_NODES) row_off[base + 1] = run; run += t1;
    if (base + 2 < N_NODES) row_off[base + 2] = run; run += t2;
    if (base + 3 < N_NODES) row_off[base + 3] = run;
    if (b == 0 && tid == 0) row_off[N_NODES] = N_EDGES;
}

__global__ void fill_kernel(const int* __restrict__ src, const int* __restrict__ dst,
                            const int* __restrict__ row_off, int* __restrict__ cursor,
                            int* __restrict__ csr_src) {
    int e = blockIdx.x * blockDim.x + threadIdx.x;
    if (e < N_EDGES) {
        int d = dst[e];
        int p = atomicAdd(&cursor[d], 1);
        csr_src[row_off[d] + p] = src[e];
    }
}

// ---------------- fp32 -> bf16 convert (feat) ----------------

__global__ __launch_bounds__(256) void convert_bf16_kernel(const float* __restrict__ in,
                                                           unsigned short* __restrict__ out) {
    size_t i = (size_t)(blockIdx.x * blockDim.x + threadIdx.x) * 4;
    float4 v = *reinterpret_cast<const float4*>(&in[i]);
    ushort4 o;
    o.x = f2bf(v.x); o.y = f2bf(v.y); o.z = f2bf(v.z); o.w = f2bf(v.w);
    *reinterpret_cast<ushort4*>(&out[i]) = o;
}

// ---------------- weight transpose+convert: WT[n][k] = W[k][n], bf16 ----------------

__global__ __launch_bounds__(256) void wt_build_kernel(const float* __restrict__ Ws0,
                                                       const float* __restrict__ Wn0,
                                                       const float* __restrict__ Ws1,
                                                       const float* __restrict__ Wn1,
                                                       unsigned short* __restrict__ WT0,
                                                       unsigned short* __restrict__ WT1) {
    int e = blockIdx.x * blockDim.x + threadIdx.x;  // 0..65535
    int layer = e >> 15;
    int r = e & 32767;
    int n = r >> 8;
    int k = r & 255;
    const float* Ws = layer ? Ws1 : Ws0;
    const float* Wn = layer ? Wn1 : Wn0;
    float v = (k < DIM) ? Ws[k * DIM + n] : Wn[(k - DIM) * DIM + n];
    unsigned short* WT = layer ? WT1 : WT0;
    WT[n * 256 + k] = f2bf(v);
}

// WT2[n][k], n in [0,48), zero-padded beyond OUTD
__global__ __launch_bounds__(256) void wt2_build_kernel(const float* __restrict__ Ws2,
                                                        const float* __restrict__ Wn2,
                                                        unsigned short* __restrict__ WT2) {
    int e = blockIdx.x * blockDim.x + threadIdx.x;  // 0..12287
    int n = e >> 8;
    int k = e & 255;
    float v = 0.f;
    if (n < OUTD) v = (k < DIM) ? Ws2[k * OUTD + n] : Wn2[(k - DIM) * OUTD + n];
    WT2[n * 256 + k] = f2bf(v);
}

// ---------------- mean aggregation (CSR gather), bf16 in/out ----------------

__global__ __launch_bounds__(256) void agg_bf16_kernel(const unsigned short* __restrict__ h,
                                                       const int* __restrict__ row_off,
                                                       const int* __restrict__ csr_src,
                                                       unsigned short* __restrict__ hn) {
    int wave = threadIdx.x >> 6;
    int lane = threadIdx.x & 63;
    int node = blockIdx.x * 4 + wave;
    if (node >= N_NODES) return;
    int lo = row_off[node], hi = row_off[node + 1];
    float ax = 0.f, ay = 0.f;
    for (int i = lo; i < hi; ++i) {
        int s = csr_src[i];
        unsigned int v = *reinterpret_cast<const unsigned int*>(&h[(size_t)s * DIM + lane * 2]);
        ax += __builtin_bit_cast(float, v << 16);
        ay += __builtin_bit_cast(float, v & 0xFFFF0000u);
    }
    float rd = (hi > lo) ? 1.0f / (float)(hi - lo) : 1.0f;
    unsigned int o = (unsigned int)f2bf(ax * rd) | ((unsigned int)f2bf(ay * rd) << 16);
    *reinterpret_cast<unsigned int*>(&hn[(size_t)node * DIM + lane * 2]) = o;
}

// ---------------- MFMA GEMM: C[N][128] = [Ab|Hb] @ WT^T, fp32 out ----------------

__global__ __launch_bounds__(256) void gemm_mfma_kernel(const unsigned short* __restrict__ Ab,
                                                        const unsigned short* __restrict__ Hb,
                                                        const unsigned short* __restrict__ WT,
                                                        float* __restrict__ C) {
    __shared__ unsigned short wt[32768];  // 64 KB, [n][k] bf16, XOR-swizzled
    const int tid = threadIdx.x;

#pragma unroll
    for (int i = 0; i < 16; ++i) {
        int c = i * 256 + tid;
        int n = c >> 5;
        unsigned int waddr = ((unsigned int)(c * 16)) ^ (((unsigned int)(n & 7)) << 4);
        uint4 v = *reinterpret_cast<const uint4*>(&WT[c * 8]);
        *reinterpret_cast<uint4*>(reinterpret_cast<char*>(wt) + waddr) = v;
    }
    __syncthreads();

    const int wid = tid >> 6;
    const int lane = tid & 63;
    const int lrow = lane & 15;
    const int g = lane >> 4;
    const int r0 = blockIdx.x * 128 + wid * 32;

    f32x4_t acc[2][8];
#pragma unroll
    for (int mt = 0; mt < 2; ++mt)
#pragma unroll
        for (int nt = 0; nt < 8; ++nt) acc[mt][nt] = (f32x4_t){0.f, 0.f, 0.f, 0.f};

#pragma unroll
    for (int ks = 0; ks < 8; ++ks) {
        const unsigned short* __restrict__ base = (ks < 4) ? Ab : Hb;
        const int kk = (ks & 3) * 32 + g * 8;
        bf16x8_t a[2];
#pragma unroll
        for (int mt = 0; mt < 2; ++mt) {
            int row = r0 + mt * 16 + lrow;
            if (row >= N_NODES) row = N_NODES - 1;
            a[mt] = *reinterpret_cast<const bf16x8_t*>(&base[(size_t)row * DIM + kk]);
        }
#pragma unroll
        for (int nt = 0; nt < 8; ++nt) {
            int n = nt * 16 + lrow;
            unsigned int raddr = ((unsigned int)(n * 512 + ks * 64 + g * 16)) ^ (((unsigned int)(n & 7)) << 4);
            bf16x8_t b = *reinterpret_cast<const bf16x8_t*>(reinterpret_cast<const char*>(wt) + raddr);
            acc[0][nt] = __builtin_amdgcn_mfma_f32_16x16x32_bf16(a[0], b, acc[0][nt], 0, 0, 0);
            acc[1][nt] = __builtin_amdgcn_mfma_f32_16x16x32_bf16(a[1], b, acc[1][nt], 0, 0, 0);
        }
    }

#pragma unroll
    for (int mt = 0; mt < 2; ++mt) {
#pragma unroll
        for (int j = 0; j < 4; ++j) {
            int row = r0 + mt * 16 + g * 4 + j;
            if (row < N_NODES) {
#pragma unroll
                for (int nt = 0; nt < 8; ++nt)
                    C[(size_t)row * DIM + nt * 16 + lrow] = acc[mt][nt][j];
            }
        }
    }
}

// ---------------- BatchNorm stats ----------------

__global__ __launch_bounds__(256) void bn_stats_kernel(const float* __restrict__ H,
                                                       float* __restrict__ bnsum,
                                                       float* __restrict__ bnsq) {
    int c = threadIdx.x & 127;
    int half = threadIdx.x >> 7;
    float s = 0.f, q = 0.f;
    for (int r = blockIdx.x * 2 + half; r < N_NODES; r += gridDim.x * 2) {
        float v = H[(size_t)r * DIM + c];
        s += v; q += v * v;
    }
    __shared__ float ls[256], lq[256];
    ls[threadIdx.x] = s; lq[threadIdx.x] = q;
    __syncthreads();
    if (half == 0) {
        s = ls[threadIdx.x] + ls[threadIdx.x + 128];
        q = lq[threadIdx.x] + lq[threadIdx.x + 128];
        atomicAdd(&bnsum[c], s);
        atomicAdd(&bnsq[c], q);
    }
}

// ---------------- BatchNorm apply + ReLU, fp32 in -> bf16 out ----------------

__global__ __launch_bounds__(256) void bn_apply_bf16_kernel(const float* __restrict__ H,
                                                            const float* __restrict__ bnsum,
                                                            const float* __restrict__ bnsq,
                                                            const float* __restrict__ gamma,
                                                            const float* __restrict__ beta,
                                                            unsigned short* __restrict__ Hb) {
    size_t idx = (size_t)(blockIdx.x * blockDim.x + threadIdx.x) * 4;
    const float invN = 1.0f / (float)N_NODES;
    int c = (int)(idx & (DIM - 1));
    float4 v = *reinterpret_cast<const float4*>(&H[idx]);
    float o[4] = {v.x, v.y, v.z, v.w};
    ushort4 ob;
#pragma unroll
    for (int j = 0; j < 4; ++j) {
        int cj = c + j;
        float mean = bnsum[cj] * invN;
        float var = bnsq[cj] * invN - mean * mean;
        float scale = gamma[cj] * rsqrtf(var + BN_EPS);
        float val = (o[j] - mean) * scale + beta[cj];
        o[j] = val > 0.f ? val : 0.f;
    }
    ob.x = f2bf(o[0]); ob.y = f2bf(o[1]); ob.z = f2bf(o[2]); ob.w = f2bf(o[3]);
    *reinterpret_cast<ushort4*>(&Hb[idx]) = ob;
}

// ---------------- output layer (MFMA): C[N][40] = [Ab|Hb] @ WT2^T + b ----------------

__global__ __launch_bounds__(256) void gemm_out_mfma_kernel(const unsigned short* __restrict__ Ab,
                                                            const unsigned short* __restrict__ Hb,
                                                            const unsigned short* __restrict__ WT2,
                                                            const float* __restrict__ bias,
                                                            float* __restrict__ C) {
    __shared__ unsigned short wt[OUTP * 256];  // 24 KB, XOR-swizzled
    const int tid = threadIdx.x;

#pragma unroll
    for (int i = 0; i < 6; ++i) {
        int c = i * 256 + tid;               // 16B chunks: 0..1535
        int n = c >> 5;
        unsigned int waddr = ((unsigned int)(c * 16)) ^ (((unsigned int)(n & 7)) << 4);
        uint4 v = *reinterpret_cast<const uint4*>(&WT2[c * 8]);
        *reinterpret_cast<uint4*>(reinterpret_cast<char*>(wt) + waddr) = v;
    }
    __syncthreads();

    const int wid = tid >> 6;
    const int lane = tid & 63;
    const int lrow = lane & 15;
    const int g = lane >> 4;
    const int r0 = blockIdx.x * 128 + wid * 32;

    f32x4_t acc[2][3];
#pragma unroll
    for (int mt = 0; mt < 2; ++mt)
#pragma unroll
        for (int nt = 0; nt < 3; ++nt) acc[mt][nt] = (f32x4_t){0.f, 0.f, 0.f, 0.f};

#pragma unroll
    for (int ks = 0; ks < 8; ++ks) {
        const unsigned short* __restrict__ base = (ks < 4) ? Ab : Hb;
        const int kk = (ks & 3) * 32 + g * 8;
        bf16x8_t a[2];
#pragma unroll
        for (int mt = 0; mt < 2; ++mt) {
            int row = r0 + mt * 16 + lrow;
            if (row >= N_NODES) row = N_NODES - 1;
            a[mt] = *reinterpret_cast<const bf16x8_t*>(&base[(size_t)row * DIM + kk]);
        }
#pragma unroll
        for (int nt = 0; nt < 3; ++nt) {
            int n = nt * 16 + lrow;
            unsigned int raddr = ((unsigned int)(n * 512 + ks * 64 + g * 16)) ^ (((unsigned int)(n & 7)) << 4);
            bf16x8_t b = *reinterpret_cast<const bf16x8_t*>(reinterpret_cast<const char*>(wt) + raddr);
            acc[0][nt] = __builtin_amdgcn_mfma_f32_16x16x32_bf16(a[0], b, acc[0][nt], 0, 0, 0);
            acc[1][nt] = __builtin_amdgcn_mfma_f32_16x16x32_bf16(a[1], b, acc[1][nt], 0, 0, 0);
        }
    }

    float bb[3];
#pragma unroll
    for (int nt = 0; nt < 3; ++nt) {
        int col = nt * 16 + lrow;
        bb[nt] = (col < OUTD) ? bias[col] : 0.f;
    }

#pragma unroll
    for (int mt = 0; mt < 2; ++mt) {
#pragma unroll
        for (int j = 0; j < 4; ++j) {
            int row = r0 + mt * 16 + g * 4 + j;
            if (row < N_NODES) {
#pragma unroll
                for (int nt = 0; nt < 3; ++nt) {
                    int col = nt * 16 + lrow;
                    if (col < OUTD)
                        C[(size_t)row * OUTD + col] = acc[mt][nt][j] + bb[nt];
                }
            }
        }
    }
}

// ---------------- launch ----------------

extern "C" void kernel_launch(void* const* d_in, const int* in_sizes, int n_in,
                              void* d_out, int out_size, void* d_ws, size_t ws_size,
                              hipStream_t stream) {
    const float* feat = (const float*)d_in[0];
    const int* src = (const int*)d_in[1];
    const int* dst = (const int*)d_in[2];
    const float* Ws0 = (const float*)d_in[3];
    const float* Wn0 = (const float*)d_in[4];
    const float* g0  = (const float*)d_in[5];
    const float* be0 = (const float*)d_in[6];
    const float* Ws1 = (const float*)d_in[7];
    const float* Wn1 = (const float*)d_in[8];
    const float* g1  = (const float*)d_in[9];
    const float* be1 = (const float*)d_in[10];
    const float* Ws2 = (const float*)d_in[11];
    const float* Wn2 = (const float*)d_in[12];
    const float* b2  = (const float*)d_in[13];
    float* out = (float*)d_out;

    char* ws = (char*)d_ws;
    int*   deg     = (int*)(ws);                       // 400000 B (zeroed)
    int*   cursor  = (int*)(ws + 400000);              // 400000 B (zeroed)
    float* bn      = (float*)(ws + 800000);            // 2048 B   (zeroed)
    int*   row_off = (int*)(ws + 802048);              // 400004 B
    int*   csr     = (int*)(ws + 1202176);             // 3200000 B
    unsigned short* featb = (unsigned short*)(ws + 4402176);   // 25.6 MB (reused as h1b)
    unsigned short* hnb   = (unsigned short*)(ws + 30002176);  // 25.6 MB
    unsigned short* h0b   = (unsigned short*)(ws + 55602176);  // 25.6 MB
    float*          hf    = (float*)(ws + 81202176);           // 51.2 MB fp32 gemm out
    unsigned short* WT0   = (unsigned short*)(ws + 132402176); // 65536 B
    unsigned short* WT1   = (unsigned short*)(ws + 132467712); // 65536 B
    int*   partials = (int*)(ws + 132533248);                  // 512 B
    unsigned short* WT2   = (unsigned short*)(ws + 132533760); // 24576 B
    unsigned short* h1b   = featb;  // featb dead after layer-0 gemm

    hipMemsetAsync(ws, 0, 802048, stream);

    const int EB = (N_EDGES + 255) / 256;        // 3125
    const int AB = (N_NODES + 3) / 4;            // 25000
    const int MB = (N_NODES + 127) / 128;        // 782
    const int NE = (N_NODES * DIM) / 4 / 256;    // 12500

    deg_kernel<<<EB, 256, 0, stream>>>(dst, deg);
    scan_partial_kernel<<<SCAN_NB, 256, 0, stream>>>(deg, partials);
    scan_partials_kernel<<<1, 128, 0, stream>>>(partials);
    scan_final_kernel<<<SCAN_NB, 256, 0, stream>>>(deg, partials, row_off);
    fill_kernel<<<EB, 256, 0, stream>>>(src, dst, row_off, cursor, csr);

    convert_bf16_kernel<<<NE, 256, 0, stream>>>(feat, featb);
    wt_build_kernel<<<256, 256, 0, stream>>>(Ws0, Wn0, Ws1, Wn1, WT0, WT1);
    wt2_build_kernel<<<48, 256, 0, stream>>>(Ws2, Wn2, WT2);

    // layer 0
    agg_bf16_kernel<<<AB, 256, 0, stream>>>(featb, row_off, csr, hnb);
    gemm_mfma_kernel<<<MB, 256, 0, stream>>>(featb, hnb, WT0, hf);
    bn_stats_kernel<<<1024, 256, 0, stream>>>(hf, bn + 0, bn + 128);
    bn_apply_bf16_kernel<<<NE, 256, 0, stream>>>(hf, bn + 0, bn + 128, g0, be0, h0b);

    // layer 1
    agg_bf16_kernel<<<AB, 256, 0, stream>>>(h0b, row_off, csr, hnb);
    gemm_mfma_kernel<<<MB, 256, 0, stream>>>(h0b, hnb, WT1, hf);
    bn_stats_kernel<<<1024, 256, 0, stream>>>(hf, bn + 256, bn + 384);
    bn_apply_bf16_kernel<<<NE, 256, 0, stream>>>(hf, bn + 256, bn + 384, g1, be1, h1b);

    // layer 2
    agg_bf16_kernel<<<AB, 256, 0, stream>>>(h1b, row_off, csr, hnb);
    gemm_out_mfma_kernel<<<MB, 256, 0, stream>>>(h1b, hnb, WT2, b2, out);
}

// Round 5
// 383.432 us; speedup vs baseline: 25.1092x; 1.3179x over previous
//
#include <hip/hip_runtime.h>

#define N_NODES 100000
#define N_EDGES 800000
#define DIM 128
#define OUTD 40
#define OUTP 48  // padded to 3x16 MFMA col-tiles
#define BN_EPS 1e-5f
#define SCAN_NB 98  // ceil(100000/1024)

typedef __bf16 bf16x8_t __attribute__((ext_vector_type(8)));
typedef float f32x4_t __attribute__((ext_vector_type(4)));

__device__ __forceinline__ unsigned short f2bf(float f) {
    unsigned int u = __builtin_bit_cast(unsigned int, f);
    u = (u + 0x7FFF + ((u >> 16) & 1)) >> 16;
    return (unsigned short)u;
}

// ---------------- CSR build ----------------

__global__ void deg_kernel(const int* __restrict__ dst, int* __restrict__ deg) {
    int e = blockIdx.x * blockDim.x + threadIdx.x;
    if (e < N_EDGES) atomicAdd(&deg[dst[e]], 1);
}

__global__ __launch_bounds__(256) void scan_partial_kernel(const int* __restrict__ deg,
                                                           int* __restrict__ partials) {
    int b = blockIdx.x;
    int tid = threadIdx.x;
    int base = b * 1024 + tid * 4;
    int t0 = 0, t1 = 0, t2 = 0, t3 = 0;
    if (base + 3 < N_NODES) {
        int4 v = *reinterpret_cast<const int4*>(&deg[base]);
        t0 = v.x; t1 = v.y; t2 = v.z; t3 = v.w;
    } else {
        if (base + 0 < N_NODES) t0 = deg[base + 0];
        if (base + 1 < N_NODES) t1 = deg[base + 1];
        if (base + 2 < N_NODES) t2 = deg[base + 2];
        if (base + 3 < N_NODES) t3 = deg[base + 3];
    }
    int s = t0 + t1 + t2 + t3;
    __shared__ int red[256];
    red[tid] = s;
    __syncthreads();
    for (int o = 128; o; o >>= 1) {
        if (tid < o) red[tid] += red[tid + o];
        __syncthreads();
    }
    if (tid == 0) partials[b] = red[0];
}

__global__ __launch_bounds__(128) void scan_partials_kernel(int* __restrict__ partials) {
    __shared__ int s[128];
    int t = threadIdx.x;
    int v = (t < SCAN_NB) ? partials[t] : 0;
    s[t] = v;
    __syncthreads();
    for (int off = 1; off < 128; off <<= 1) {
        int u = (t >= off) ? s[t - off] : 0;
        __syncthreads();
        s[t] += u;
        __syncthreads();
    }
    if (t < SCAN_NB) partials[t] = s[t] - v;  // exclusive
}

__global__ __launch_bounds__(256) void scan_final_kernel(const int* __restrict__ deg,
                                                         const int* __restrict__ partials,
                                                         int* __restrict__ row_off) {
    int b = blockIdx.x;
    int tid = threadIdx.x;
    int base = b * 1024 + tid * 4;
    int t0 = 0, t1 = 0, t2 = 0, t3 = 0;
    if (base + 3 < N_NODES) {
        int4 v = *reinterpret_cast<const int4*>(&deg[base]);
        t0 = v.x; t1 = v.y; t2 = v.z; t3 = v.w;
    } else {
        if (base + 0 < N_NODES) t0 = deg[base + 0];
        if (base + 1 < N_NODES) t1 = deg[base + 1];
        if (base + 2 < N_NODES) t2 = deg[base + 2];
        if (base + 3 < N_NODES) t3 = deg[base + 3];
    }
    int s = t0 + t1 + t2 + t3;
    __shared__ int sc[256];
    sc[tid] = s;
    __syncthreads();
    for (int off = 1; off < 256; off <<= 1) {
        int u = (tid >= off) ? sc[tid - off] : 0;
        __syncthreads();
        sc[tid] += u;
        __syncthreads();
    }
    int run = partials[b] + sc[tid] - s;
    if (base + 0 < N_NODES) row_off[base + 0] = run; run += t0;
    if (base + 1 < N_NODES) row_off[base + 1] = run; run += t1;
    if (base + 2 < N_NODES) row_off[base + 2] = run; run += t2;
    if (base + 3 < N_NODES) row_off[base + 3] = run;
    if (b == 0 && tid == 0) row_off[N_NODES] = N_EDGES;
}

__global__ void fill_kernel(const int* __restrict__ src, const int* __restrict__ dst,
                            const int* __restrict__ row_off, int* __restrict__ cursor,
                            int* __restrict__ csr_src) {
    int e = blockIdx.x * blockDim.x + threadIdx.x;
    if (e < N_EDGES) {
        int d = dst[e];
        int p = atomicAdd(&cursor[d], 1);
        csr_src[row_off[d] + p] = src[e];
    }
}

// ---------------- fp32 -> bf16 convert (feat) ----------------

__global__ __launch_bounds__(256) void convert_bf16_kernel(const float* __restrict__ in,
                                                           unsigned short* __restrict__ out) {
    size_t i = (size_t)(blockIdx.x * blockDim.x + threadIdx.x) * 4;
    float4 v = *reinterpret_cast<const float4*>(&in[i]);
    ushort4 o;
    o.x = f2bf(v.x); o.y = f2bf(v.y); o.z = f2bf(v.z); o.w = f2bf(v.w);
    *reinterpret_cast<ushort4*>(&out[i]) = o;
}

// ---------------- weight transpose+convert: WT[n][k] = W[k][n], bf16 ----------------

__global__ __launch_bounds__(256) void wt_build_kernel(const float* __restrict__ Ws0,
                                                       const float* __restrict__ Wn0,
                                                       const float* __restrict__ Ws1,
                                                       const float* __restrict__ Wn1,
                                                       unsigned short* __restrict__ WT0,
                                                       unsigned short* __restrict__ WT1) {
    int e = blockIdx.x * blockDim.x + threadIdx.x;  // 0..65535
    int layer = e >> 15;
    int r = e & 32767;
    int n = r >> 8;
    int k = r & 255;
    const float* Ws = layer ? Ws1 : Ws0;
    const float* Wn = layer ? Wn1 : Wn0;
    float v = (k < DIM) ? Ws[k * DIM + n] : Wn[(k - DIM) * DIM + n];
    unsigned short* WT = layer ? WT1 : WT0;
    WT[n * 256 + k] = f2bf(v);
}

// WT2[n][k], n in [0,48), zero-padded beyond OUTD
__global__ __launch_bounds__(256) void wt2_build_kernel(const float* __restrict__ Ws2,
                                                        const float* __restrict__ Wn2,
                                                        unsigned short* __restrict__ WT2) {
    int e = blockIdx.x * blockDim.x + threadIdx.x;  // 0..12287
    int n = e >> 8;
    int k = e & 255;
    float v = 0.f;
    if (n < OUTD) v = (k < DIM) ? Ws2[k * OUTD + n] : Wn2[(k - DIM) * OUTD + n];
    WT2[n * 256 + k] = f2bf(v);
}

// ---------------- mean aggregation (CSR gather), bf16 in/out ----------------
// wave per node; 4x16-lane groups each gather a FULL 256B neighbor row
// (16B/lane), 4 neighbors in flight; butterfly-combine groups at the end.

__global__ __launch_bounds__(256) void agg_bf16_kernel(const unsigned short* __restrict__ h,
                                                       const int* __restrict__ row_off,
                                                       const int* __restrict__ csr_src,
                                                       unsigned short* __restrict__ hn) {
    int wave = threadIdx.x >> 6;
    int lane = threadIdx.x & 63;
    int node = blockIdx.x * 4 + wave;
    if (node >= N_NODES) return;
    int lo = row_off[node], hi = row_off[node + 1];
    const int grp = lane >> 4;   // 0..3: neighbor sub-slot
    const int l16 = lane & 15;   // 16B slice of the row
    float a[8] = {0.f, 0.f, 0.f, 0.f, 0.f, 0.f, 0.f, 0.f};
    for (int i = lo + grp; i < hi; i += 4) {
        int s = csr_src[i];
        uint4 v = *reinterpret_cast<const uint4*>(&h[(size_t)s * DIM + l16 * 8]);
        unsigned int w0 = v.x, w1 = v.y, w2 = v.z, w3 = v.w;
        a[0] += __builtin_bit_cast(float, w0 << 16);
        a[1] += __builtin_bit_cast(float, w0 & 0xFFFF0000u);
        a[2] += __builtin_bit_cast(float, w1 << 16);
        a[3] += __builtin_bit_cast(float, w1 & 0xFFFF0000u);
        a[4] += __builtin_bit_cast(float, w2 << 16);
        a[5] += __builtin_bit_cast(float, w2 & 0xFFFF0000u);
        a[6] += __builtin_bit_cast(float, w3 << 16);
        a[7] += __builtin_bit_cast(float, w3 & 0xFFFF0000u);
    }
#pragma unroll
    for (int q = 0; q < 8; ++q) {
        a[q] += __shfl_xor(a[q], 16, 64);
        a[q] += __shfl_xor(a[q], 32, 64);
    }
    if (grp == 0) {
        float rd = (hi > lo) ? 1.0f / (float)(hi - lo) : 1.0f;
        uint4 o;
        o.x = (unsigned int)f2bf(a[0] * rd) | ((unsigned int)f2bf(a[1] * rd) << 16);
        o.y = (unsigned int)f2bf(a[2] * rd) | ((unsigned int)f2bf(a[3] * rd) << 16);
        o.z = (unsigned int)f2bf(a[4] * rd) | ((unsigned int)f2bf(a[5] * rd) << 16);
        o.w = (unsigned int)f2bf(a[6] * rd) | ((unsigned int)f2bf(a[7] * rd) << 16);
        *reinterpret_cast<uint4*>(&hn[(size_t)node * DIM + l16 * 8]) = o;
    }
}

// ---------------- MFMA GEMM: C[N][128] = [Ab|Hb] @ WT^T, fp32 out ----------------

__global__ __launch_bounds__(256) void gemm_mfma_kernel(const unsigned short* __restrict__ Ab,
                                                        const unsigned short* __restrict__ Hb,
                                                        const unsigned short* __restrict__ WT,
                                                        float* __restrict__ C) {
    __shared__ unsigned short wt[32768];  // 64 KB, [n][k] bf16, XOR-swizzled
    const int tid = threadIdx.x;

#pragma unroll
    for (int i = 0; i < 16; ++i) {
        int c = i * 256 + tid;
        int n = c >> 5;
        unsigned int waddr = ((unsigned int)(c * 16)) ^ (((unsigned int)(n & 7)) << 4);
        uint4 v = *reinterpret_cast<const uint4*>(&WT[c * 8]);
        *reinterpret_cast<uint4*>(reinterpret_cast<char*>(wt) + waddr) = v;
    }
    __syncthreads();

    const int wid = tid >> 6;
    const int lane = tid & 63;
    const int lrow = lane & 15;
    const int g = lane >> 4;
    const int r0 = blockIdx.x * 128 + wid * 32;

    f32x4_t acc[2][8];
#pragma unroll
    for (int mt = 0; mt < 2; ++mt)
#pragma unroll
        for (int nt = 0; nt < 8; ++nt) acc[mt][nt] = (f32x4_t){0.f, 0.f, 0.f, 0.f};

#pragma unroll
    for (int ks = 0; ks < 8; ++ks) {
        const unsigned short* __restrict__ base = (ks < 4) ? Ab : Hb;
        const int kk = (ks & 3) * 32 + g * 8;
        bf16x8_t a[2];
#pragma unroll
        for (int mt = 0; mt < 2; ++mt) {
            int row = r0 + mt * 16 + lrow;
            if (row >= N_NODES) row = N_NODES - 1;
            a[mt] = *reinterpret_cast<const bf16x8_t*>(&base[(size_t)row * DIM + kk]);
        }
#pragma unroll
        for (int nt = 0; nt < 8; ++nt) {
            int n = nt * 16 + lrow;
            unsigned int raddr = ((unsigned int)(n * 512 + ks * 64 + g * 16)) ^ (((unsigned int)(n & 7)) << 4);
            bf16x8_t b = *reinterpret_cast<const bf16x8_t*>(reinterpret_cast<const char*>(wt) + raddr);
            acc[0][nt] = __builtin_amdgcn_mfma_f32_16x16x32_bf16(a[0], b, acc[0][nt], 0, 0, 0);
            acc[1][nt] = __builtin_amdgcn_mfma_f32_16x16x32_bf16(a[1], b, acc[1][nt], 0, 0, 0);
        }
    }

#pragma unroll
    for (int mt = 0; mt < 2; ++mt) {
#pragma unroll
        for (int j = 0; j < 4; ++j) {
            int row = r0 + mt * 16 + g * 4 + j;
            if (row < N_NODES) {
#pragma unroll
                for (int nt = 0; nt < 8; ++nt)
                    C[(size_t)row * DIM + nt * 16 + lrow] = acc[mt][nt][j];
            }
        }
    }
}

// ---------------- BatchNorm stats ----------------

__global__ __launch_bounds__(256) void bn_stats_kernel(const float* __restrict__ H,
                                                       float* __restrict__ bnsum,
                                                       float* __restrict__ bnsq) {
    int c = threadIdx.x & 127;
    int half = threadIdx.x >> 7;
    float s = 0.f, q = 0.f;
    for (int r = blockIdx.x * 2 + half; r < N_NODES; r += gridDim.x * 2) {
        float v = H[(size_t)r * DIM + c];
        s += v; q += v * v;
    }
    __shared__ float ls[256], lq[256];
    ls[threadIdx.x] = s; lq[threadIdx.x] = q;
    __syncthreads();
    if (half == 0) {
        s = ls[threadIdx.x] + ls[threadIdx.x + 128];
        q = lq[threadIdx.x] + lq[threadIdx.x + 128];
        atomicAdd(&bnsum[c], s);
        atomicAdd(&bnsq[c], q);
    }
}

// ---------------- BatchNorm apply + ReLU, fp32 in -> bf16 out ----------------

__global__ __launch_bounds__(256) void bn_apply_bf16_kernel(const float* __restrict__ H,
                                                            const float* __restrict__ bnsum,
                                                            const float* __restrict__ bnsq,
                                                            const float* __restrict__ gamma,
                                                            const float* __restrict__ beta,
                                                            unsigned short* __restrict__ Hb) {
    size_t idx = (size_t)(blockIdx.x * blockDim.x + threadIdx.x) * 4;
    const float invN = 1.0f / (float)N_NODES;
    int c = (int)(idx & (DIM - 1));
    float4 v = *reinterpret_cast<const float4*>(&H[idx]);
    float o[4] = {v.x, v.y, v.z, v.w};
    ushort4 ob;
#pragma unroll
    for (int j = 0; j < 4; ++j) {
        int cj = c + j;
        float mean = bnsum[cj] * invN;
        float var = bnsq[cj] * invN - mean * mean;
        float scale = gamma[cj] * rsqrtf(var + BN_EPS);
        float val = (o[j] - mean) * scale + beta[cj];
        o[j] = val > 0.f ? val : 0.f;
    }
    ob.x = f2bf(o[0]); ob.y = f2bf(o[1]); ob.z = f2bf(o[2]); ob.w = f2bf(o[3]);
    *reinterpret_cast<ushort4*>(&Hb[idx]) = ob;
}

// ---------------- output layer (MFMA): C[N][40] = [Ab|Hb] @ WT2^T + b ----------------

__global__ __launch_bounds__(256) void gemm_out_mfma_kernel(const unsigned short* __restrict__ Ab,
                                                            const unsigned short* __restrict__ Hb,
                                                            const unsigned short* __restrict__ WT2,
                                                            const float* __restrict__ bias,
                                                            float* __restrict__ C) {
    __shared__ unsigned short wt[OUTP * 256];  // 24 KB, XOR-swizzled
    const int tid = threadIdx.x;

#pragma unroll
    for (int i = 0; i < 6; ++i) {
        int c = i * 256 + tid;               // 16B chunks: 0..1535
        int n = c >> 5;
        unsigned int waddr = ((unsigned int)(c * 16)) ^ (((unsigned int)(n & 7)) << 4);
        uint4 v = *reinterpret_cast<const uint4*>(&WT2[c * 8]);
        *reinterpret_cast<uint4*>(reinterpret_cast<char*>(wt) + waddr) = v;
    }
    __syncthreads();

    const int wid = tid >> 6;
    const int lane = tid & 63;
    const int lrow = lane & 15;
    const int g = lane >> 4;
    const int r0 = blockIdx.x * 128 + wid * 32;

    f32x4_t acc[2][3];
#pragma unroll
    for (int mt = 0; mt < 2; ++mt)
#pragma unroll
        for (int nt = 0; nt < 3; ++nt) acc[mt][nt] = (f32x4_t){0.f, 0.f, 0.f, 0.f};

#pragma unroll
    for (int ks = 0; ks < 8; ++ks) {
        const unsigned short* __restrict__ base = (ks < 4) ? Ab : Hb;
        const int kk = (ks & 3) * 32 + g * 8;
        bf16x8_t a[2];
#pragma unroll
        for (int mt = 0; mt < 2; ++mt) {
            int row = r0 + mt * 16 + lrow;
            if (row >= N_NODES) row = N_NODES - 1;
            a[mt] = *reinterpret_cast<const bf16x8_t*>(&base[(size_t)row * DIM + kk]);
        }
#pragma unroll
        for (int nt = 0; nt < 3; ++nt) {
            int n = nt * 16 + lrow;
            unsigned int raddr = ((unsigned int)(n * 512 + ks * 64 + g * 16)) ^ (((unsigned int)(n & 7)) << 4);
            bf16x8_t b = *reinterpret_cast<const bf16x8_t*>(reinterpret_cast<const char*>(wt) + raddr);
            acc[0][nt] = __builtin_amdgcn_mfma_f32_16x16x32_bf16(a[0], b, acc[0][nt], 0, 0, 0);
            acc[1][nt] = __builtin_amdgcn_mfma_f32_16x16x32_bf16(a[1], b, acc[1][nt], 0, 0, 0);
        }
    }

    float bb[3];
#pragma unroll
    for (int nt = 0; nt < 3; ++nt) {
        int col = nt * 16 + lrow;
        bb[nt] = (col < OUTD) ? bias[col] : 0.f;
    }

#pragma unroll
    for (int mt = 0; mt < 2; ++mt) {
#pragma unroll
        for (int j = 0; j < 4; ++j) {
            int row = r0 + mt * 16 + g * 4 + j;
            if (row < N_NODES) {
#pragma unroll
                for (int nt = 0; nt < 3; ++nt) {
                    int col = nt * 16 + lrow;
                    if (col < OUTD)
                        C[(size_t)row * OUTD + col] = acc[mt][nt][j] + bb[nt];
                }
            }
        }
    }
}

// ---------------- launch ----------------

extern "C" void kernel_launch(void* const* d_in, const int* in_sizes, int n_in,
                              void* d_out, int out_size, void* d_ws, size_t ws_size,
                              hipStream_t stream) {
    const float* feat = (const float*)d_in[0];
    const int* src = (const int*)d_in[1];
    const int* dst = (const int*)d_in[2];
    const float* Ws0 = (const float*)d_in[3];
    const float* Wn0 = (const float*)d_in[4];
    const float* g0  = (const float*)d_in[5];
    const float* be0 = (const float*)d_in[6];
    const float* Ws1 = (const float*)d_in[7];
    const float* Wn1 = (const float*)d_in[8];
    const float* g1  = (const float*)d_in[9];
    const float* be1 = (const float*)d_in[10];
    const float* Ws2 = (const float*)d_in[11];
    const float* Wn2 = (const float*)d_in[12];
    const float* b2  = (const float*)d_in[13];
    float* out = (float*)d_out;

    char* ws = (char*)d_ws;
    int*   deg     = (int*)(ws);                       // 400000 B (zeroed)
    int*   cursor  = (int*)(ws + 400000);              // 400000 B (zeroed)
    float* bn      = (float*)(ws + 800000);            // 2048 B   (zeroed)
    int*   row_off = (int*)(ws + 802048);              // 400004 B
    int*   csr     = (int*)(ws + 1202176);             // 3200000 B
    unsigned short* featb = (unsigned short*)(ws + 4402176);   // 25.6 MB (reused as h1b)
    unsigned short* hnb   = (unsigned short*)(ws + 30002176);  // 25.6 MB
    unsigned short* h0b   = (unsigned short*)(ws + 55602176);  // 25.6 MB
    float*          hf    = (float*)(ws + 81202176);           // 51.2 MB fp32 gemm out
    unsigned short* WT0   = (unsigned short*)(ws + 132402176); // 65536 B
    unsigned short* WT1   = (unsigned short*)(ws + 132467712); // 65536 B
    int*   partials = (int*)(ws + 132533248);                  // 512 B
    unsigned short* WT2   = (unsigned short*)(ws + 132533760); // 24576 B
    unsigned short* h1b   = featb;  // featb dead after layer-0 gemm

    hipMemsetAsync(ws, 0, 802048, stream);

    const int EB = (N_EDGES + 255) / 256;        // 3125
    const int AB = (N_NODES + 3) / 4;            // 25000
    const int MB = (N_NODES + 127) / 128;        // 782
    const int NE = (N_NODES * DIM) / 4 / 256;    // 12500

    deg_kernel<<<EB, 256, 0, stream>>>(dst, deg);
    scan_partial_kernel<<<SCAN_NB, 256, 0, stream>>>(deg, partials);
    scan_partials_kernel<<<1, 128, 0, stream>>>(partials);
    scan_final_kernel<<<SCAN_NB, 256, 0, stream>>>(deg, partials, row_off);
    fill_kernel<<<EB, 256, 0, stream>>>(src, dst, row_off, cursor, csr);

    convert_bf16_kernel<<<NE, 256, 0, stream>>>(feat, featb);
    wt_build_kernel<<<256, 256, 0, stream>>>(Ws0, Wn0, Ws1, Wn1, WT0, WT1);
    wt2_build_kernel<<<48, 256, 0, stream>>>(Ws2, Wn2, WT2);

    // layer 0
    agg_bf16_kernel<<<AB, 256, 0, stream>>>(featb, row_off, csr, hnb);
    gemm_mfma_kernel<<<MB, 256, 0, stream>>>(featb, hnb, WT0, hf);
    bn_stats_kernel<<<1024, 256, 0, stream>>>(hf, bn + 0, bn + 128);
    bn_apply_bf16_kernel<<<NE, 256, 0, stream>>>(hf, bn + 0, bn + 128, g0, be0, h0b);

    // layer 1
    agg_bf16_kernel<<<AB, 256, 0, stream>>>(h0b, row_off, csr, hnb);
    gemm_mfma_kernel<<<MB, 256, 0, stream>>>(h0b, hnb, WT1, hf);
    bn_stats_kernel<<<1024, 256, 0, stream>>>(hf, bn + 256, bn + 384);
    bn_apply_bf16_kernel<<<NE, 256, 0, stream>>>(hf, bn + 256, bn + 384, g1, be1, h1b);

    // layer 2
    agg_bf16_kernel<<<AB, 256, 0, stream>>>(h1b, row_off, csr, hnb);
    gemm_out_mfma_kernel<<<MB, 256, 0, stream>>>(h1b, hnb, WT2, b2, out);
}

// Round 7
// 326.469 us; speedup vs baseline: 29.4902x; 1.1745x over previous
//
#include <hip/hip_runtime.h>

#define N_NODES 100000
#define N_EDGES 800000
#define DIM 128
#define OUTD 40
#define OUTP 48  // padded to 3x16 MFMA col-tiles
#define BN_EPS 1e-5f
#define SCAN_NB 98  // ceil(100000/1024)

typedef __bf16 bf16x8_t __attribute__((ext_vector_type(8)));
typedef float f32x4_t __attribute__((ext_vector_type(4)));

__device__ __forceinline__ unsigned short f2bf(float f) {
    unsigned int u = __builtin_bit_cast(unsigned int, f);
    u = (u + 0x7FFF + ((u >> 16) & 1)) >> 16;
    return (unsigned short)u;
}

// ---------------- CSR build ----------------

__global__ void deg_kernel(const int* __restrict__ dst, int* __restrict__ deg) {
    int e = blockIdx.x * blockDim.x + threadIdx.x;
    if (e < N_EDGES) atomicAdd(&deg[dst[e]], 1);
}

__global__ __launch_bounds__(256) void scan_partial_kernel(const int* __restrict__ deg,
                                                           int* __restrict__ partials) {
    int b = blockIdx.x;
    int tid = threadIdx.x;
    int base = b * 1024 + tid * 4;
    int t0 = 0, t1 = 0, t2 = 0, t3 = 0;
    if (base + 3 < N_NODES) {
        int4 v = *reinterpret_cast<const int4*>(&deg[base]);
        t0 = v.x; t1 = v.y; t2 = v.z; t3 = v.w;
    } else {
        if (base + 0 < N_NODES) t0 = deg[base + 0];
        if (base + 1 < N_NODES) t1 = deg[base + 1];
        if (base + 2 < N_NODES) t2 = deg[base + 2];
        if (base + 3 < N_NODES) t3 = deg[base + 3];
    }
    int s = t0 + t1 + t2 + t3;
    __shared__ int red[256];
    red[tid] = s;
    __syncthreads();
    for (int o = 128; o; o >>= 1) {
        if (tid < o) red[tid] += red[tid + o];
        __syncthreads();
    }
    if (tid == 0) partials[b] = red[0];
}

__global__ __launch_bounds__(128) void scan_partials_kernel(int* __restrict__ partials) {
    __shared__ int s[128];
    int t = threadIdx.x;
    int v = (t < SCAN_NB) ? partials[t] : 0;
    s[t] = v;
    __syncthreads();
    for (int off = 1; off < 128; off <<= 1) {
        int u = (t >= off) ? s[t - off] : 0;
        __syncthreads();
        s[t] += u;
        __syncthreads();
    }
    if (t < SCAN_NB) partials[t] = s[t] - v;  // exclusive
}

__global__ __launch_bounds__(256) void scan_final_kernel(const int* __restrict__ deg,
                                                         const int* __restrict__ partials,
                                                         int* __restrict__ row_off) {
    int b = blockIdx.x;
    int tid = threadIdx.x;
    int base = b * 1024 + tid * 4;
    int t0 = 0, t1 = 0, t2 = 0, t3 = 0;
    if (base + 3 < N_NODES) {
        int4 v = *reinterpret_cast<const int4*>(&deg[base]);
        t0 = v.x; t1 = v.y; t2 = v.z; t3 = v.w;
    } else {
        if (base + 0 < N_NODES) t0 = deg[base + 0];
        if (base + 1 < N_NODES) t1 = deg[base + 1];
        if (base + 2 < N_NODES) t2 = deg[base + 2];
        if (base + 3 < N_NODES) t3 = deg[base + 3];
    }
    int s = t0 + t1 + t2 + t3;
    __shared__ int sc[256];
    sc[tid] = s;
    __syncthreads();
    for (int off = 1; off < 256; off <<= 1) {
        int u = (tid >= off) ? sc[tid - off] : 0;
        __syncthreads();
        sc[tid] += u;
        __syncthreads();
    }
    int run = partials[b] + sc[tid] - s;
    if (base + 0 < N_NODES) row_off[base + 0] = run; run += t0;
    if (base + 1 < N_NODES) row_off[base + 1] = run; run += t1;
    if (base + 2 < N_NODES) row_off[base + 2] = run; run += t2;
    if (base + 3 < N_NODES) row_off[base + 3] = run;
    if (b == 0 && tid == 0) row_off[N_NODES] = N_EDGES;
}

__global__ void fill_kernel(const int* __restrict__ src, const int* __restrict__ dst,
                            const int* __restrict__ row_off, int* __restrict__ cursor,
                            int* __restrict__ csr_src) {
    int e = blockIdx.x * blockDim.x + threadIdx.x;
    if (e < N_EDGES) {
        int d = dst[e];
        int p = atomicAdd(&cursor[d], 1);
        csr_src[row_off[d] + p] = src[e];
    }
}

// ---------------- fp32 -> bf16 convert (feat) ----------------

__global__ __launch_bounds__(256) void convert_bf16_kernel(const float* __restrict__ in,
                                                           unsigned short* __restrict__ out) {
    size_t i = (size_t)(blockIdx.x * blockDim.x + threadIdx.x) * 4;
    float4 v = *reinterpret_cast<const float4*>(&in[i]);
    ushort4 o;
    o.x = f2bf(v.x); o.y = f2bf(v.y); o.z = f2bf(v.z); o.w = f2bf(v.w);
    *reinterpret_cast<ushort4*>(&out[i]) = o;
}

// ---------------- weight transpose+convert: WT[n][k] = W[k][n], bf16 ----------------

__global__ __launch_bounds__(256) void wt_build_kernel(const float* __restrict__ Ws0,
                                                       const float* __restrict__ Wn0,
                                                       const float* __restrict__ Ws1,
                                                       const float* __restrict__ Wn1,
                                                       unsigned short* __restrict__ WT0,
                                                       unsigned short* __restrict__ WT1) {
    int e = blockIdx.x * blockDim.x + threadIdx.x;  // 0..65535
    int layer = e >> 15;
    int r = e & 32767;
    int n = r >> 8;
    int k = r & 255;
    const float* Ws = layer ? Ws1 : Ws0;
    const float* Wn = layer ? Wn1 : Wn0;
    float v = (k < DIM) ? Ws[k * DIM + n] : Wn[(k - DIM) * DIM + n];
    unsigned short* WT = layer ? WT1 : WT0;
    WT[n * 256 + k] = f2bf(v);
}

// WT2[n][k], n in [0,48), zero-padded beyond OUTD
__global__ __launch_bounds__(256) void wt2_build_kernel(const float* __restrict__ Ws2,
                                                        const float* __restrict__ Wn2,
                                                        unsigned short* __restrict__ WT2) {
    int e = blockIdx.x * blockDim.x + threadIdx.x;  // 0..12287
    int n = e >> 8;
    int k = e & 255;
    float v = 0.f;
    if (n < OUTD) v = (k < DIM) ? Ws2[k * OUTD + n] : Wn2[(k - DIM) * OUTD + n];
    WT2[n * 256 + k] = f2bf(v);
}

// ---------------- mean aggregation v3b ----------------
// wave per node; indices loaded coalesced (one load / 64 neighbors) and
// shfl-broadcast from CONVERGED code (uniform trip count; loads predicated).
// 4x16-lane groups each gather full 256B rows, up to 8 rows in flight.

__device__ __forceinline__ void unpack_add(float* a, uint4 v) {
    a[0] += __builtin_bit_cast(float, v.x << 16);
    a[1] += __builtin_bit_cast(float, v.x & 0xFFFF0000u);
    a[2] += __builtin_bit_cast(float, v.y << 16);
    a[3] += __builtin_bit_cast(float, v.y & 0xFFFF0000u);
    a[4] += __builtin_bit_cast(float, v.z << 16);
    a[5] += __builtin_bit_cast(float, v.z & 0xFFFF0000u);
    a[6] += __builtin_bit_cast(float, v.w << 16);
    a[7] += __builtin_bit_cast(float, v.w & 0xFFFF0000u);
}

__global__ __launch_bounds__(256) void agg_bf16_kernel(const unsigned short* __restrict__ h,
                                                       const int* __restrict__ row_off,
                                                       const int* __restrict__ csr_src,
                                                       unsigned short* __restrict__ hn) {
    int wave = threadIdx.x >> 6;
    int lane = threadIdx.x & 63;
    int node = blockIdx.x * 4 + wave;
    if (node >= N_NODES) return;  // whole wave uniform
    int lo = row_off[node], hi = row_off[node + 1];
    const int grp = lane >> 4;   // 0..3: neighbor sub-slot
    const int l16 = lane & 15;   // 16B slice of the row
    float a[8] = {0.f, 0.f, 0.f, 0.f, 0.f, 0.f, 0.f, 0.f};
    for (int base = lo; base < hi; base += 64) {      // uniform per wave
        int cnt = hi - base; if (cnt > 64) cnt = 64;  // uniform
        int li = (lane < cnt) ? lane : (cnt - 1);
        int idx = csr_src[base + li];  // defined on EVERY lane (clamped)
        int nIter = (cnt + 7) >> 3;    // uniform trip count -> converged shfls
        for (int k = 0; k < nIter; ++k) {
            int t0 = k * 8 + grp;              // <= 59
            int s0 = __shfl(idx, t0, 64);      // all 64 lanes execute
            int s1 = __shfl(idx, t0 + 4, 64);  // <= 63
            if (t0 < cnt) {
                uint4 v0 = *reinterpret_cast<const uint4*>(&h[(size_t)s0 * DIM + l16 * 8]);
                unpack_add(a, v0);
            }
            if (t0 + 4 < cnt) {
                uint4 v1 = *reinterpret_cast<const uint4*>(&h[(size_t)s1 * DIM + l16 * 8]);
                unpack_add(a, v1);
            }
        }
    }
    // converged butterfly across the 4 groups
#pragma unroll
    for (int q = 0; q < 8; ++q) {
        a[q] += __shfl_xor(a[q], 16, 64);
        a[q] += __shfl_xor(a[q], 32, 64);
    }
    if (grp == 0) {
        float rd = (hi > lo) ? 1.0f / (float)(hi - lo) : 1.0f;
        uint4 o;
        o.x = (unsigned int)f2bf(a[0] * rd) | ((unsigned int)f2bf(a[1] * rd) << 16);
        o.y = (unsigned int)f2bf(a[2] * rd) | ((unsigned int)f2bf(a[3] * rd) << 16);
        o.z = (unsigned int)f2bf(a[4] * rd) | ((unsigned int)f2bf(a[5] * rd) << 16);
        o.w = (unsigned int)f2bf(a[6] * rd) | ((unsigned int)f2bf(a[7] * rd) << 16);
        *reinterpret_cast<uint4*>(&hn[(size_t)node * DIM + l16 * 8]) = o;
    }
}

// ---------------- MFMA GEMM + fused BN column stats ----------------
// C[N][128] = [Ab|Hb] @ WT^T (fp32 out); per-block column sum/sumsq
// reduced in-register + LDS (aliased over wt, barrier-ordered) ->
// one atomicAdd per column per block. All shfls in converged code.

__global__ __launch_bounds__(256) void gemm_mfma_kernel(const unsigned short* __restrict__ Ab,
                                                        const unsigned short* __restrict__ Hb,
                                                        const unsigned short* __restrict__ WT,
                                                        float* __restrict__ C,
                                                        float* __restrict__ bnsum,
                                                        float* __restrict__ bnsq) {
    __shared__ unsigned short wt[32768];  // 64 KB, [n][k] bf16, XOR-swizzled
    const int tid = threadIdx.x;

#pragma unroll
    for (int i = 0; i < 16; ++i) {
        int c = i * 256 + tid;
        int n = c >> 5;
        unsigned int waddr = ((unsigned int)(c * 16)) ^ (((unsigned int)(n & 7)) << 4);
        uint4 v = *reinterpret_cast<const uint4*>(&WT[c * 8]);
        *reinterpret_cast<uint4*>(reinterpret_cast<char*>(wt) + waddr) = v;
    }
    __syncthreads();

    const int wid = tid >> 6;
    const int lane = tid & 63;
    const int lrow = lane & 15;
    const int g = lane >> 4;
    const int r0 = blockIdx.x * 128 + wid * 32;

    f32x4_t acc[2][8];
#pragma unroll
    for (int mt = 0; mt < 2; ++mt)
#pragma unroll
        for (int nt = 0; nt < 8; ++nt) acc[mt][nt] = (f32x4_t){0.f, 0.f, 0.f, 0.f};

#pragma unroll
    for (int ks = 0; ks < 8; ++ks) {
        const unsigned short* __restrict__ base = (ks < 4) ? Ab : Hb;
        const int kk = (ks & 3) * 32 + g * 8;
        bf16x8_t a[2];
#pragma unroll
        for (int mt = 0; mt < 2; ++mt) {
            int row = r0 + mt * 16 + lrow;
            if (row >= N_NODES) row = N_NODES - 1;
            a[mt] = *reinterpret_cast<const bf16x8_t*>(&base[(size_t)row * DIM + kk]);
        }
#pragma unroll
        for (int nt = 0; nt < 8; ++nt) {
            int n = nt * 16 + lrow;
            unsigned int raddr = ((unsigned int)(n * 512 + ks * 64 + g * 16)) ^ (((unsigned int)(n & 7)) << 4);
            bf16x8_t b = *reinterpret_cast<const bf16x8_t*>(reinterpret_cast<const char*>(wt) + raddr);
            acc[0][nt] = __builtin_amdgcn_mfma_f32_16x16x32_bf16(a[0], b, acc[0][nt], 0, 0, 0);
            acc[1][nt] = __builtin_amdgcn_mfma_f32_16x16x32_bf16(a[1], b, acc[1][nt], 0, 0, 0);
        }
    }

    // ---- fused BN stats ----
    float ssum[8], ssq[8];
#pragma unroll
    for (int nt = 0; nt < 8; ++nt) { ssum[nt] = 0.f; ssq[nt] = 0.f; }
#pragma unroll
    for (int mt = 0; mt < 2; ++mt) {
#pragma unroll
        for (int j = 0; j < 4; ++j) {
            int row = r0 + mt * 16 + g * 4 + j;
            if (row < N_NODES) {
#pragma unroll
                for (int nt = 0; nt < 8; ++nt) {
                    float v = acc[mt][nt][j];
                    ssum[nt] += v;
                    ssq[nt] += v * v;
                }
            }
        }
    }
#pragma unroll
    for (int nt = 0; nt < 8; ++nt) {  // converged butterfly over row-groups
        ssum[nt] += __shfl_xor(ssum[nt], 16, 64);
        ssum[nt] += __shfl_xor(ssum[nt], 32, 64);
        ssq[nt] += __shfl_xor(ssq[nt], 16, 64);
        ssq[nt] += __shfl_xor(ssq[nt], 32, 64);
    }
    __syncthreads();  // all waves done reading wt -> safe to alias
    float* ls = reinterpret_cast<float*>(wt);        // [4][128]
    float* lq = ls + 512;                            // [4][128]
    if (g == 0) {
#pragma unroll
        for (int nt = 0; nt < 8; ++nt) {
            ls[wid * 128 + nt * 16 + lrow] = ssum[nt];
            lq[wid * 128 + nt * 16 + lrow] = ssq[nt];
        }
    }
    __syncthreads();
    if (tid < 128) {
        float s = ls[tid] + ls[128 + tid] + ls[256 + tid] + ls[384 + tid];
        float q = lq[tid] + lq[128 + tid] + lq[256 + tid] + lq[384 + tid];
        atomicAdd(&bnsum[tid], s);
        atomicAdd(&bnsq[tid], q);
    }

    // ---- C write ----
#pragma unroll
    for (int mt = 0; mt < 2; ++mt) {
#pragma unroll
        for (int j = 0; j < 4; ++j) {
            int row = r0 + mt * 16 + g * 4 + j;
            if (row < N_NODES) {
#pragma unroll
                for (int nt = 0; nt < 8; ++nt)
                    C[(size_t)row * DIM + nt * 16 + lrow] = acc[mt][nt][j];
            }
        }
    }
}

// ---------------- BatchNorm apply + ReLU, fp32 in -> bf16 out ----------------

__global__ __launch_bounds__(256) void bn_apply_bf16_kernel(const float* __restrict__ H,
                                                            const float* __restrict__ bnsum,
                                                            const float* __restrict__ bnsq,
                                                            const float* __restrict__ gamma,
                                                            const float* __restrict__ beta,
                                                            unsigned short* __restrict__ Hb) {
    size_t idx = (size_t)(blockIdx.x * blockDim.x + threadIdx.x) * 4;
    const float invN = 1.0f / (float)N_NODES;
    int c = (int)(idx & (DIM - 1));
    float4 v = *reinterpret_cast<const float4*>(&H[idx]);
    float o[4] = {v.x, v.y, v.z, v.w};
    ushort4 ob;
#pragma unroll
    for (int j = 0; j < 4; ++j) {
        int cj = c + j;
        float mean = bnsum[cj] * invN;
        float var = bnsq[cj] * invN - mean * mean;
        float scale = gamma[cj] * rsqrtf(var + BN_EPS);
        float val = (o[j] - mean) * scale + beta[cj];
        o[j] = val > 0.f ? val : 0.f;
    }
    ob.x = f2bf(o[0]); ob.y = f2bf(o[1]); ob.z = f2bf(o[2]); ob.w = f2bf(o[3]);
    *reinterpret_cast<ushort4*>(&Hb[idx]) = ob;
}

// ---------------- output layer (MFMA): C[N][40] = [Ab|Hb] @ WT2^T + b ----------------

__global__ __launch_bounds__(256) void gemm_out_mfma_kernel(const unsigned short* __restrict__ Ab,
                                                            const unsigned short* __restrict__ Hb,
                                                            const unsigned short* __restrict__ WT2,
                                                            const float* __restrict__ bias,
                                                            float* __restrict__ C) {
    __shared__ unsigned short wt[OUTP * 256];  // 24 KB, XOR-swizzled
    const int tid = threadIdx.x;

#pragma unroll
    for (int i = 0; i < 6; ++i) {
        int c = i * 256 + tid;               // 16B chunks: 0..1535
        int n = c >> 5;
        unsigned int waddr = ((unsigned int)(c * 16)) ^ (((unsigned int)(n & 7)) << 4);
        uint4 v = *reinterpret_cast<const uint4*>(&WT2[c * 8]);
        *reinterpret_cast<uint4*>(reinterpret_cast<char*>(wt) + waddr) = v;
    }
    __syncthreads();

    const int wid = tid >> 6;
    const int lane = tid & 63;
    const int lrow = lane & 15;
    const int g = lane >> 4;
    const int r0 = blockIdx.x * 128 + wid * 32;

    f32x4_t acc[2][3];
#pragma unroll
    for (int mt = 0; mt < 2; ++mt)
#pragma unroll
        for (int nt = 0; nt < 3; ++nt) acc[mt][nt] = (f32x4_t){0.f, 0.f, 0.f, 0.f};

#pragma unroll
    for (int ks = 0; ks < 8; ++ks) {
        const unsigned short* __restrict__ base = (ks < 4) ? Ab : Hb;
        const int kk = (ks & 3) * 32 + g * 8;
        bf16x8_t a[2];
#pragma unroll
        for (int mt = 0; mt < 2; ++mt) {
            int row = r0 + mt * 16 + lrow;
            if (row >= N_NODES) row = N_NODES - 1;
            a[mt] = *reinterpret_cast<const bf16x8_t*>(&base[(size_t)row * DIM + kk]);
        }
#pragma unroll
        for (int nt = 0; nt < 3; ++nt) {
            int n = nt * 16 + lrow;
            unsigned int raddr = ((unsigned int)(n * 512 + ks * 64 + g * 16)) ^ (((unsigned int)(n & 7)) << 4);
            bf16x8_t b = *reinterpret_cast<const bf16x8_t*>(reinterpret_cast<const char*>(wt) + raddr);
            acc[0][nt] = __builtin_amdgcn_mfma_f32_16x16x32_bf16(a[0], b, acc[0][nt], 0, 0, 0);
            acc[1][nt] = __builtin_amdgcn_mfma_f32_16x16x32_bf16(a[1], b, acc[1][nt], 0, 0, 0);
        }
    }

    float bb[3];
#pragma unroll
    for (int nt = 0; nt < 3; ++nt) {
        int col = nt * 16 + lrow;
        bb[nt] = (col < OUTD) ? bias[col] : 0.f;
    }

#pragma unroll
    for (int mt = 0; mt < 2; ++mt) {
#pragma unroll
        for (int j = 0; j < 4; ++j) {
            int row = r0 + mt * 16 + g * 4 + j;
            if (row < N_NODES) {
#pragma unroll
                for (int nt = 0; nt < 3; ++nt) {
                    int col = nt * 16 + lrow;
                    if (col < OUTD)
                        C[(size_t)row * OUTD + col] = acc[mt][nt][j] + bb[nt];
                }
            }
        }
    }
}

// ---------------- launch ----------------

extern "C" void kernel_launch(void* const* d_in, const int* in_sizes, int n_in,
                              void* d_out, int out_size, void* d_ws, size_t ws_size,
                              hipStream_t stream) {
    const float* feat = (const float*)d_in[0];
    const int* src = (const int*)d_in[1];
    const int* dst = (const int*)d_in[2];
    const float* Ws0 = (const float*)d_in[3];
    const float* Wn0 = (const float*)d_in[4];
    const float* g0  = (const float*)d_in[5];
    const float* be0 = (const float*)d_in[6];
    const float* Ws1 = (const float*)d_in[7];
    const float* Wn1 = (const float*)d_in[8];
    const float* g1  = (const float*)d_in[9];
    const float* be1 = (const float*)d_in[10];
    const float* Ws2 = (const float*)d_in[11];
    const float* Wn2 = (const float*)d_in[12];
    const float* b2  = (const float*)d_in[13];
    float* out = (float*)d_out;

    char* ws = (char*)d_ws;
    int*   deg     = (int*)(ws);                       // 400000 B (zeroed)
    int*   cursor  = (int*)(ws + 400000);              // 400000 B (zeroed)
    float* bn      = (float*)(ws + 800000);            // 2048 B   (zeroed)
    int*   row_off = (int*)(ws + 802048);              // 400004 B
    int*   csr     = (int*)(ws + 1202176);             // 3200000 B
    unsigned short* featb = (unsigned short*)(ws + 4402176);   // 25.6 MB (reused as h1b)
    unsigned short* hnb   = (unsigned short*)(ws + 30002176);  // 25.6 MB
    unsigned short* h0b   = (unsigned short*)(ws + 55602176);  // 25.6 MB
    float*          hf    = (float*)(ws + 81202176);           // 51.2 MB fp32 gemm out
    unsigned short* WT0   = (unsigned short*)(ws + 132402176); // 65536 B
    unsigned short* WT1   = (unsigned short*)(ws + 132467712); // 65536 B
    int*   partials = (int*)(ws + 132533248);                  // 512 B
    unsigned short* WT2   = (unsigned short*)(ws + 132533760); // 24576 B
    unsigned short* h1b   = featb;  // featb dead after layer-0 gemm

    hipMemsetAsync(ws, 0, 802048, stream);

    const int EB = (N_EDGES + 255) / 256;        // 3125
    const int AB = (N_NODES + 3) / 4;            // 25000
    const int MB = (N_NODES + 127) / 128;        // 782
    const int NE = (N_NODES * DIM) / 4 / 256;    // 12500

    deg_kernel<<<EB, 256, 0, stream>>>(dst, deg);
    scan_partial_kernel<<<SCAN_NB, 256, 0, stream>>>(deg, partials);
    scan_partials_kernel<<<1, 128, 0, stream>>>(partials);
    scan_final_kernel<<<SCAN_NB, 256, 0, stream>>>(deg, partials, row_off);
    fill_kernel<<<EB, 256, 0, stream>>>(src, dst, row_off, cursor, csr);

    convert_bf16_kernel<<<NE, 256, 0, stream>>>(feat, featb);
    wt_build_kernel<<<256, 256, 0, stream>>>(Ws0, Wn0, Ws1, Wn1, WT0, WT1);
    wt2_build_kernel<<<48, 256, 0, stream>>>(Ws2, Wn2, WT2);

    // layer 0
    agg_bf16_kernel<<<AB, 256, 0, stream>>>(featb, row_off, csr, hnb);
    gemm_mfma_kernel<<<MB, 256, 0, stream>>>(featb, hnb, WT0, hf, bn + 0, bn + 128);
    bn_apply_bf16_kernel<<<NE, 256, 0, stream>>>(hf, bn + 0, bn + 128, g0, be0, h0b);

    // layer 1
    agg_bf16_kernel<<<AB, 256, 0, stream>>>(h0b, row_off, csr, hnb);
    gemm_mfma_kernel<<<MB, 256, 0, stream>>>(h0b, hnb, WT1, hf, bn + 256, bn + 384);
    bn_apply_bf16_kernel<<<NE, 256, 0, stream>>>(hf, bn + 256, bn + 384, g1, be1, h1b);

    // layer 2
    agg_bf16_kernel<<<AB, 256, 0, stream>>>(h1b, row_off, csr, hnb);
    gemm_out_mfma_kernel<<<MB, 256, 0, stream>>>(h1b, hnb, WT2, b2, out);
}

// Round 8
// 319.576 us; speedup vs baseline: 30.1263x; 1.0216x over previous
//
#include <hip/hip_runtime.h>

#define N_NODES 100000
#define N_EDGES 800000
#define DIM 128
#define OUTD 40
#define OUTP 48  // padded to 3x16 MFMA col-tiles
#define BN_EPS 1e-5f
#define SCAN_NB 98  // ceil(100000/1024)

typedef __bf16 bf16x8_t __attribute__((ext_vector_type(8)));
typedef float f32x4_t __attribute__((ext_vector_type(4)));

__device__ __forceinline__ unsigned short f2bf(float f) {
    unsigned int u = __builtin_bit_cast(unsigned int, f);
    u = (u + 0x7FFF + ((u >> 16) & 1)) >> 16;
    return (unsigned short)u;
}
__device__ __forceinline__ float bf2f(unsigned short b) {
    return __builtin_bit_cast(float, (unsigned int)b << 16);
}

// ---------------- CSR build ----------------

__global__ void deg_kernel(const int* __restrict__ dst, int* __restrict__ deg) {
    int e = blockIdx.x * blockDim.x + threadIdx.x;
    if (e < N_EDGES) atomicAdd(&deg[dst[e]], 1);
}

__global__ __launch_bounds__(256) void scan_partial_kernel(const int* __restrict__ deg,
                                                           int* __restrict__ partials) {
    int b = blockIdx.x;
    int tid = threadIdx.x;
    int base = b * 1024 + tid * 4;
    int t0 = 0, t1 = 0, t2 = 0, t3 = 0;
    if (base + 3 < N_NODES) {
        int4 v = *reinterpret_cast<const int4*>(&deg[base]);
        t0 = v.x; t1 = v.y; t2 = v.z; t3 = v.w;
    } else {
        if (base + 0 < N_NODES) t0 = deg[base + 0];
        if (base + 1 < N_NODES) t1 = deg[base + 1];
        if (base + 2 < N_NODES) t2 = deg[base + 2];
        if (base + 3 < N_NODES) t3 = deg[base + 3];
    }
    int s = t0 + t1 + t2 + t3;
    __shared__ int red[256];
    red[tid] = s;
    __syncthreads();
    for (int o = 128; o; o >>= 1) {
        if (tid < o) red[tid] += red[tid + o];
        __syncthreads();
    }
    if (tid == 0) partials[b] = red[0];
}

__global__ __launch_bounds__(128) void scan_partials_kernel(int* __restrict__ partials) {
    __shared__ int s[128];
    int t = threadIdx.x;
    int v = (t < SCAN_NB) ? partials[t] : 0;
    s[t] = v;
    __syncthreads();
    for (int off = 1; off < 128; off <<= 1) {
        int u = (t >= off) ? s[t - off] : 0;
        __syncthreads();
        s[t] += u;
        __syncthreads();
    }
    if (t < SCAN_NB) partials[t] = s[t] - v;  // exclusive
}

__global__ __launch_bounds__(256) void scan_final_kernel(const int* __restrict__ deg,
                                                         const int* __restrict__ partials,
                                                         int* __restrict__ row_off) {
    int b = blockIdx.x;
    int tid = threadIdx.x;
    int base = b * 1024 + tid * 4;
    int t0 = 0, t1 = 0, t2 = 0, t3 = 0;
    if (base + 3 < N_NODES) {
        int4 v = *reinterpret_cast<const int4*>(&deg[base]);
        t0 = v.x; t1 = v.y; t2 = v.z; t3 = v.w;
    } else {
        if (base + 0 < N_NODES) t0 = deg[base + 0];
        if (base + 1 < N_NODES) t1 = deg[base + 1];
        if (base + 2 < N_NODES) t2 = deg[base + 2];
        if (base + 3 < N_NODES) t3 = deg[base + 3];
    }
    int s = t0 + t1 + t2 + t3;
    __shared__ int sc[256];
    sc[tid] = s;
    __syncthreads();
    for (int off = 1; off < 256; off <<= 1) {
        int u = (tid >= off) ? sc[tid - off] : 0;
        __syncthreads();
        sc[tid] += u;
        __syncthreads();
    }
    int run = partials[b] + sc[tid] - s;
    if (base + 0 < N_NODES) row_off[base + 0] = run; run += t0;
    if (base + 1 < N_NODES) row_off[base + 1] = run; run += t1;
    if (base + 2 < N_NODES) row_off[base + 2] = run; run += t2;
    if (base + 3 < N_NODES) row_off[base + 3] = run;
    if (b == 0 && tid == 0) row_off[N_NODES] = N_EDGES;
}

__global__ void fill_kernel(const int* __restrict__ src, const int* __restrict__ dst,
                            const int* __restrict__ row_off, int* __restrict__ cursor,
                            int* __restrict__ csr_src) {
    int e = blockIdx.x * blockDim.x + threadIdx.x;
    if (e < N_EDGES) {
        int d = dst[e];
        int p = atomicAdd(&cursor[d], 1);
        csr_src[row_off[d] + p] = src[e];
    }
}

// ---------------- fp32 -> bf16 convert (feat) ----------------

__global__ __launch_bounds__(256) void convert_bf16_kernel(const float* __restrict__ in,
                                                           unsigned short* __restrict__ out) {
    size_t i = (size_t)(blockIdx.x * blockDim.x + threadIdx.x) * 4;
    float4 v = *reinterpret_cast<const float4*>(&in[i]);
    ushort4 o;
    o.x = f2bf(v.x); o.y = f2bf(v.y); o.z = f2bf(v.z); o.w = f2bf(v.w);
    *reinterpret_cast<ushort4*>(&out[i]) = o;
}

// ---------------- weight transpose+convert: WT[n][k] = W[k][n], bf16 ----------------

__global__ __launch_bounds__(256) void wt_build_kernel(const float* __restrict__ Ws0,
                                                       const float* __restrict__ Wn0,
                                                       const float* __restrict__ Ws1,
                                                       const float* __restrict__ Wn1,
                                                       unsigned short* __restrict__ WT0,
                                                       unsigned short* __restrict__ WT1) {
    int e = blockIdx.x * blockDim.x + threadIdx.x;  // 0..65535
    int layer = e >> 15;
    int r = e & 32767;
    int n = r >> 8;
    int k = r & 255;
    const float* Ws = layer ? Ws1 : Ws0;
    const float* Wn = layer ? Wn1 : Wn0;
    float v = (k < DIM) ? Ws[k * DIM + n] : Wn[(k - DIM) * DIM + n];
    unsigned short* WT = layer ? WT1 : WT0;
    WT[n * 256 + k] = f2bf(v);
}

// WT2[n][k], n in [0,48), zero-padded beyond OUTD
__global__ __launch_bounds__(256) void wt2_build_kernel(const float* __restrict__ Ws2,
                                                        const float* __restrict__ Wn2,
                                                        unsigned short* __restrict__ WT2) {
    int e = blockIdx.x * blockDim.x + threadIdx.x;  // 0..12287
    int n = e >> 8;
    int k = e & 255;
    float v = 0.f;
    if (n < OUTD) v = (k < DIM) ? Ws2[k * OUTD + n] : Wn2[(k - DIM) * OUTD + n];
    WT2[n * 256 + k] = f2bf(v);
}

// ---------------- mean aggregation v3b (unchanged from round 7) ----------------

__device__ __forceinline__ void unpack_add(float* a, uint4 v) {
    a[0] += __builtin_bit_cast(float, v.x << 16);
    a[1] += __builtin_bit_cast(float, v.x & 0xFFFF0000u);
    a[2] += __builtin_bit_cast(float, v.y << 16);
    a[3] += __builtin_bit_cast(float, v.y & 0xFFFF0000u);
    a[4] += __builtin_bit_cast(float, v.z << 16);
    a[5] += __builtin_bit_cast(float, v.z & 0xFFFF0000u);
    a[6] += __builtin_bit_cast(float, v.w << 16);
    a[7] += __builtin_bit_cast(float, v.w & 0xFFFF0000u);
}

__global__ __launch_bounds__(256) void agg_bf16_kernel(const unsigned short* __restrict__ h,
                                                       const int* __restrict__ row_off,
                                                       const int* __restrict__ csr_src,
                                                       unsigned short* __restrict__ hn) {
    int wave = threadIdx.x >> 6;
    int lane = threadIdx.x & 63;
    int node = blockIdx.x * 4 + wave;
    if (node >= N_NODES) return;  // whole wave uniform
    int lo = row_off[node], hi = row_off[node + 1];
    const int grp = lane >> 4;
    const int l16 = lane & 15;
    float a[8] = {0.f, 0.f, 0.f, 0.f, 0.f, 0.f, 0.f, 0.f};
    for (int base = lo; base < hi; base += 64) {
        int cnt = hi - base; if (cnt > 64) cnt = 64;
        int li = (lane < cnt) ? lane : (cnt - 1);
        int idx = csr_src[base + li];
        int nIter = (cnt + 7) >> 3;
        for (int k = 0; k < nIter; ++k) {
            int t0 = k * 8 + grp;
            int s0 = __shfl(idx, t0, 64);
            int s1 = __shfl(idx, t0 + 4, 64);
            if (t0 < cnt) {
                uint4 v0 = *reinterpret_cast<const uint4*>(&h[(size_t)s0 * DIM + l16 * 8]);
                unpack_add(a, v0);
            }
            if (t0 + 4 < cnt) {
                uint4 v1 = *reinterpret_cast<const uint4*>(&h[(size_t)s1 * DIM + l16 * 8]);
                unpack_add(a, v1);
            }
        }
    }
#pragma unroll
    for (int q = 0; q < 8; ++q) {
        a[q] += __shfl_xor(a[q], 16, 64);
        a[q] += __shfl_xor(a[q], 32, 64);
    }
    if (grp == 0) {
        float rd = (hi > lo) ? 1.0f / (float)(hi - lo) : 1.0f;
        uint4 o;
        o.x = (unsigned int)f2bf(a[0] * rd) | ((unsigned int)f2bf(a[1] * rd) << 16);
        o.y = (unsigned int)f2bf(a[2] * rd) | ((unsigned int)f2bf(a[3] * rd) << 16);
        o.z = (unsigned int)f2bf(a[4] * rd) | ((unsigned int)f2bf(a[5] * rd) << 16);
        o.w = (unsigned int)f2bf(a[6] * rd) | ((unsigned int)f2bf(a[7] * rd) << 16);
        *reinterpret_cast<uint4*>(&hn[(size_t)node * DIM + l16 * 8]) = o;
    }
}

// ---------------- MFMA GEMM v2: A-prefetch + 32KB ks-split LDS + bf16 C + fused stats ----
// C[N][128] = [Ab|Hb] @ WT^T, written as bf16 (pre-BN); fp32 stats via atomics.

__global__ __launch_bounds__(256) void gemm_mfma_kernel(const unsigned short* __restrict__ Ab,
                                                        const unsigned short* __restrict__ Hb,
                                                        const unsigned short* __restrict__ WT,
                                                        unsigned short* __restrict__ C,
                                                        float* __restrict__ bnsum,
                                                        float* __restrict__ bnsq) {
    __shared__ unsigned short wt[16384];  // 32 KB: one K-half [n=128][k=128], XOR-swizzled
    const int tid = threadIdx.x;
    const int wid = tid >> 6;
    const int lane = tid & 63;
    const int lrow = lane & 15;
    const int g = lane >> 4;
    const int r0 = blockIdx.x * 128 + wid * 32;

    // prefetch ALL A-fragments: 16 independent global loads in flight
    bf16x8_t a[2][8];
#pragma unroll
    for (int ks = 0; ks < 8; ++ks) {
        const unsigned short* __restrict__ base = (ks < 4) ? Ab : Hb;
        const int kk = (ks & 3) * 32 + g * 8;
#pragma unroll
        for (int mt = 0; mt < 2; ++mt) {
            int row = r0 + mt * 16 + lrow;
            if (row >= N_NODES) row = N_NODES - 1;
            a[mt][ks] = *reinterpret_cast<const bf16x8_t*>(&base[(size_t)row * DIM + kk]);
        }
    }

    f32x4_t acc[2][8];
#pragma unroll
    for (int mt = 0; mt < 2; ++mt)
#pragma unroll
        for (int nt = 0; nt < 8; ++nt) acc[mt][nt] = (f32x4_t){0.f, 0.f, 0.f, 0.f};

#pragma unroll
    for (int hh = 0; hh < 2; ++hh) {
        if (hh) __syncthreads();  // all waves done with previous half's LDS reads
        // stage K-half: 2048 x 16B chunks, 8 per thread
#pragma unroll
        for (int i = 0; i < 8; ++i) {
            int c = i * 256 + tid;          // chunk id 0..2047
            int n = c >> 4;                 // 16 chunks (256B) per output-col row
            int koff = (c & 15) * 8;        // element offset within the 128-k half
            unsigned int waddr = ((unsigned int)(c * 16)) ^ (((unsigned int)(n & 7)) << 4);
            uint4 v = *reinterpret_cast<const uint4*>(&WT[n * 256 + hh * 128 + koff]);
            *reinterpret_cast<uint4*>(reinterpret_cast<char*>(wt) + waddr) = v;
        }
        __syncthreads();
#pragma unroll
        for (int ks = 0; ks < 4; ++ks) {
#pragma unroll
            for (int nt = 0; nt < 8; ++nt) {
                int n = nt * 16 + lrow;
                unsigned int raddr = ((unsigned int)(n * 256 + ks * 64 + g * 16)) ^ (((unsigned int)(n & 7)) << 4);
                bf16x8_t b = *reinterpret_cast<const bf16x8_t*>(reinterpret_cast<const char*>(wt) + raddr);
                acc[0][nt] = __builtin_amdgcn_mfma_f32_16x16x32_bf16(a[0][hh * 4 + ks], b, acc[0][nt], 0, 0, 0);
                acc[1][nt] = __builtin_amdgcn_mfma_f32_16x16x32_bf16(a[1][hh * 4 + ks], b, acc[1][nt], 0, 0, 0);
            }
        }
    }

    // ---- fused BN stats (fp32, from acc) ----
    float ssum[8], ssq[8];
#pragma unroll
    for (int nt = 0; nt < 8; ++nt) { ssum[nt] = 0.f; ssq[nt] = 0.f; }
#pragma unroll
    for (int mt = 0; mt < 2; ++mt) {
#pragma unroll
        for (int j = 0; j < 4; ++j) {
            int row = r0 + mt * 16 + g * 4 + j;
            if (row < N_NODES) {
#pragma unroll
                for (int nt = 0; nt < 8; ++nt) {
                    float v = acc[mt][nt][j];
                    ssum[nt] += v;
                    ssq[nt] += v * v;
                }
            }
        }
    }
#pragma unroll
    for (int nt = 0; nt < 8; ++nt) {  // converged butterfly over row-groups
        ssum[nt] += __shfl_xor(ssum[nt], 16, 64);
        ssum[nt] += __shfl_xor(ssum[nt], 32, 64);
        ssq[nt] += __shfl_xor(ssq[nt], 16, 64);
        ssq[nt] += __shfl_xor(ssq[nt], 32, 64);
    }
    __syncthreads();  // all waves done reading wt -> safe to alias
    float* ls = reinterpret_cast<float*>(wt);        // [4][128]
    float* lq = ls + 512;                            // [4][128]
    if (g == 0) {
#pragma unroll
        for (int nt = 0; nt < 8; ++nt) {
            ls[wid * 128 + nt * 16 + lrow] = ssum[nt];
            lq[wid * 128 + nt * 16 + lrow] = ssq[nt];
        }
    }
    __syncthreads();
    if (tid < 128) {
        float s = ls[tid] + ls[128 + tid] + ls[256 + tid] + ls[384 + tid];
        float q = lq[tid] + lq[128 + tid] + lq[256 + tid] + lq[384 + tid];
        atomicAdd(&bnsum[tid], s);
        atomicAdd(&bnsq[tid], q);
    }

    // ---- C write (bf16, pre-BN) ----
#pragma unroll
    for (int mt = 0; mt < 2; ++mt) {
#pragma unroll
        for (int j = 0; j < 4; ++j) {
            int row = r0 + mt * 16 + g * 4 + j;
            if (row < N_NODES) {
#pragma unroll
                for (int nt = 0; nt < 8; ++nt)
                    C[(size_t)row * DIM + nt * 16 + lrow] = f2bf(acc[mt][nt][j]);
            }
        }
    }
}

// ---------------- BatchNorm apply + ReLU, bf16 in -> bf16 out (in place) ----------------

__global__ __launch_bounds__(256) void bn_apply_bf16_kernel(unsigned short* __restrict__ H,
                                                            const float* __restrict__ bnsum,
                                                            const float* __restrict__ bnsq,
                                                            const float* __restrict__ gamma,
                                                            const float* __restrict__ beta) {
    size_t idx = (size_t)(blockIdx.x * blockDim.x + threadIdx.x) * 8;
    const float invN = 1.0f / (float)N_NODES;
    int c = (int)(idx & (DIM - 1));
    uint4 v = *reinterpret_cast<const uint4*>(&H[idx]);
    unsigned int w[4] = {v.x, v.y, v.z, v.w};
    uint4 o;
    unsigned int* op = &o.x;
#pragma unroll
    for (int p = 0; p < 4; ++p) {
        float x0 = __builtin_bit_cast(float, w[p] << 16);
        float x1 = __builtin_bit_cast(float, w[p] & 0xFFFF0000u);
        int c0 = c + p * 2, c1 = c0 + 1;
        float mean0 = bnsum[c0] * invN, mean1 = bnsum[c1] * invN;
        float var0 = bnsq[c0] * invN - mean0 * mean0;
        float var1 = bnsq[c1] * invN - mean1 * mean1;
        float y0 = (x0 - mean0) * gamma[c0] * rsqrtf(var0 + BN_EPS) + beta[c0];
        float y1 = (x1 - mean1) * gamma[c1] * rsqrtf(var1 + BN_EPS) + beta[c1];
        y0 = y0 > 0.f ? y0 : 0.f;
        y1 = y1 > 0.f ? y1 : 0.f;
        op[p] = (unsigned int)f2bf(y0) | ((unsigned int)f2bf(y1) << 16);
    }
    *reinterpret_cast<uint4*>(&H[idx]) = o;
}

// ---------------- output layer (MFMA): C[N][40] = [Ab|Hb] @ WT2^T + b ----------------

__global__ __launch_bounds__(256) void gemm_out_mfma_kernel(const unsigned short* __restrict__ Ab,
                                                            const unsigned short* __restrict__ Hb,
                                                            const unsigned short* __restrict__ WT2,
                                                            const float* __restrict__ bias,
                                                            float* __restrict__ C) {
    __shared__ unsigned short wt[OUTP * 256];  // 24 KB, XOR-swizzled
    const int tid = threadIdx.x;

#pragma unroll
    for (int i = 0; i < 6; ++i) {
        int c = i * 256 + tid;               // 16B chunks: 0..1535
        int n = c >> 5;
        unsigned int waddr = ((unsigned int)(c * 16)) ^ (((unsigned int)(n & 7)) << 4);
        uint4 v = *reinterpret_cast<const uint4*>(&WT2[c * 8]);
        *reinterpret_cast<uint4*>(reinterpret_cast<char*>(wt) + waddr) = v;
    }
    __syncthreads();

    const int wid = tid >> 6;
    const int lane = tid & 63;
    const int lrow = lane & 15;
    const int g = lane >> 4;
    const int r0 = blockIdx.x * 128 + wid * 32;

    // prefetch all A-fragments
    bf16x8_t a[2][8];
#pragma unroll
    for (int ks = 0; ks < 8; ++ks) {
        const unsigned short* __restrict__ base = (ks < 4) ? Ab : Hb;
        const int kk = (ks & 3) * 32 + g * 8;
#pragma unroll
        for (int mt = 0; mt < 2; ++mt) {
            int row = r0 + mt * 16 + lrow;
            if (row >= N_NODES) row = N_NODES - 1;
            a[mt][ks] = *reinterpret_cast<const bf16x8_t*>(&base[(size_t)row * DIM + kk]);
        }
    }

    f32x4_t acc[2][3];
#pragma unroll
    for (int mt = 0; mt < 2; ++mt)
#pragma unroll
        for (int nt = 0; nt < 3; ++nt) acc[mt][nt] = (f32x4_t){0.f, 0.f, 0.f, 0.f};

#pragma unroll
    for (int ks = 0; ks < 8; ++ks) {
#pragma unroll
        for (int nt = 0; nt < 3; ++nt) {
            int n = nt * 16 + lrow;
            unsigned int raddr = ((unsigned int)(n * 512 + ks * 64 + g * 16)) ^ (((unsigned int)(n & 7)) << 4);
            bf16x8_t b = *reinterpret_cast<const bf16x8_t*>(reinterpret_cast<const char*>(wt) + raddr);
            acc[0][nt] = __builtin_amdgcn_mfma_f32_16x16x32_bf16(a[0][ks], b, acc[0][nt], 0, 0, 0);
            acc[1][nt] = __builtin_amdgcn_mfma_f32_16x16x32_bf16(a[1][ks], b, acc[1][nt], 0, 0, 0);
        }
    }

    float bb[3];
#pragma unroll
    for (int nt = 0; nt < 3; ++nt) {
        int col = nt * 16 + lrow;
        bb[nt] = (col < OUTD) ? bias[col] : 0.f;
    }

#pragma unroll
    for (int mt = 0; mt < 2; ++mt) {
#pragma unroll
        for (int j = 0; j < 4; ++j) {
            int row = r0 + mt * 16 + g * 4 + j;
            if (row < N_NODES) {
#pragma unroll
                for (int nt = 0; nt < 3; ++nt) {
                    int col = nt * 16 + lrow;
                    if (col < OUTD)
                        C[(size_t)row * OUTD + col] = acc[mt][nt][j] + bb[nt];
                }
            }
        }
    }
}

// ---------------- launch ----------------

extern "C" void kernel_launch(void* const* d_in, const int* in_sizes, int n_in,
                              void* d_out, int out_size, void* d_ws, size_t ws_size,
                              hipStream_t stream) {
    const float* feat = (const float*)d_in[0];
    const int* src = (const int*)d_in[1];
    const int* dst = (const int*)d_in[2];
    const float* Ws0 = (const float*)d_in[3];
    const float* Wn0 = (const float*)d_in[4];
    const float* g0  = (const float*)d_in[5];
    const float* be0 = (const float*)d_in[6];
    const float* Ws1 = (const float*)d_in[7];
    const float* Wn1 = (const float*)d_in[8];
    const float* g1  = (const float*)d_in[9];
    const float* be1 = (const float*)d_in[10];
    const float* Ws2 = (const float*)d_in[11];
    const float* Wn2 = (const float*)d_in[12];
    const float* b2  = (const float*)d_in[13];
    float* out = (float*)d_out;

    char* ws = (char*)d_ws;
    int*   deg     = (int*)(ws);                       // 400000 B (zeroed)
    int*   cursor  = (int*)(ws + 400000);              // 400000 B (zeroed)
    float* bn      = (float*)(ws + 800000);            // 2048 B   (zeroed)
    int*   row_off = (int*)(ws + 802048);              // 400004 B
    int*   csr     = (int*)(ws + 1202176);             // 3200000 B
    unsigned short* featb = (unsigned short*)(ws + 4402176);   // 25.6 MB (reused as h1b)
    unsigned short* hnb   = (unsigned short*)(ws + 30002176);  // 25.6 MB
    unsigned short* h0b   = (unsigned short*)(ws + 55602176);  // 25.6 MB
    unsigned short* WT0   = (unsigned short*)(ws + 132402176); // 65536 B
    unsigned short* WT1   = (unsigned short*)(ws + 132467712); // 65536 B
    int*   partials = (int*)(ws + 132533248);                  // 512 B
    unsigned short* WT2   = (unsigned short*)(ws + 132533760); // 24576 B
    unsigned short* h1b   = featb;  // featb dead after layer-0 gemm

    hipMemsetAsync(ws, 0, 802048, stream);

    const int EB = (N_EDGES + 255) / 256;        // 3125
    const int AB = (N_NODES + 3) / 4;            // 25000
    const int MB = (N_NODES + 127) / 128;        // 782
    const int NE = (N_NODES * DIM) / 4 / 256;    // 12500
    const int NB8 = (N_NODES * DIM) / 8 / 256;   // 6250

    deg_kernel<<<EB, 256, 0, stream>>>(dst, deg);
    scan_partial_kernel<<<SCAN_NB, 256, 0, stream>>>(deg, partials);
    scan_partials_kernel<<<1, 128, 0, stream>>>(partials);
    scan_final_kernel<<<SCAN_NB, 256, 0, stream>>>(deg, partials, row_off);
    fill_kernel<<<EB, 256, 0, stream>>>(src, dst, row_off, cursor, csr);

    convert_bf16_kernel<<<NE, 256, 0, stream>>>(feat, featb);
    wt_build_kernel<<<256, 256, 0, stream>>>(Ws0, Wn0, Ws1, Wn1, WT0, WT1);
    wt2_build_kernel<<<48, 256, 0, stream>>>(Ws2, Wn2, WT2);

    // layer 0
    agg_bf16_kernel<<<AB, 256, 0, stream>>>(featb, row_off, csr, hnb);
    gemm_mfma_kernel<<<MB, 256, 0, stream>>>(featb, hnb, WT0, h0b, bn + 0, bn + 128);
    bn_apply_bf16_kernel<<<NB8, 256, 0, stream>>>(h0b, bn + 0, bn + 128, g0, be0);

    // layer 1
    agg_bf16_kernel<<<AB, 256, 0, stream>>>(h0b, row_off, csr, hnb);
    gemm_mfma_kernel<<<MB, 256, 0, stream>>>(h0b, hnb, WT1, h1b, bn + 256, bn + 384);
    bn_apply_bf16_kernel<<<NB8, 256, 0, stream>>>(h1b, bn + 256, bn + 384, g1, be1);

    // layer 2
    agg_bf16_kernel<<<AB, 256, 0, stream>>>(h1b, row_off, csr, hnb);
    gemm_out_mfma_kernel<<<MB, 256, 0, stream>>>(h1b, hnb, WT2, b2, out);
}

// Round 9
// 279.986 us; speedup vs baseline: 34.3861x; 1.1414x over previous
//
#include <hip/hip_runtime.h>

#define N_NODES 100000
#define N_EDGES 800000
#define DIM 128
#define OUTD 40
#define OUTP 48  // padded to 3x16 MFMA col-tiles
#define BN_EPS 1e-5f
#define SCAN_NB 98   // ceil(100000/1024)
#define NBKT 98      // dst buckets of 1024 nodes
#define BKT_CAP 12288  // per-bucket pair capacity (avg 8163, +45 sigma)

typedef __bf16 bf16x8_t __attribute__((ext_vector_type(8)));
typedef float f32x4_t __attribute__((ext_vector_type(4)));

__device__ __forceinline__ unsigned short f2bf(float f) {
    unsigned int u = __builtin_bit_cast(unsigned int, f);
    u = (u + 0x7FFF + ((u >> 16) & 1)) >> 16;
    return (unsigned short)u;
}

// ---------------- CSR build: bucketed (XCD-local writes) ----------------

// Phase A: scatter (src,dst) into dst-buckets; per-block contiguous runs.
__global__ __launch_bounds__(256) void bucketA_kernel(const int* __restrict__ src,
                                                      const int* __restrict__ dst,
                                                      uint2* __restrict__ pairs,
                                                      int* __restrict__ gcursor) {
    __shared__ int cnt[NBKT], base[NBKT], rec[NBKT];
    const int t = threadIdx.x;
    if (t < NBKT) { cnt[t] = 0; rec[t] = 0; }
    __syncthreads();
    const int e0 = blockIdx.x * 4096 + t * 16;
    const bool active = (e0 + 16 <= N_EDGES);  // tail is 80x16 -> all-or-nothing
    int s[16], d[16];
    if (active) {
#pragma unroll
        for (int i = 0; i < 4; ++i) {
            int4 sv = *reinterpret_cast<const int4*>(&src[e0 + i * 4]);
            int4 dv = *reinterpret_cast<const int4*>(&dst[e0 + i * 4]);
            s[i * 4 + 0] = sv.x; s[i * 4 + 1] = sv.y; s[i * 4 + 2] = sv.z; s[i * 4 + 3] = sv.w;
            d[i * 4 + 0] = dv.x; d[i * 4 + 1] = dv.y; d[i * 4 + 2] = dv.z; d[i * 4 + 3] = dv.w;
        }
#pragma unroll
        for (int i = 0; i < 16; ++i) atomicAdd(&cnt[d[i] >> 10], 1);
    }
    __syncthreads();
    if (t < NBKT && cnt[t] > 0) base[t] = atomicAdd(&gcursor[t], cnt[t]);
    __syncthreads();
    if (active) {
#pragma unroll
        for (int i = 0; i < 16; ++i) {
            int bk = d[i] >> 10;
            int loc = atomicAdd(&rec[bk], 1);
            pairs[(size_t)bk * BKT_CAP + base[bk] + loc] = make_uint2((unsigned)s[i], (unsigned)d[i]);
        }
    }
}

// Phase B: per-bucket degree histogram -> coalesced deg write (no global atomics).
__global__ __launch_bounds__(256) void phaseB_deg_kernel(const uint2* __restrict__ pairs,
                                                         const int* __restrict__ gcursor,
                                                         int* __restrict__ deg) {
    __shared__ int hist[1024];
    const int b = blockIdx.x;
    const int t = threadIdx.x;
#pragma unroll
    for (int j = 0; j < 4; ++j) hist[t * 4 + j] = 0;
    __syncthreads();
    const int m = gcursor[b];
    const uint2* __restrict__ bp = &pairs[(size_t)b * BKT_CAP];
    for (int i = t; i < m; i += 256) {
        uint2 p = bp[i];
        atomicAdd(&hist[p.y & 1023], 1);
    }
    __syncthreads();
    const int n0 = b << 10;
#pragma unroll
    for (int j = 0; j < 4; ++j) {
        int node = n0 + t * 4 + j;
        if (node < N_NODES) deg[node] = hist[t * 4 + j];
    }
}

__global__ __launch_bounds__(256) void scan_partial_kernel(const int* __restrict__ deg,
                                                           int* __restrict__ partials) {
    int b = blockIdx.x;
    int tid = threadIdx.x;
    int base = b * 1024 + tid * 4;
    int t0 = 0, t1 = 0, t2 = 0, t3 = 0;
    if (base + 3 < N_NODES) {
        int4 v = *reinterpret_cast<const int4*>(&deg[base]);
        t0 = v.x; t1 = v.y; t2 = v.z; t3 = v.w;
    } else {
        if (base + 0 < N_NODES) t0 = deg[base + 0];
        if (base + 1 < N_NODES) t1 = deg[base + 1];
        if (base + 2 < N_NODES) t2 = deg[base + 2];
        if (base + 3 < N_NODES) t3 = deg[base + 3];
    }
    int s = t0 + t1 + t2 + t3;
    __shared__ int red[256];
    red[tid] = s;
    __syncthreads();
    for (int o = 128; o; o >>= 1) {
        if (tid < o) red[tid] += red[tid + o];
        __syncthreads();
    }
    if (tid == 0) partials[b] = red[0];
}

__global__ __launch_bounds__(128) void scan_partials_kernel(int* __restrict__ partials) {
    __shared__ int s[128];
    int t = threadIdx.x;
    int v = (t < SCAN_NB) ? partials[t] : 0;
    s[t] = v;
    __syncthreads();
    for (int off = 1; off < 128; off <<= 1) {
        int u = (t >= off) ? s[t - off] : 0;
        __syncthreads();
        s[t] += u;
        __syncthreads();
    }
    if (t < SCAN_NB) partials[t] = s[t] - v;  // exclusive
}

__global__ __launch_bounds__(256) void scan_final_kernel(const int* __restrict__ deg,
                                                         const int* __restrict__ partials,
                                                         int* __restrict__ row_off) {
    int b = blockIdx.x;
    int tid = threadIdx.x;
    int base = b * 1024 + tid * 4;
    int t0 = 0, t1 = 0, t2 = 0, t3 = 0;
    if (base + 3 < N_NODES) {
        int4 v = *reinterpret_cast<const int4*>(&deg[base]);
        t0 = v.x; t1 = v.y; t2 = v.z; t3 = v.w;
    } else {
        if (base + 0 < N_NODES) t0 = deg[base + 0];
        if (base + 1 < N_NODES) t1 = deg[base + 1];
        if (base + 2 < N_NODES) t2 = deg[base + 2];
        if (base + 3 < N_NODES) t3 = deg[base + 3];
    }
    int s = t0 + t1 + t2 + t3;
    __shared__ int sc[256];
    sc[tid] = s;
    __syncthreads();
    for (int off = 1; off < 256; off <<= 1) {
        int u = (tid >= off) ? sc[tid - off] : 0;
        __syncthreads();
        sc[tid] += u;
        __syncthreads();
    }
    int run = partials[b] + sc[tid] - s;
    if (base + 0 < N_NODES) row_off[base + 0] = run; run += t0;
    if (base + 1 < N_NODES) row_off[base + 1] = run; run += t1;
    if (base + 2 < N_NODES) row_off[base + 2] = run; run += t2;
    if (base + 3 < N_NODES) row_off[base + 3] = run;
    if (b == 0 && tid == 0) row_off[N_NODES] = N_EDGES;
}

// Phase C: per-bucket CSR fill; LDS cursors; writes land in block-owned range.
__global__ __launch_bounds__(256) void phaseC_fill_kernel(const uint2* __restrict__ pairs,
                                                          const int* __restrict__ gcursor,
                                                          const int* __restrict__ row_off,
                                                          int* __restrict__ csr_src) {
    __shared__ int cur[1024];
    const int b = blockIdx.x;
    const int t = threadIdx.x;
    const int n0 = b << 10;
#pragma unroll
    for (int j = 0; j < 4; ++j) {
        int node = n0 + t * 4 + j;
        if (node < N_NODES) cur[t * 4 + j] = row_off[node];
    }
    __syncthreads();
    const int m = gcursor[b];
    const uint2* __restrict__ bp = &pairs[(size_t)b * BKT_CAP];
    for (int i = t; i < m; i += 256) {
        uint2 p = bp[i];
        int pos = atomicAdd(&cur[p.y & 1023], 1);
        csr_src[pos] = (int)p.x;
    }
}

// ---------------- fp32 -> bf16 convert (feat) ----------------

__global__ __launch_bounds__(256) void convert_bf16_kernel(const float* __restrict__ in,
                                                           unsigned short* __restrict__ out) {
    size_t i = (size_t)(blockIdx.x * blockDim.x + threadIdx.x) * 4;
    float4 v = *reinterpret_cast<const float4*>(&in[i]);
    ushort4 o;
    o.x = f2bf(v.x); o.y = f2bf(v.y); o.z = f2bf(v.z); o.w = f2bf(v.w);
    *reinterpret_cast<ushort4*>(&out[i]) = o;
}

// ---------------- weight transpose+convert: WT[n][k] = W[k][n], bf16 ----------------

__global__ __launch_bounds__(256) void wt_build_kernel(const float* __restrict__ Ws0,
                                                       const float* __restrict__ Wn0,
                                                       const float* __restrict__ Ws1,
                                                       const float* __restrict__ Wn1,
                                                       unsigned short* __restrict__ WT0,
                                                       unsigned short* __restrict__ WT1) {
    int e = blockIdx.x * blockDim.x + threadIdx.x;  // 0..65535
    int layer = e >> 15;
    int r = e & 32767;
    int n = r >> 8;
    int k = r & 255;
    const float* Ws = layer ? Ws1 : Ws0;
    const float* Wn = layer ? Wn1 : Wn0;
    float v = (k < DIM) ? Ws[k * DIM + n] : Wn[(k - DIM) * DIM + n];
    unsigned short* WT = layer ? WT1 : WT0;
    WT[n * 256 + k] = f2bf(v);
}

// WT2[n][k], n in [0,48), zero-padded beyond OUTD
__global__ __launch_bounds__(256) void wt2_build_kernel(const float* __restrict__ Ws2,
                                                        const float* __restrict__ Wn2,
                                                        unsigned short* __restrict__ WT2) {
    int e = blockIdx.x * blockDim.x + threadIdx.x;  // 0..12287
    int n = e >> 8;
    int k = e & 255;
    float v = 0.f;
    if (n < OUTD) v = (k < DIM) ? Ws2[k * OUTD + n] : Wn2[(k - DIM) * OUTD + n];
    WT2[n * 256 + k] = f2bf(v);
}

// ---------------- mean aggregation v3b ----------------

__device__ __forceinline__ void unpack_add(float* a, uint4 v) {
    a[0] += __builtin_bit_cast(float, v.x << 16);
    a[1] += __builtin_bit_cast(float, v.x & 0xFFFF0000u);
    a[2] += __builtin_bit_cast(float, v.y << 16);
    a[3] += __builtin_bit_cast(float, v.y & 0xFFFF0000u);
    a[4] += __builtin_bit_cast(float, v.z << 16);
    a[5] += __builtin_bit_cast(float, v.z & 0xFFFF0000u);
    a[6] += __builtin_bit_cast(float, v.w << 16);
    a[7] += __builtin_bit_cast(float, v.w & 0xFFFF0000u);
}

__global__ __launch_bounds__(256) void agg_bf16_kernel(const unsigned short* __restrict__ h,
                                                       const int* __restrict__ row_off,
                                                       const int* __restrict__ csr_src,
                                                       unsigned short* __restrict__ hn) {
    int wave = threadIdx.x >> 6;
    int lane = threadIdx.x & 63;
    int node = blockIdx.x * 4 + wave;
    if (node >= N_NODES) return;  // whole wave uniform
    int lo = row_off[node], hi = row_off[node + 1];
    const int grp = lane >> 4;
    const int l16 = lane & 15;
    float a[8] = {0.f, 0.f, 0.f, 0.f, 0.f, 0.f, 0.f, 0.f};
    for (int base = lo; base < hi; base += 64) {
        int cnt = hi - base; if (cnt > 64) cnt = 64;
        int li = (lane < cnt) ? lane : (cnt - 1);
        int idx = csr_src[base + li];
        int nIter = (cnt + 7) >> 3;
        for (int k = 0; k < nIter; ++k) {
            int t0 = k * 8 + grp;
            int s0 = __shfl(idx, t0, 64);
            int s1 = __shfl(idx, t0 + 4, 64);
            if (t0 < cnt) {
                uint4 v0 = *reinterpret_cast<const uint4*>(&h[(size_t)s0 * DIM + l16 * 8]);
                unpack_add(a, v0);
            }
            if (t0 + 4 < cnt) {
                uint4 v1 = *reinterpret_cast<const uint4*>(&h[(size_t)s1 * DIM + l16 * 8]);
                unpack_add(a, v1);
            }
        }
    }
#pragma unroll
    for (int q = 0; q < 8; ++q) {
        a[q] += __shfl_xor(a[q], 16, 64);
        a[q] += __shfl_xor(a[q], 32, 64);
    }
    if (grp == 0) {
        float rd = (hi > lo) ? 1.0f / (float)(hi - lo) : 1.0f;
        uint4 o;
        o.x = (unsigned int)f2bf(a[0] * rd) | ((unsigned int)f2bf(a[1] * rd) << 16);
        o.y = (unsigned int)f2bf(a[2] * rd) | ((unsigned int)f2bf(a[3] * rd) << 16);
        o.z = (unsigned int)f2bf(a[4] * rd) | ((unsigned int)f2bf(a[5] * rd) << 16);
        o.w = (unsigned int)f2bf(a[6] * rd) | ((unsigned int)f2bf(a[7] * rd) << 16);
        *reinterpret_cast<uint4*>(&hn[(size_t)node * DIM + l16 * 8]) = o;
    }
}

// ---------------- MFMA GEMM v2 + fused BN stats (unchanged from round 8) ----------------

__global__ __launch_bounds__(256) void gemm_mfma_kernel(const unsigned short* __restrict__ Ab,
                                                        const unsigned short* __restrict__ Hb,
                                                        const unsigned short* __restrict__ WT,
                                                        unsigned short* __restrict__ C,
                                                        float* __restrict__ bnsum,
                                                        float* __restrict__ bnsq) {
    __shared__ unsigned short wt[16384];  // 32 KB: one K-half [n=128][k=128], XOR-swizzled
    const int tid = threadIdx.x;
    const int wid = tid >> 6;
    const int lane = tid & 63;
    const int lrow = lane & 15;
    const int g = lane >> 4;
    const int r0 = blockIdx.x * 128 + wid * 32;

    bf16x8_t a[2][8];
#pragma unroll
    for (int ks = 0; ks < 8; ++ks) {
        const unsigned short* __restrict__ base = (ks < 4) ? Ab : Hb;
        const int kk = (ks & 3) * 32 + g * 8;
#pragma unroll
        for (int mt = 0; mt < 2; ++mt) {
            int row = r0 + mt * 16 + lrow;
            if (row >= N_NODES) row = N_NODES - 1;
            a[mt][ks] = *reinterpret_cast<const bf16x8_t*>(&base[(size_t)row * DIM + kk]);
        }
    }

    f32x4_t acc[2][8];
#pragma unroll
    for (int mt = 0; mt < 2; ++mt)
#pragma unroll
        for (int nt = 0; nt < 8; ++nt) acc[mt][nt] = (f32x4_t){0.f, 0.f, 0.f, 0.f};

#pragma unroll
    for (int hh = 0; hh < 2; ++hh) {
        if (hh) __syncthreads();
#pragma unroll
        for (int i = 0; i < 8; ++i) {
            int c = i * 256 + tid;
            int n = c >> 4;
            int koff = (c & 15) * 8;
            unsigned int waddr = ((unsigned int)(c * 16)) ^ (((unsigned int)(n & 7)) << 4);
            uint4 v = *reinterpret_cast<const uint4*>(&WT[n * 256 + hh * 128 + koff]);
            *reinterpret_cast<uint4*>(reinterpret_cast<char*>(wt) + waddr) = v;
        }
        __syncthreads();
#pragma unroll
        for (int ks = 0; ks < 4; ++ks) {
#pragma unroll
            for (int nt = 0; nt < 8; ++nt) {
                int n = nt * 16 + lrow;
                unsigned int raddr = ((unsigned int)(n * 256 + ks * 64 + g * 16)) ^ (((unsigned int)(n & 7)) << 4);
                bf16x8_t b = *reinterpret_cast<const bf16x8_t*>(reinterpret_cast<const char*>(wt) + raddr);
                acc[0][nt] = __builtin_amdgcn_mfma_f32_16x16x32_bf16(a[0][hh * 4 + ks], b, acc[0][nt], 0, 0, 0);
                acc[1][nt] = __builtin_amdgcn_mfma_f32_16x16x32_bf16(a[1][hh * 4 + ks], b, acc[1][nt], 0, 0, 0);
            }
        }
    }

    float ssum[8], ssq[8];
#pragma unroll
    for (int nt = 0; nt < 8; ++nt) { ssum[nt] = 0.f; ssq[nt] = 0.f; }
#pragma unroll
    for (int mt = 0; mt < 2; ++mt) {
#pragma unroll
        for (int j = 0; j < 4; ++j) {
            int row = r0 + mt * 16 + g * 4 + j;
            if (row < N_NODES) {
#pragma unroll
                for (int nt = 0; nt < 8; ++nt) {
                    float v = acc[mt][nt][j];
                    ssum[nt] += v;
                    ssq[nt] += v * v;
                }
            }
        }
    }
#pragma unroll
    for (int nt = 0; nt < 8; ++nt) {
        ssum[nt] += __shfl_xor(ssum[nt], 16, 64);
        ssum[nt] += __shfl_xor(ssum[nt], 32, 64);
        ssq[nt] += __shfl_xor(ssq[nt], 16, 64);
        ssq[nt] += __shfl_xor(ssq[nt], 32, 64);
    }
    __syncthreads();
    float* ls = reinterpret_cast<float*>(wt);        // [4][128]
    float* lq = ls + 512;                            // [4][128]
    if (g == 0) {
#pragma unroll
        for (int nt = 0; nt < 8; ++nt) {
            ls[wid * 128 + nt * 16 + lrow] = ssum[nt];
            lq[wid * 128 + nt * 16 + lrow] = ssq[nt];
        }
    }
    __syncthreads();
    if (tid < 128) {
        float s = ls[tid] + ls[128 + tid] + ls[256 + tid] + ls[384 + tid];
        float q = lq[tid] + lq[128 + tid] + lq[256 + tid] + lq[384 + tid];
        atomicAdd(&bnsum[tid], s);
        atomicAdd(&bnsq[tid], q);
    }

#pragma unroll
    for (int mt = 0; mt < 2; ++mt) {
#pragma unroll
        for (int j = 0; j < 4; ++j) {
            int row = r0 + mt * 16 + g * 4 + j;
            if (row < N_NODES) {
#pragma unroll
                for (int nt = 0; nt < 8; ++nt)
                    C[(size_t)row * DIM + nt * 16 + lrow] = f2bf(acc[mt][nt][j]);
            }
        }
    }
}

// ---------------- BatchNorm apply + ReLU, bf16 in-place ----------------

__global__ __launch_bounds__(256) void bn_apply_bf16_kernel(unsigned short* __restrict__ H,
                                                            const float* __restrict__ bnsum,
                                                            const float* __restrict__ bnsq,
                                                            const float* __restrict__ gamma,
                                                            const float* __restrict__ beta) {
    size_t idx = (size_t)(blockIdx.x * blockDim.x + threadIdx.x) * 8;
    const float invN = 1.0f / (float)N_NODES;
    int c = (int)(idx & (DIM - 1));
    uint4 v = *reinterpret_cast<const uint4*>(&H[idx]);
    unsigned int w[4] = {v.x, v.y, v.z, v.w};
    uint4 o;
    unsigned int* op = &o.x;
#pragma unroll
    for (int p = 0; p < 4; ++p) {
        float x0 = __builtin_bit_cast(float, w[p] << 16);
        float x1 = __builtin_bit_cast(float, w[p] & 0xFFFF0000u);
        int c0 = c + p * 2, c1 = c0 + 1;
        float mean0 = bnsum[c0] * invN, mean1 = bnsum[c1] * invN;
        float var0 = bnsq[c0] * invN - mean0 * mean0;
        float var1 = bnsq[c1] * invN - mean1 * mean1;
        float y0 = (x0 - mean0) * gamma[c0] * rsqrtf(var0 + BN_EPS) + beta[c0];
        float y1 = (x1 - mean1) * gamma[c1] * rsqrtf(var1 + BN_EPS) + beta[c1];
        y0 = y0 > 0.f ? y0 : 0.f;
        y1 = y1 > 0.f ? y1 : 0.f;
        op[p] = (unsigned int)f2bf(y0) | ((unsigned int)f2bf(y1) << 16);
    }
    *reinterpret_cast<uint4*>(&H[idx]) = o;
}

// ---------------- output layer (MFMA): C[N][40] = [Ab|Hb] @ WT2^T + b ----------------

__global__ __launch_bounds__(256) void gemm_out_mfma_kernel(const unsigned short* __restrict__ Ab,
                                                            const unsigned short* __restrict__ Hb,
                                                            const unsigned short* __restrict__ WT2,
                                                            const float* __restrict__ bias,
                                                            float* __restrict__ C) {
    __shared__ unsigned short wt[OUTP * 256];  // 24 KB, XOR-swizzled
    const int tid = threadIdx.x;

#pragma unroll
    for (int i = 0; i < 6; ++i) {
        int c = i * 256 + tid;
        int n = c >> 5;
        unsigned int waddr = ((unsigned int)(c * 16)) ^ (((unsigned int)(n & 7)) << 4);
        uint4 v = *reinterpret_cast<const uint4*>(&WT2[c * 8]);
        *reinterpret_cast<uint4*>(reinterpret_cast<char*>(wt) + waddr) = v;
    }
    __syncthreads();

    const int wid = tid >> 6;
    const int lane = tid & 63;
    const int lrow = lane & 15;
    const int g = lane >> 4;
    const int r0 = blockIdx.x * 128 + wid * 32;

    bf16x8_t a[2][8];
#pragma unroll
    for (int ks = 0; ks < 8; ++ks) {
        const unsigned short* __restrict__ base = (ks < 4) ? Ab : Hb;
        const int kk = (ks & 3) * 32 + g * 8;
#pragma unroll
        for (int mt = 0; mt < 2; ++mt) {
            int row = r0 + mt * 16 + lrow;
            if (row >= N_NODES) row = N_NODES - 1;
            a[mt][ks] = *reinterpret_cast<const bf16x8_t*>(&base[(size_t)row * DIM + kk]);
        }
    }

    f32x4_t acc[2][3];
#pragma unroll
    for (int mt = 0; mt < 2; ++mt)
#pragma unroll
        for (int nt = 0; nt < 3; ++nt) acc[mt][nt] = (f32x4_t){0.f, 0.f, 0.f, 0.f};

#pragma unroll
    for (int ks = 0; ks < 8; ++ks) {
#pragma unroll
        for (int nt = 0; nt < 3; ++nt) {
            int n = nt * 16 + lrow;
            unsigned int raddr = ((unsigned int)(n * 512 + ks * 64 + g * 16)) ^ (((unsigned int)(n & 7)) << 4);
            bf16x8_t b = *reinterpret_cast<const bf16x8_t*>(reinterpret_cast<const char*>(wt) + raddr);
            acc[0][nt] = __builtin_amdgcn_mfma_f32_16x16x32_bf16(a[0][ks], b, acc[0][nt], 0, 0, 0);
            acc[1][nt] = __builtin_amdgcn_mfma_f32_16x16x32_bf16(a[1][ks], b, acc[1][nt], 0, 0, 0);
        }
    }

    float bb[3];
#pragma unroll
    for (int nt = 0; nt < 3; ++nt) {
        int col = nt * 16 + lrow;
        bb[nt] = (col < OUTD) ? bias[col] : 0.f;
    }

#pragma unroll
    for (int mt = 0; mt < 2; ++mt) {
#pragma unroll
        for (int j = 0; j < 4; ++j) {
            int row = r0 + mt * 16 + g * 4 + j;
            if (row < N_NODES) {
#pragma unroll
                for (int nt = 0; nt < 3; ++nt) {
                    int col = nt * 16 + lrow;
                    if (col < OUTD)
                        C[(size_t)row * OUTD + col] = acc[mt][nt][j] + bb[nt];
                }
            }
        }
    }
}

// ---------------- launch ----------------

extern "C" void kernel_launch(void* const* d_in, const int* in_sizes, int n_in,
                              void* d_out, int out_size, void* d_ws, size_t ws_size,
                              hipStream_t stream) {
    const float* feat = (const float*)d_in[0];
    const int* src = (const int*)d_in[1];
    const int* dst = (const int*)d_in[2];
    const float* Ws0 = (const float*)d_in[3];
    const float* Wn0 = (const float*)d_in[4];
    const float* g0  = (const float*)d_in[5];
    const float* be0 = (const float*)d_in[6];
    const float* Ws1 = (const float*)d_in[7];
    const float* Wn1 = (const float*)d_in[8];
    const float* g1  = (const float*)d_in[9];
    const float* be1 = (const float*)d_in[10];
    const float* Ws2 = (const float*)d_in[11];
    const float* Wn2 = (const float*)d_in[12];
    const float* b2  = (const float*)d_in[13];
    float* out = (float*)d_out;

    char* ws = (char*)d_ws;
    int*   gcursor = (int*)(ws);                        // 512 B (zeroed)
    float* bn      = (float*)(ws + 512);                // 2048 B (zeroed)
    int*   row_off = (int*)(ws + 2560);                 // 400004 B -> ends 402564
    int*   partials= (int*)(ws + 402576);               // 512 B
    uint2* pairs   = (uint2*)(ws + 403200);             // 98*12288*8 = 9633792 -> ends 10036992
    int*   csr     = (int*)(ws + 10036992);             // 3200000 -> ends 13236992
    int*   deg     = (int*)(ws + 13236992);             // 400000 -> ends 13636992
    unsigned short* featb = (unsigned short*)(ws + 13636992);  // 25.6MB -> ends 39236992
    unsigned short* hnb   = (unsigned short*)(ws + 39236992);  // 25.6MB -> ends 64836992
    unsigned short* h0b   = (unsigned short*)(ws + 64836992);  // 25.6MB -> ends 90436992
    unsigned short* WT0   = (unsigned short*)(ws + 90436992);  // 65536
    unsigned short* WT1   = (unsigned short*)(ws + 90502528);  // 65536
    unsigned short* WT2   = (unsigned short*)(ws + 90568064);  // 24576 -> ends 90592640
    unsigned short* h1b   = featb;  // featb dead after layer-0 gemm

    hipMemsetAsync(ws, 0, 2560, stream);

    const int ABK = (N_EDGES + 4095) / 4096;     // 196
    const int AB = (N_NODES + 3) / 4;            // 25000
    const int MB = (N_NODES + 127) / 128;        // 782
    const int NE = (N_NODES * DIM) / 4 / 256;    // 12500
    const int NB8 = (N_NODES * DIM) / 8 / 256;   // 6250

    bucketA_kernel<<<ABK, 256, 0, stream>>>(src, dst, pairs, gcursor);
    phaseB_deg_kernel<<<NBKT, 256, 0, stream>>>(pairs, gcursor, deg);
    scan_partial_kernel<<<SCAN_NB, 256, 0, stream>>>(deg, partials);
    scan_partials_kernel<<<1, 128, 0, stream>>>(partials);
    scan_final_kernel<<<SCAN_NB, 256, 0, stream>>>(deg, partials, row_off);
    phaseC_fill_kernel<<<NBKT, 256, 0, stream>>>(pairs, gcursor, row_off, csr);

    convert_bf16_kernel<<<NE, 256, 0, stream>>>(feat, featb);
    wt_build_kernel<<<256, 256, 0, stream>>>(Ws0, Wn0, Ws1, Wn1, WT0, WT1);
    wt2_build_kernel<<<48, 256, 0, stream>>>(Ws2, Wn2, WT2);

    // layer 0
    agg_bf16_kernel<<<AB, 256, 0, stream>>>(featb, row_off, csr, hnb);
    gemm_mfma_kernel<<<MB, 256, 0, stream>>>(featb, hnb, WT0, h0b, bn + 0, bn + 128);
    bn_apply_bf16_kernel<<<NB8, 256, 0, stream>>>(h0b, bn + 0, bn + 128, g0, be0);

    // layer 1
    agg_bf16_kernel<<<AB, 256, 0, stream>>>(h0b, row_off, csr, hnb);
    gemm_mfma_kernel<<<MB, 256, 0, stream>>>(h0b, hnb, WT1, h1b, bn + 256, bn + 384);
    bn_apply_bf16_kernel<<<NB8, 256, 0, stream>>>(h1b, bn + 256, bn + 384, g1, be1);

    // layer 2
    agg_bf16_kernel<<<AB, 256, 0, stream>>>(h1b, row_off, csr, hnb);
    gemm_out_mfma_kernel<<<MB, 256, 0, stream>>>(h1b, hnb, WT2, b2, out);
}

// Round 11
// 279.922 us; speedup vs baseline: 34.3940x; 1.0002x over previous
//
#include <hip/hip_runtime.h>

#define N_NODES 100000
#define N_EDGES 800000
#define DIM 128
#define OUTD 40
#define OUTP 48  // padded to 3x16 MFMA col-tiles
#define BN_EPS 1e-5f
#define SCAN_NB 98   // ceil(100000/1024)
#define NBKT 98      // dst buckets of 1024 nodes
#define BKT_CAP 12288  // per-bucket pair capacity

typedef __bf16 bf16x8_t __attribute__((ext_vector_type(8)));
typedef float f32x4_t __attribute__((ext_vector_type(4)));
typedef float f32x2_t __attribute__((ext_vector_type(2)));

__device__ __forceinline__ unsigned short f2bf(float f) {
    unsigned int u = __builtin_bit_cast(unsigned int, f);
    u = (u + 0x7FFF + ((u >> 16) & 1)) >> 16;
    return (unsigned short)u;
}

// ---------------- CSR build: bucketed (XCD-local writes) ----------------

__global__ __launch_bounds__(256) void bucketA_kernel(const int* __restrict__ src,
                                                      const int* __restrict__ dst,
                                                      uint2* __restrict__ pairs,
                                                      int* __restrict__ gcursor) {
    __shared__ int cnt[NBKT], base[NBKT], rec[NBKT];
    const int t = threadIdx.x;
    if (t < NBKT) { cnt[t] = 0; rec[t] = 0; }
    __syncthreads();
    const int e0 = blockIdx.x * 4096 + t * 16;
    const bool active = (e0 + 16 <= N_EDGES);  // tail is 80x16 -> all-or-nothing
    int s[16], d[16];
    if (active) {
#pragma unroll
        for (int i = 0; i < 4; ++i) {
            int4 sv = *reinterpret_cast<const int4*>(&src[e0 + i * 4]);
            int4 dv = *reinterpret_cast<const int4*>(&dst[e0 + i * 4]);
            s[i * 4 + 0] = sv.x; s[i * 4 + 1] = sv.y; s[i * 4 + 2] = sv.z; s[i * 4 + 3] = sv.w;
            d[i * 4 + 0] = dv.x; d[i * 4 + 1] = dv.y; d[i * 4 + 2] = dv.z; d[i * 4 + 3] = dv.w;
        }
#pragma unroll
        for (int i = 0; i < 16; ++i) atomicAdd(&cnt[d[i] >> 10], 1);
    }
    __syncthreads();
    if (t < NBKT && cnt[t] > 0) base[t] = atomicAdd(&gcursor[t], cnt[t]);
    __syncthreads();
    if (active) {
#pragma unroll
        for (int i = 0; i < 16; ++i) {
            int bk = d[i] >> 10;
            int loc = atomicAdd(&rec[bk], 1);
            pairs[(size_t)bk * BKT_CAP + base[bk] + loc] = make_uint2((unsigned)s[i], (unsigned)d[i]);
        }
    }
}

__global__ __launch_bounds__(256) void phaseB_deg_kernel(const uint2* __restrict__ pairs,
                                                         const int* __restrict__ gcursor,
                                                         int* __restrict__ deg) {
    __shared__ int hist[1024];
    const int b = blockIdx.x;
    const int t = threadIdx.x;
#pragma unroll
    for (int j = 0; j < 4; ++j) hist[t * 4 + j] = 0;
    __syncthreads();
    const int m = gcursor[b];
    const uint2* __restrict__ bp = &pairs[(size_t)b * BKT_CAP];
    for (int i = t; i < m; i += 256) {
        uint2 p = bp[i];
        atomicAdd(&hist[p.y & 1023], 1);
    }
    __syncthreads();
    const int n0 = b << 10;
#pragma unroll
    for (int j = 0; j < 4; ++j) {
        int node = n0 + t * 4 + j;
        if (node < N_NODES) deg[node] = hist[t * 4 + j];
    }
}

__global__ __launch_bounds__(256) void scan_partial_kernel(const int* __restrict__ deg,
                                                           int* __restrict__ partials) {
    int b = blockIdx.x;
    int tid = threadIdx.x;
    int base = b * 1024 + tid * 4;
    int t0 = 0, t1 = 0, t2 = 0, t3 = 0;
    if (base + 3 < N_NODES) {
        int4 v = *reinterpret_cast<const int4*>(&deg[base]);
        t0 = v.x; t1 = v.y; t2 = v.z; t3 = v.w;
    } else {
        if (base + 0 < N_NODES) t0 = deg[base + 0];
        if (base + 1 < N_NODES) t1 = deg[base + 1];
        if (base + 2 < N_NODES) t2 = deg[base + 2];
        if (base + 3 < N_NODES) t3 = deg[base + 3];
    }
    int s = t0 + t1 + t2 + t3;
    __shared__ int red[256];
    red[tid] = s;
    __syncthreads();
    for (int o = 128; o; o >>= 1) {
        if (tid < o) red[tid] += red[tid + o];
        __syncthreads();
    }
    if (tid == 0) partials[b] = red[0];
}

__global__ __launch_bounds__(128) void scan_partials_kernel(int* __restrict__ partials) {
    __shared__ int s[128];
    int t = threadIdx.x;
    int v = (t < SCAN_NB) ? partials[t] : 0;
    s[t] = v;
    __syncthreads();
    for (int off = 1; off < 128; off <<= 1) {
        int u = (t >= off) ? s[t - off] : 0;
        __syncthreads();
        s[t] += u;
        __syncthreads();
    }
    if (t < SCAN_NB) partials[t] = s[t] - v;  // exclusive
}

__global__ __launch_bounds__(256) void scan_final_kernel(const int* __restrict__ deg,
                                                         const int* __restrict__ partials,
                                                         int* __restrict__ row_off) {
    int b = blockIdx.x;
    int tid = threadIdx.x;
    int base = b * 1024 + tid * 4;
    int t0 = 0, t1 = 0, t2 = 0, t3 = 0;
    if (base + 3 < N_NODES) {
        int4 v = *reinterpret_cast<const int4*>(&deg[base]);
        t0 = v.x; t1 = v.y; t2 = v.z; t3 = v.w;
    } else {
        if (base + 0 < N_NODES) t0 = deg[base + 0];
        if (base + 1 < N_NODES) t1 = deg[base + 1];
        if (base + 2 < N_NODES) t2 = deg[base + 2];
        if (base + 3 < N_NODES) t3 = deg[base + 3];
    }
    int s = t0 + t1 + t2 + t3;
    __shared__ int sc[256];
    sc[tid] = s;
    __syncthreads();
    for (int off = 1; off < 256; off <<= 1) {
        int u = (tid >= off) ? sc[tid - off] : 0;
        __syncthreads();
        sc[tid] += u;
        __syncthreads();
    }
    int run = partials[b] + sc[tid] - s;
    if (base + 0 < N_NODES) row_off[base + 0] = run; run += t0;
    if (base + 1 < N_NODES) row_off[base + 1] = run; run += t1;
    if (base + 2 < N_NODES) row_off[base + 2] = run; run += t2;
    if (base + 3 < N_NODES) row_off[base + 3] = run;
    if (b == 0 && tid == 0) row_off[N_NODES] = N_EDGES;
}

__global__ __launch_bounds__(256) void phaseC_fill_kernel(const uint2* __restrict__ pairs,
                                                          const int* __restrict__ gcursor,
                                                          const int* __restrict__ row_off,
                                                          int* __restrict__ csr_src) {
    __shared__ int cur[1024];
    const int b = blockIdx.x;
    const int t = threadIdx.x;
    const int n0 = b << 10;
#pragma unroll
    for (int j = 0; j < 4; ++j) {
        int node = n0 + t * 4 + j;
        if (node < N_NODES) cur[t * 4 + j] = row_off[node];
    }
    __syncthreads();
    const int m = gcursor[b];
    const uint2* __restrict__ bp = &pairs[(size_t)b * BKT_CAP];
    for (int i = t; i < m; i += 256) {
        uint2 p = bp[i];
        int pos = atomicAdd(&cur[p.y & 1023], 1);
        csr_src[pos] = (int)p.x;
    }
}

// ---------------- fp32 -> bf16 convert (feat) ----------------

__global__ __launch_bounds__(256) void convert_bf16_kernel(const float* __restrict__ in,
                                                           unsigned short* __restrict__ out) {
    size_t i = (size_t)(blockIdx.x * blockDim.x + threadIdx.x) * 4;
    float4 v = *reinterpret_cast<const float4*>(&in[i]);
    ushort4 o;
    o.x = f2bf(v.x); o.y = f2bf(v.y); o.z = f2bf(v.z); o.w = f2bf(v.w);
    *reinterpret_cast<ushort4*>(&out[i]) = o;
}

// ---------------- weight transpose+convert: WT[n][k] = W[k][n], bf16 ----------------

__global__ __launch_bounds__(256) void wt_build_kernel(const float* __restrict__ Ws0,
                                                       const float* __restrict__ Wn0,
                                                       const float* __restrict__ Ws1,
                                                       const float* __restrict__ Wn1,
                                                       unsigned short* __restrict__ WT0,
                                                       unsigned short* __restrict__ WT1) {
    int e = blockIdx.x * blockDim.x + threadIdx.x;  // 0..65535
    int layer = e >> 15;
    int r = e & 32767;
    int n = r >> 8;
    int k = r & 255;
    const float* Ws = layer ? Ws1 : Ws0;
    const float* Wn = layer ? Wn1 : Wn0;
    float v = (k < DIM) ? Ws[k * DIM + n] : Wn[(k - DIM) * DIM + n];
    unsigned short* WT = layer ? WT1 : WT0;
    WT[n * 256 + k] = f2bf(v);
}

__global__ __launch_bounds__(256) void wt2_build_kernel(const float* __restrict__ Ws2,
                                                        const float* __restrict__ Wn2,
                                                        unsigned short* __restrict__ WT2) {
    int e = blockIdx.x * blockDim.x + threadIdx.x;  // 0..12287
    int n = e >> 8;
    int k = e & 255;
    float v = 0.f;
    if (n < OUTD) v = (k < DIM) ? Ws2[k * OUTD + n] : Wn2[(k - DIM) * OUTD + n];
    WT2[n * 256 + k] = f2bf(v);
}

// ---------------- mean aggregation v3c: float2 packed accumulate ----------------
// Identical math to v3b (same f32 adds, same order); float2 lanes let the
// compiler emit v_pk_add_f32 (2 adds/inst). All shfls in converged code.

__device__ __forceinline__ void unpack_add2(f32x2_t* a, uint4 v) {
    f32x2_t t0, t1, t2, t3;
    t0[0] = __builtin_bit_cast(float, v.x << 16);
    t0[1] = __builtin_bit_cast(float, v.x & 0xFFFF0000u);
    t1[0] = __builtin_bit_cast(float, v.y << 16);
    t1[1] = __builtin_bit_cast(float, v.y & 0xFFFF0000u);
    t2[0] = __builtin_bit_cast(float, v.z << 16);
    t2[1] = __builtin_bit_cast(float, v.z & 0xFFFF0000u);
    t3[0] = __builtin_bit_cast(float, v.w << 16);
    t3[1] = __builtin_bit_cast(float, v.w & 0xFFFF0000u);
    a[0] += t0;
    a[1] += t1;
    a[2] += t2;
    a[3] += t3;
}

__global__ __launch_bounds__(256) void agg_bf16_kernel(const unsigned short* __restrict__ h,
                                                       const int* __restrict__ row_off,
                                                       const int* __restrict__ csr_src,
                                                       unsigned short* __restrict__ hn) {
    int wave = threadIdx.x >> 6;
    int lane = threadIdx.x & 63;
    int node = blockIdx.x * 4 + wave;
    if (node >= N_NODES) return;  // whole wave uniform
    int lo = row_off[node], hi = row_off[node + 1];
    const int grp = lane >> 4;
    const int l16 = lane & 15;
    f32x2_t a2[4];
#pragma unroll
    for (int q = 0; q < 4; ++q) a2[q] = (f32x2_t){0.f, 0.f};
    for (int base = lo; base < hi; base += 64) {      // uniform per wave
        int cnt = hi - base; if (cnt > 64) cnt = 64;  // uniform
        int li = (lane < cnt) ? lane : (cnt - 1);
        int idx = csr_src[base + li];  // defined on EVERY lane (clamped)
        int nIter = (cnt + 7) >> 3;    // uniform trip count -> converged shfls
        for (int k = 0; k < nIter; ++k) {
            int t0 = k * 8 + grp;
            int s0 = __shfl(idx, t0, 64);
            int s1 = __shfl(idx, t0 + 4, 64);
            if (t0 < cnt) {
                uint4 v0 = *reinterpret_cast<const uint4*>(&h[(size_t)s0 * DIM + l16 * 8]);
                unpack_add2(a2, v0);
            }
            if (t0 + 4 < cnt) {
                uint4 v1 = *reinterpret_cast<const uint4*>(&h[(size_t)s1 * DIM + l16 * 8]);
                unpack_add2(a2, v1);
            }
        }
    }
    float a[8] = {a2[0][0], a2[0][1], a2[1][0], a2[1][1],
                  a2[2][0], a2[2][1], a2[3][0], a2[3][1]};
    // converged butterfly across the 4 groups
#pragma unroll
    for (int q = 0; q < 8; ++q) {
        a[q] += __shfl_xor(a[q], 16, 64);
        a[q] += __shfl_xor(a[q], 32, 64);
    }
    if (grp == 0) {
        float rd = (hi > lo) ? 1.0f / (float)(hi - lo) : 1.0f;
        uint4 o;
        o.x = (unsigned int)f2bf(a[0] * rd) | ((unsigned int)f2bf(a[1] * rd) << 16);
        o.y = (unsigned int)f2bf(a[2] * rd) | ((unsigned int)f2bf(a[3] * rd) << 16);
        o.z = (unsigned int)f2bf(a[4] * rd) | ((unsigned int)f2bf(a[5] * rd) << 16);
        o.w = (unsigned int)f2bf(a[6] * rd) | ((unsigned int)f2bf(a[7] * rd) << 16);
        *reinterpret_cast<uint4*>(&hn[(size_t)node * DIM + l16 * 8]) = o;
    }
}

// ---------------- MFMA GEMM v2 + fused BN stats ----------------

__global__ __launch_bounds__(256) void gemm_mfma_kernel(const unsigned short* __restrict__ Ab,
                                                        const unsigned short* __restrict__ Hb,
                                                        const unsigned short* __restrict__ WT,
                                                        unsigned short* __restrict__ C,
                                                        float* __restrict__ bnsum,
                                                        float* __restrict__ bnsq) {
    __shared__ unsigned short wt[16384];  // 32 KB: one K-half [n=128][k=128], XOR-swizzled
    const int tid = threadIdx.x;
    const int wid = tid >> 6;
    const int lane = tid & 63;
    const int lrow = lane & 15;
    const int g = lane >> 4;
    const int r0 = blockIdx.x * 128 + wid * 32;

    bf16x8_t a[2][8];
#pragma unroll
    for (int ks = 0; ks < 8; ++ks) {
        const unsigned short* __restrict__ base = (ks < 4) ? Ab : Hb;
        const int kk = (ks & 3) * 32 + g * 8;
#pragma unroll
        for (int mt = 0; mt < 2; ++mt) {
            int row = r0 + mt * 16 + lrow;
            if (row >= N_NODES) row = N_NODES - 1;
            a[mt][ks] = *reinterpret_cast<const bf16x8_t*>(&base[(size_t)row * DIM + kk]);
        }
    }

    f32x4_t acc[2][8];
#pragma unroll
    for (int mt = 0; mt < 2; ++mt)
#pragma unroll
        for (int nt = 0; nt < 8; ++nt) acc[mt][nt] = (f32x4_t){0.f, 0.f, 0.f, 0.f};

#pragma unroll
    for (int hh = 0; hh < 2; ++hh) {
        if (hh) __syncthreads();
#pragma unroll
        for (int i = 0; i < 8; ++i) {
            int c = i * 256 + tid;
            int n = c >> 4;
            int koff = (c & 15) * 8;
            unsigned int waddr = ((unsigned int)(c * 16)) ^ (((unsigned int)(n & 7)) << 4);
            uint4 v = *reinterpret_cast<const uint4*>(&WT[n * 256 + hh * 128 + koff]);
            *reinterpret_cast<uint4*>(reinterpret_cast<char*>(wt) + waddr) = v;
        }
        __syncthreads();
#pragma unroll
        for (int ks = 0; ks < 4; ++ks) {
#pragma unroll
            for (int nt = 0; nt < 8; ++nt) {
                int n = nt * 16 + lrow;
                unsigned int raddr = ((unsigned int)(n * 256 + ks * 64 + g * 16)) ^ (((unsigned int)(n & 7)) << 4);
                bf16x8_t b = *reinterpret_cast<const bf16x8_t*>(reinterpret_cast<const char*>(wt) + raddr);
                acc[0][nt] = __builtin_amdgcn_mfma_f32_16x16x32_bf16(a[0][hh * 4 + ks], b, acc[0][nt], 0, 0, 0);
                acc[1][nt] = __builtin_amdgcn_mfma_f32_16x16x32_bf16(a[1][hh * 4 + ks], b, acc[1][nt], 0, 0, 0);
            }
        }
    }

    float ssum[8], ssq[8];
#pragma unroll
    for (int nt = 0; nt < 8; ++nt) { ssum[nt] = 0.f; ssq[nt] = 0.f; }
#pragma unroll
    for (int mt = 0; mt < 2; ++mt) {
#pragma unroll
        for (int j = 0; j < 4; ++j) {
            int row = r0 + mt * 16 + g * 4 + j;
            if (row < N_NODES) {
#pragma unroll
                for (int nt = 0; nt < 8; ++nt) {
                    float v = acc[mt][nt][j];
                    ssum[nt] += v;
                    ssq[nt] += v * v;
                }
            }
        }
    }
#pragma unroll
    for (int nt = 0; nt < 8; ++nt) {
        ssum[nt] += __shfl_xor(ssum[nt], 16, 64);
        ssum[nt] += __shfl_xor(ssum[nt], 32, 64);
        ssq[nt] += __shfl_xor(ssq[nt], 16, 64);
        ssq[nt] += __shfl_xor(ssq[nt], 32, 64);
    }
    __syncthreads();
    float* ls = reinterpret_cast<float*>(wt);        // [4][128]
    float* lq = ls + 512;                            // [4][128]
    if (g == 0) {
#pragma unroll
        for (int nt = 0; nt < 8; ++nt) {
            ls[wid * 128 + nt * 16 + lrow] = ssum[nt];
            lq[wid * 128 + nt * 16 + lrow] = ssq[nt];
        }
    }
    __syncthreads();
    if (tid < 128) {
        float s = ls[tid] + ls[128 + tid] + ls[256 + tid] + ls[384 + tid];
        float q = lq[tid] + lq[128 + tid] + lq[256 + tid] + lq[384 + tid];
        atomicAdd(&bnsum[tid], s);
        atomicAdd(&bnsq[tid], q);
    }

#pragma unroll
    for (int mt = 0; mt < 2; ++mt) {
#pragma unroll
        for (int j = 0; j < 4; ++j) {
            int row = r0 + mt * 16 + g * 4 + j;
            if (row < N_NODES) {
#pragma unroll
                for (int nt = 0; nt < 8; ++nt)
                    C[(size_t)row * DIM + nt * 16 + lrow] = f2bf(acc[mt][nt][j]);
            }
        }
    }
}

// ---------------- BatchNorm apply + ReLU, bf16 in-place ----------------

__global__ __launch_bounds__(256) void bn_apply_bf16_kernel(unsigned short* __restrict__ H,
                                                            const float* __restrict__ bnsum,
                                                            const float* __restrict__ bnsq,
                                                            const float* __restrict__ gamma,
                                                            const float* __restrict__ beta) {
    size_t idx = (size_t)(blockIdx.x * blockDim.x + threadIdx.x) * 8;
    const float invN = 1.0f / (float)N_NODES;
    int c = (int)(idx & (DIM - 1));
    uint4 v = *reinterpret_cast<const uint4*>(&H[idx]);
    unsigned int w[4] = {v.x, v.y, v.z, v.w};
    uint4 o;
    unsigned int* op = &o.x;
#pragma unroll
    for (int p = 0; p < 4; ++p) {
        float x0 = __builtin_bit_cast(float, w[p] << 16);
        float x1 = __builtin_bit_cast(float, w[p] & 0xFFFF0000u);
        int c0 = c + p * 2, c1 = c0 + 1;
        float mean0 = bnsum[c0] * invN, mean1 = bnsum[c1] * invN;
        float var0 = bnsq[c0] * invN - mean0 * mean0;
        float var1 = bnsq[c1] * invN - mean1 * mean1;
        float y0 = (x0 - mean0) * gamma[c0] * rsqrtf(var0 + BN_EPS) + beta[c0];
        float y1 = (x1 - mean1) * gamma[c1] * rsqrtf(var1 + BN_EPS) + beta[c1];
        y0 = y0 > 0.f ? y0 : 0.f;
        y1 = y1 > 0.f ? y1 : 0.f;
        op[p] = (unsigned int)f2bf(y0) | ((unsigned int)f2bf(y1) << 16);
    }
    *reinterpret_cast<uint4*>(&H[idx]) = o;
}

// ---------------- output layer (MFMA): C[N][40] = [Ab|Hb] @ WT2^T + b ----------------

__global__ __launch_bounds__(256) void gemm_out_mfma_kernel(const unsigned short* __restrict__ Ab,
                                                            const unsigned short* __restrict__ Hb,
                                                            const unsigned short* __restrict__ WT2,
                                                            const float* __restrict__ bias,
                                                            float* __restrict__ C) {
    __shared__ unsigned short wt[OUTP * 256];  // 24 KB, XOR-swizzled
    const int tid = threadIdx.x;

#pragma unroll
    for (int i = 0; i < 6; ++i) {
        int c = i * 256 + tid;
        int n = c >> 5;
        unsigned int waddr = ((unsigned int)(c * 16)) ^ (((unsigned int)(n & 7)) << 4);
        uint4 v = *reinterpret_cast<const uint4*>(&WT2[c * 8]);
        *reinterpret_cast<uint4*>(reinterpret_cast<char*>(wt) + waddr) = v;
    }
    __syncthreads();

    const int wid = tid >> 6;
    const int lane = tid & 63;
    const int lrow = lane & 15;
    const int g = lane >> 4;
    const int r0 = blockIdx.x * 128 + wid * 32;

    bf16x8_t a[2][8];
#pragma unroll
    for (int ks = 0; ks < 8; ++ks) {
        const unsigned short* __restrict__ base = (ks < 4) ? Ab : Hb;
        const int kk = (ks & 3) * 32 + g * 8;
#pragma unroll
        for (int mt = 0; mt < 2; ++mt) {
            int row = r0 + mt * 16 + lrow;
            if (row >= N_NODES) row = N_NODES - 1;
            a[mt][ks] = *reinterpret_cast<const bf16x8_t*>(&base[(size_t)row * DIM + kk]);
        }
    }

    f32x4_t acc[2][3];
#pragma unroll
    for (int mt = 0; mt < 2; ++mt)
#pragma unroll
        for (int nt = 0; nt < 3; ++nt) acc[mt][nt] = (f32x4_t){0.f, 0.f, 0.f, 0.f};

#pragma unroll
    for (int ks = 0; ks < 8; ++ks) {
#pragma unroll
        for (int nt = 0; nt < 3; ++nt) {
            int n = nt * 16 + lrow;
            unsigned int raddr = ((unsigned int)(n * 512 + ks * 64 + g * 16)) ^ (((unsigned int)(n & 7)) << 4);
            bf16x8_t b = *reinterpret_cast<const bf16x8_t*>(reinterpret_cast<const char*>(wt) + raddr);
            acc[0][nt] = __builtin_amdgcn_mfma_f32_16x16x32_bf16(a[0][ks], b, acc[0][nt], 0, 0, 0);
            acc[1][nt] = __builtin_amdgcn_mfma_f32_16x16x32_bf16(a[1][ks], b, acc[1][nt], 0, 0, 0);
        }
    }

    float bb[3];
#pragma unroll
    for (int nt = 0; nt < 3; ++nt) {
        int col = nt * 16 + lrow;
        bb[nt] = (col < OUTD) ? bias[col] : 0.f;
    }

#pragma unroll
    for (int mt = 0; mt < 2; ++mt) {
#pragma unroll
        for (int j = 0; j < 4; ++j) {
            int row = r0 + mt * 16 + g * 4 + j;
            if (row < N_NODES) {
#pragma unroll
                for (int nt = 0; nt < 3; ++nt) {
                    int col = nt * 16 + lrow;
                    if (col < OUTD)
                        C[(size_t)row * OUTD + col] = acc[mt][nt][j] + bb[nt];
                }
            }
        }
    }
}

// ---------------- launch ----------------

extern "C" void kernel_launch(void* const* d_in, const int* in_sizes, int n_in,
                              void* d_out, int out_size, void* d_ws, size_t ws_size,
                              hipStream_t stream) {
    const float* feat = (const float*)d_in[0];
    const int* src = (const int*)d_in[1];
    const int* dst = (const int*)d_in[2];
    const float* Ws0 = (const float*)d_in[3];
    const float* Wn0 = (const float*)d_in[4];
    const float* g0  = (const float*)d_in[5];
    const float* be0 = (const float*)d_in[6];
    const float* Ws1 = (const float*)d_in[7];
    const float* Wn1 = (const float*)d_in[8];
    const float* g1  = (const float*)d_in[9];
    const float* be1 = (const float*)d_in[10];
    const float* Ws2 = (const float*)d_in[11];
    const float* Wn2 = (const float*)d_in[12];
    const float* b2  = (const float*)d_in[13];
    float* out = (float*)d_out;

    char* ws = (char*)d_ws;
    int*   gcursor = (int*)(ws);                        // 512 B (zeroed)
    float* bn      = (float*)(ws + 512);                // 2048 B (zeroed)
    int*   row_off = (int*)(ws + 2560);                 // 400004 B
    int*   partials= (int*)(ws + 402576);               // 512 B
    uint2* pairs   = (uint2*)(ws + 403200);             // 9633792 B
    int*   csr     = (int*)(ws + 10036992);             // 3200000 B
    int*   deg     = (int*)(ws + 13236992);             // 400000 B
    unsigned short* featb = (unsigned short*)(ws + 13636992);  // 25.6MB
    unsigned short* hnb   = (unsigned short*)(ws + 39236992);  // 25.6MB
    unsigned short* h0b   = (unsigned short*)(ws + 64836992);  // 25.6MB
    unsigned short* WT0   = (unsigned short*)(ws + 90436992);  // 65536
    unsigned short* WT1   = (unsigned short*)(ws + 90502528);  // 65536
    unsigned short* WT2   = (unsigned short*)(ws + 90568064);  // 24576
    unsigned short* h1b   = featb;  // featb dead after layer-0 gemm

    hipMemsetAsync(ws, 0, 2560, stream);

    const int ABK = (N_EDGES + 4095) / 4096;     // 196
    const int AB = (N_NODES + 3) / 4;            // 25000
    const int MB = (N_NODES + 127) / 128;        // 782
    const int NE = (N_NODES * DIM) / 4 / 256;    // 12500
    const int NB8 = (N_NODES * DIM) / 8 / 256;   // 6250

    bucketA_kernel<<<ABK, 256, 0, stream>>>(src, dst, pairs, gcursor);
    phaseB_deg_kernel<<<NBKT, 256, 0, stream>>>(pairs, gcursor, deg);
    scan_partial_kernel<<<SCAN_NB, 256, 0, stream>>>(deg, partials);
    scan_partials_kernel<<<1, 128, 0, stream>>>(partials);
    scan_final_kernel<<<SCAN_NB, 256, 0, stream>>>(deg, partials, row_off);
    phaseC_fill_kernel<<<NBKT, 256, 0, stream>>>(pairs, gcursor, row_off, csr);

    convert_bf16_kernel<<<NE, 256, 0, stream>>>(feat, featb);
    wt_build_kernel<<<256, 256, 0, stream>>>(Ws0, Wn0, Ws1, Wn1, WT0, WT1);
    wt2_build_kernel<<<48, 256, 0, stream>>>(Ws2, Wn2, WT2);

    // layer 0
    agg_bf16_kernel<<<AB, 256, 0, stream>>>(featb, row_off, csr, hnb);
    gemm_mfma_kernel<<<MB, 256, 0, stream>>>(featb, hnb, WT0, h0b, bn + 0, bn + 128);
    bn_apply_bf16_kernel<<<NB8, 256, 0, stream>>>(h0b, bn + 0, bn + 128, g0, be0);

    // layer 1
    agg_bf16_kernel<<<AB, 256, 0, stream>>>(h0b, row_off, csr, hnb);
    gemm_mfma_kernel<<<MB, 256, 0, stream>>>(h0b, hnb, WT1, h1b, bn + 256, bn + 384);
    bn_apply_bf16_kernel<<<NB8, 256, 0, stream>>>(h1b, bn + 256, bn + 384, g1, be1);

    // layer 2
    agg_bf16_kernel<<<AB, 256, 0, stream>>>(h1b, row_off, csr, hnb);
    gemm_out_mfma_kernel<<<MB, 256, 0, stream>>>(h1b, hnb, WT2, b2, out);
}

// Round 12
// 264.078 us; speedup vs baseline: 36.4576x; 1.0600x over previous
//
#include <hip/hip_runtime.h>

#define N_NODES 100000
#define N_EDGES 800000
#define DIM 128
#define OUTD 40
#define OUTP 48  // padded to 3x16 MFMA col-tiles
#define BN_EPS 1e-5f
#define SCAN_NB 98   // ceil(100000/1024)
#define NBKT 98      // dst buckets of 1024 nodes
#define BKT_CAP 12288  // per-bucket pair capacity

typedef __bf16 bf16x8_t __attribute__((ext_vector_type(8)));
typedef float f32x4_t __attribute__((ext_vector_type(4)));
typedef float f32x2_t __attribute__((ext_vector_type(2)));

__device__ __forceinline__ unsigned short f2bf(float f) {
    unsigned int u = __builtin_bit_cast(unsigned int, f);
    u = (u + 0x7FFF + ((u >> 16) & 1)) >> 16;
    return (unsigned short)u;
}

// ---------------- CSR build: bucketed (XCD-local writes) ----------------

__global__ __launch_bounds__(256) void bucketA_kernel(const int* __restrict__ src,
                                                      const int* __restrict__ dst,
                                                      uint2* __restrict__ pairs,
                                                      int* __restrict__ gcursor) {
    __shared__ int cnt[NBKT], base[NBKT], rec[NBKT];
    const int t = threadIdx.x;
    if (t < NBKT) { cnt[t] = 0; rec[t] = 0; }
    __syncthreads();
    const int e0 = blockIdx.x * 4096 + t * 16;
    const bool active = (e0 + 16 <= N_EDGES);  // tail is 80x16 -> all-or-nothing
    int s[16], d[16];
    if (active) {
#pragma unroll
        for (int i = 0; i < 4; ++i) {
            int4 sv = *reinterpret_cast<const int4*>(&src[e0 + i * 4]);
            int4 dv = *reinterpret_cast<const int4*>(&dst[e0 + i * 4]);
            s[i * 4 + 0] = sv.x; s[i * 4 + 1] = sv.y; s[i * 4 + 2] = sv.z; s[i * 4 + 3] = sv.w;
            d[i * 4 + 0] = dv.x; d[i * 4 + 1] = dv.y; d[i * 4 + 2] = dv.z; d[i * 4 + 3] = dv.w;
        }
#pragma unroll
        for (int i = 0; i < 16; ++i) atomicAdd(&cnt[d[i] >> 10], 1);
    }
    __syncthreads();
    if (t < NBKT && cnt[t] > 0) base[t] = atomicAdd(&gcursor[t], cnt[t]);
    __syncthreads();
    if (active) {
#pragma unroll
        for (int i = 0; i < 16; ++i) {
            int bk = d[i] >> 10;
            int loc = atomicAdd(&rec[bk], 1);
            pairs[(size_t)bk * BKT_CAP + base[bk] + loc] = make_uint2((unsigned)s[i], (unsigned)d[i]);
        }
    }
}

__global__ __launch_bounds__(256) void phaseB_deg_kernel(const uint2* __restrict__ pairs,
                                                         const int* __restrict__ gcursor,
                                                         int* __restrict__ deg) {
    __shared__ int hist[1024];
    const int b = blockIdx.x;
    const int t = threadIdx.x;
#pragma unroll
    for (int j = 0; j < 4; ++j) hist[t * 4 + j] = 0;
    __syncthreads();
    const int m = gcursor[b];
    const uint2* __restrict__ bp = &pairs[(size_t)b * BKT_CAP];
    for (int i = t; i < m; i += 256) {
        uint2 p = bp[i];
        atomicAdd(&hist[p.y & 1023], 1);
    }
    __syncthreads();
    const int n0 = b << 10;
#pragma unroll
    for (int j = 0; j < 4; ++j) {
        int node = n0 + t * 4 + j;
        if (node < N_NODES) deg[node] = hist[t * 4 + j];
    }
}

__global__ __launch_bounds__(256) void scan_partial_kernel(const int* __restrict__ deg,
                                                           int* __restrict__ partials) {
    int b = blockIdx.x;
    int tid = threadIdx.x;
    int base = b * 1024 + tid * 4;
    int t0 = 0, t1 = 0, t2 = 0, t3 = 0;
    if (base + 3 < N_NODES) {
        int4 v = *reinterpret_cast<const int4*>(&deg[base]);
        t0 = v.x; t1 = v.y; t2 = v.z; t3 = v.w;
    } else {
        if (base + 0 < N_NODES) t0 = deg[base + 0];
        if (base + 1 < N_NODES) t1 = deg[base + 1];
        if (base + 2 < N_NODES) t2 = deg[base + 2];
        if (base + 3 < N_NODES) t3 = deg[base + 3];
    }
    int s = t0 + t1 + t2 + t3;
    __shared__ int red[256];
    red[tid] = s;
    __syncthreads();
    for (int o = 128; o; o >>= 1) {
        if (tid < o) red[tid] += red[tid + o];
        __syncthreads();
    }
    if (tid == 0) partials[b] = red[0];
}

__global__ __launch_bounds__(128) void scan_partials_kernel(int* __restrict__ partials) {
    __shared__ int s[128];
    int t = threadIdx.x;
    int v = (t < SCAN_NB) ? partials[t] : 0;
    s[t] = v;
    __syncthreads();
    for (int off = 1; off < 128; off <<= 1) {
        int u = (t >= off) ? s[t - off] : 0;
        __syncthreads();
        s[t] += u;
        __syncthreads();
    }
    if (t < SCAN_NB) partials[t] = s[t] - v;  // exclusive
}

__global__ __launch_bounds__(256) void scan_final_kernel(const int* __restrict__ deg,
                                                         const int* __restrict__ partials,
                                                         int* __restrict__ row_off) {
    int b = blockIdx.x;
    int tid = threadIdx.x;
    int base = b * 1024 + tid * 4;
    int t0 = 0, t1 = 0, t2 = 0, t3 = 0;
    if (base + 3 < N_NODES) {
        int4 v = *reinterpret_cast<const int4*>(&deg[base]);
        t0 = v.x; t1 = v.y; t2 = v.z; t3 = v.w;
    } else {
        if (base + 0 < N_NODES) t0 = deg[base + 0];
        if (base + 1 < N_NODES) t1 = deg[base + 1];
        if (base + 2 < N_NODES) t2 = deg[base + 2];
        if (base + 3 < N_NODES) t3 = deg[base + 3];
    }
    int s = t0 + t1 + t2 + t3;
    __shared__ int sc[256];
    sc[tid] = s;
    __syncthreads();
    for (int off = 1; off < 256; off <<= 1) {
        int u = (tid >= off) ? sc[tid - off] : 0;
        __syncthreads();
        sc[tid] += u;
        __syncthreads();
    }
    int run = partials[b] + sc[tid] - s;
    if (base + 0 < N_NODES) row_off[base + 0] = run; run += t0;
    if (base + 1 < N_NODES) row_off[base + 1] = run; run += t1;
    if (base + 2 < N_NODES) row_off[base + 2] = run; run += t2;
    if (base + 3 < N_NODES) row_off[base + 3] = run;
    if (b == 0 && tid == 0) row_off[N_NODES] = N_EDGES;
}

__global__ __launch_bounds__(256) void phaseC_fill_kernel(const uint2* __restrict__ pairs,
                                                          const int* __restrict__ gcursor,
                                                          const int* __restrict__ row_off,
                                                          int* __restrict__ csr_src) {
    __shared__ int cur[1024];
    const int b = blockIdx.x;
    const int t = threadIdx.x;
    const int n0 = b << 10;
#pragma unroll
    for (int j = 0; j < 4; ++j) {
        int node = n0 + t * 4 + j;
        if (node < N_NODES) cur[t * 4 + j] = row_off[node];
    }
    __syncthreads();
    const int m = gcursor[b];
    const uint2* __restrict__ bp = &pairs[(size_t)b * BKT_CAP];
    for (int i = t; i < m; i += 256) {
        uint2 p = bp[i];
        int pos = atomicAdd(&cur[p.y & 1023], 1);
        csr_src[pos] = (int)p.x;
    }
}

// ---------------- fp32 -> bf16 convert (feat) ----------------

__global__ __launch_bounds__(256) void convert_bf16_kernel(const float* __restrict__ in,
                                                           unsigned short* __restrict__ out) {
    size_t i = (size_t)(blockIdx.x * blockDim.x + threadIdx.x) * 4;
    float4 v = *reinterpret_cast<const float4*>(&in[i]);
    ushort4 o;
    o.x = f2bf(v.x); o.y = f2bf(v.y); o.z = f2bf(v.z); o.w = f2bf(v.w);
    *reinterpret_cast<ushort4*>(&out[i]) = o;
}

// ---------------- weight transpose+convert: WT[n][k] = W[k][n], bf16 ----------------

__global__ __launch_bounds__(256) void wt_build_kernel(const float* __restrict__ Ws0,
                                                       const float* __restrict__ Wn0,
                                                       const float* __restrict__ Ws1,
                                                       const float* __restrict__ Wn1,
                                                       unsigned short* __restrict__ WT0,
                                                       unsigned short* __restrict__ WT1) {
    int e = blockIdx.x * blockDim.x + threadIdx.x;  // 0..65535
    int layer = e >> 15;
    int r = e & 32767;
    int n = r >> 8;
    int k = r & 255;
    const float* Ws = layer ? Ws1 : Ws0;
    const float* Wn = layer ? Wn1 : Wn0;
    float v = (k < DIM) ? Ws[k * DIM + n] : Wn[(k - DIM) * DIM + n];
    unsigned short* WT = layer ? WT1 : WT0;
    WT[n * 256 + k] = f2bf(v);
}

__global__ __launch_bounds__(256) void wt2_build_kernel(const float* __restrict__ Ws2,
                                                        const float* __restrict__ Wn2,
                                                        unsigned short* __restrict__ WT2) {
    int e = blockIdx.x * blockDim.x + threadIdx.x;  // 0..12287
    int n = e >> 8;
    int k = e & 255;
    float v = 0.f;
    if (n < OUTD) v = (k < DIM) ? Ws2[k * OUTD + n] : Wn2[(k - DIM) * OUTD + n];
    WT2[n * 256 + k] = f2bf(v);
}

// ---------------- mean aggregation v5: node-per-16-lane-group ----------------
// 4 nodes per wave (group g owns node), 16 lanes cover the full 256B row.
// No butterfly, no broadcast shfls, all 64 lanes write. Neighbor loop bound
// is wave-uniform (2-shfl converged max); loads hoisted + clamped so 4
// gathers issue back-to-back (unroll-4 -> 16 independent chains/wave).

__device__ __forceinline__ void unpack_add2(f32x2_t* a, uint4 v) {
    f32x2_t t0, t1, t2, t3;
    t0[0] = __builtin_bit_cast(float, v.x << 16);
    t0[1] = __builtin_bit_cast(float, v.x & 0xFFFF0000u);
    t1[0] = __builtin_bit_cast(float, v.y << 16);
    t1[1] = __builtin_bit_cast(float, v.y & 0xFFFF0000u);
    t2[0] = __builtin_bit_cast(float, v.z << 16);
    t2[1] = __builtin_bit_cast(float, v.z & 0xFFFF0000u);
    t3[0] = __builtin_bit_cast(float, v.w << 16);
    t3[1] = __builtin_bit_cast(float, v.w & 0xFFFF0000u);
    a[0] += t0;
    a[1] += t1;
    a[2] += t2;
    a[3] += t3;
}

__global__ __launch_bounds__(256) void agg_bf16_kernel(const unsigned short* __restrict__ h,
                                                       const int* __restrict__ row_off,
                                                       const int* __restrict__ csr_src,
                                                       unsigned short* __restrict__ hn) {
    const int wave = threadIdx.x >> 6;
    const int lane = threadIdx.x & 63;
    const int grp = lane >> 4;     // node-within-wave (group owns node)
    const int l16 = lane & 15;     // 16B slice of the 256B row
    const int node = blockIdx.x * 16 + wave * 4 + grp;  // 100000 = 6250*16, no tail
    const int lo = row_off[node];
    const int hi = row_off[node + 1];
    const int cnt = hi - lo;
    // wave-uniform neighbor-loop bound (converged shfls)
    int mc = cnt;
    mc = max(mc, __shfl_xor(mc, 16, 64));
    mc = max(mc, __shfl_xor(mc, 32, 64));

    f32x2_t a2[4];
#pragma unroll
    for (int q = 0; q < 4; ++q) a2[q] = (f32x2_t){0.f, 0.f};
    const unsigned rowoff = (unsigned)l16 * 8u;

    for (int t = 0; t < mc; t += 4) {
        const bool p0 = t + 0 < cnt, p1 = t + 1 < cnt;
        const bool p2 = t + 2 < cnt, p3 = t + 3 < cnt;
        // group-uniform index loads; clamp offsets into the node's own range
        int i0 = csr_src[lo + min(t + 0, cnt > 0 ? cnt - 1 : 0)];
        int i1 = csr_src[lo + min(t + 1, cnt > 0 ? cnt - 1 : 0)];
        int i2 = csr_src[lo + min(t + 2, cnt > 0 ? cnt - 1 : 0)];
        int i3 = csr_src[lo + min(t + 3, cnt > 0 ? cnt - 1 : 0)];
        // safety clamp (deg-0 groups read garbage indices; never accumulated)
        i0 = min(max(i0, 0), N_NODES - 1);
        i1 = min(max(i1, 0), N_NODES - 1);
        i2 = min(max(i2, 0), N_NODES - 1);
        i3 = min(max(i3, 0), N_NODES - 1);
        // all 4 gathers issue unconditionally -> 4 in flight
        uint4 v0 = *reinterpret_cast<const uint4*>(&h[(size_t)i0 * DIM + rowoff]);
        uint4 v1 = *reinterpret_cast<const uint4*>(&h[(size_t)i1 * DIM + rowoff]);
        uint4 v2 = *reinterpret_cast<const uint4*>(&h[(size_t)i2 * DIM + rowoff]);
        uint4 v3 = *reinterpret_cast<const uint4*>(&h[(size_t)i3 * DIM + rowoff]);
        if (p0) unpack_add2(a2, v0);
        if (p1) unpack_add2(a2, v1);
        if (p2) unpack_add2(a2, v2);
        if (p3) unpack_add2(a2, v3);
    }

    const float rd = (cnt > 0) ? 1.0f / (float)cnt : 1.0f;
    uint4 o;
    o.x = (unsigned int)f2bf(a2[0][0] * rd) | ((unsigned int)f2bf(a2[0][1] * rd) << 16);
    o.y = (unsigned int)f2bf(a2[1][0] * rd) | ((unsigned int)f2bf(a2[1][1] * rd) << 16);
    o.z = (unsigned int)f2bf(a2[2][0] * rd) | ((unsigned int)f2bf(a2[2][1] * rd) << 16);
    o.w = (unsigned int)f2bf(a2[3][0] * rd) | ((unsigned int)f2bf(a2[3][1] * rd) << 16);
    *reinterpret_cast<uint4*>(&hn[(size_t)node * DIM + rowoff]) = o;
}

// ---------------- MFMA GEMM v2 + fused BN stats ----------------

__global__ __launch_bounds__(256) void gemm_mfma_kernel(const unsigned short* __restrict__ Ab,
                                                        const unsigned short* __restrict__ Hb,
                                                        const unsigned short* __restrict__ WT,
                                                        unsigned short* __restrict__ C,
                                                        float* __restrict__ bnsum,
                                                        float* __restrict__ bnsq) {
    __shared__ unsigned short wt[16384];  // 32 KB: one K-half [n=128][k=128], XOR-swizzled
    const int tid = threadIdx.x;
    const int wid = tid >> 6;
    const int lane = tid & 63;
    const int lrow = lane & 15;
    const int g = lane >> 4;
    const int r0 = blockIdx.x * 128 + wid * 32;

    bf16x8_t a[2][8];
#pragma unroll
    for (int ks = 0; ks < 8; ++ks) {
        const unsigned short* __restrict__ base = (ks < 4) ? Ab : Hb;
        const int kk = (ks & 3) * 32 + g * 8;
#pragma unroll
        for (int mt = 0; mt < 2; ++mt) {
            int row = r0 + mt * 16 + lrow;
            if (row >= N_NODES) row = N_NODES - 1;
            a[mt][ks] = *reinterpret_cast<const bf16x8_t*>(&base[(size_t)row * DIM + kk]);
        }
    }

    f32x4_t acc[2][8];
#pragma unroll
    for (int mt = 0; mt < 2; ++mt)
#pragma unroll
        for (int nt = 0; nt < 8; ++nt) acc[mt][nt] = (f32x4_t){0.f, 0.f, 0.f, 0.f};

#pragma unroll
    for (int hh = 0; hh < 2; ++hh) {
        if (hh) __syncthreads();
#pragma unroll
        for (int i = 0; i < 8; ++i) {
            int c = i * 256 + tid;
            int n = c >> 4;
            int koff = (c & 15) * 8;
            unsigned int waddr = ((unsigned int)(c * 16)) ^ (((unsigned int)(n & 7)) << 4);
            uint4 v = *reinterpret_cast<const uint4*>(&WT[n * 256 + hh * 128 + koff]);
            *reinterpret_cast<uint4*>(reinterpret_cast<char*>(wt) + waddr) = v;
        }
        __syncthreads();
#pragma unroll
        for (int ks = 0; ks < 4; ++ks) {
#pragma unroll
            for (int nt = 0; nt < 8; ++nt) {
                int n = nt * 16 + lrow;
                unsigned int raddr = ((unsigned int)(n * 256 + ks * 64 + g * 16)) ^ (((unsigned int)(n & 7)) << 4);
                bf16x8_t b = *reinterpret_cast<const bf16x8_t*>(reinterpret_cast<const char*>(wt) + raddr);
                acc[0][nt] = __builtin_amdgcn_mfma_f32_16x16x32_bf16(a[0][hh * 4 + ks], b, acc[0][nt], 0, 0, 0);
                acc[1][nt] = __builtin_amdgcn_mfma_f32_16x16x32_bf16(a[1][hh * 4 + ks], b, acc[1][nt], 0, 0, 0);
            }
        }
    }

    float ssum[8], ssq[8];
#pragma unroll
    for (int nt = 0; nt < 8; ++nt) { ssum[nt] = 0.f; ssq[nt] = 0.f; }
#pragma unroll
    for (int mt = 0; mt < 2; ++mt) {
#pragma unroll
        for (int j = 0; j < 4; ++j) {
            int row = r0 + mt * 16 + g * 4 + j;
            if (row < N_NODES) {
#pragma unroll
                for (int nt = 0; nt < 8; ++nt) {
                    float v = acc[mt][nt][j];
                    ssum[nt] += v;
                    ssq[nt] += v * v;
                }
            }
        }
    }
#pragma unroll
    for (int nt = 0; nt < 8; ++nt) {
        ssum[nt] += __shfl_xor(ssum[nt], 16, 64);
        ssum[nt] += __shfl_xor(ssum[nt], 32, 64);
        ssq[nt] += __shfl_xor(ssq[nt], 16, 64);
        ssq[nt] += __shfl_xor(ssq[nt], 32, 64);
    }
    __syncthreads();
    float* ls = reinterpret_cast<float*>(wt);        // [4][128]
    float* lq = ls + 512;                            // [4][128]
    if (g == 0) {
#pragma unroll
        for (int nt = 0; nt < 8; ++nt) {
            ls[wid * 128 + nt * 16 + lrow] = ssum[nt];
            lq[wid * 128 + nt * 16 + lrow] = ssq[nt];
        }
    }
    __syncthreads();
    if (tid < 128) {
        float s = ls[tid] + ls[128 + tid] + ls[256 + tid] + ls[384 + tid];
        float q = lq[tid] + lq[128 + tid] + lq[256 + tid] + lq[384 + tid];
        atomicAdd(&bnsum[tid], s);
        atomicAdd(&bnsq[tid], q);
    }

#pragma unroll
    for (int mt = 0; mt < 2; ++mt) {
#pragma unroll
        for (int j = 0; j < 4; ++j) {
            int row = r0 + mt * 16 + g * 4 + j;
            if (row < N_NODES) {
#pragma unroll
                for (int nt = 0; nt < 8; ++nt)
                    C[(size_t)row * DIM + nt * 16 + lrow] = f2bf(acc[mt][nt][j]);
            }
        }
    }
}

// ---------------- BatchNorm apply + ReLU, bf16 in-place ----------------

__global__ __launch_bounds__(256) void bn_apply_bf16_kernel(unsigned short* __restrict__ H,
                                                            const float* __restrict__ bnsum,
                                                            const float* __restrict__ bnsq,
                                                            const float* __restrict__ gamma,
                                                            const float* __restrict__ beta) {
    size_t idx = (size_t)(blockIdx.x * blockDim.x + threadIdx.x) * 8;
    const float invN = 1.0f / (float)N_NODES;
    int c = (int)(idx & (DIM - 1));
    uint4 v = *reinterpret_cast<const uint4*>(&H[idx]);
    unsigned int w[4] = {v.x, v.y, v.z, v.w};
    uint4 o;
    unsigned int* op = &o.x;
#pragma unroll
    for (int p = 0; p < 4; ++p) {
        float x0 = __builtin_bit_cast(float, w[p] << 16);
        float x1 = __builtin_bit_cast(float, w[p] & 0xFFFF0000u);
        int c0 = c + p * 2, c1 = c0 + 1;
        float mean0 = bnsum[c0] * invN, mean1 = bnsum[c1] * invN;
        float var0 = bnsq[c0] * invN - mean0 * mean0;
        float var1 = bnsq[c1] * invN - mean1 * mean1;
        float y0 = (x0 - mean0) * gamma[c0] * rsqrtf(var0 + BN_EPS) + beta[c0];
        float y1 = (x1 - mean1) * gamma[c1] * rsqrtf(var1 + BN_EPS) + beta[c1];
        y0 = y0 > 0.f ? y0 : 0.f;
        y1 = y1 > 0.f ? y1 : 0.f;
        op[p] = (unsigned int)f2bf(y0) | ((unsigned int)f2bf(y1) << 16);
    }
    *reinterpret_cast<uint4*>(&H[idx]) = o;
}

// ---------------- output layer (MFMA): C[N][40] = [Ab|Hb] @ WT2^T + b ----------------

__global__ __launch_bounds__(256) void gemm_out_mfma_kernel(const unsigned short* __restrict__ Ab,
                                                            const unsigned short* __restrict__ Hb,
                                                            const unsigned short* __restrict__ WT2,
                                                            const float* __restrict__ bias,
                                                            float* __restrict__ C) {
    __shared__ unsigned short wt[OUTP * 256];  // 24 KB, XOR-swizzled
    const int tid = threadIdx.x;

#pragma unroll
    for (int i = 0; i < 6; ++i) {
        int c = i * 256 + tid;
        int n = c >> 5;
        unsigned int waddr = ((unsigned int)(c * 16)) ^ (((unsigned int)(n & 7)) << 4);
        uint4 v = *reinterpret_cast<const uint4*>(&WT2[c * 8]);
        *reinterpret_cast<uint4*>(reinterpret_cast<char*>(wt) + waddr) = v;
    }
    __syncthreads();

    const int wid = tid >> 6;
    const int lane = tid & 63;
    const int lrow = lane & 15;
    const int g = lane >> 4;
    const int r0 = blockIdx.x * 128 + wid * 32;

    bf16x8_t a[2][8];
#pragma unroll
    for (int ks = 0; ks < 8; ++ks) {
        const unsigned short* __restrict__ base = (ks < 4) ? Ab : Hb;
        const int kk = (ks & 3) * 32 + g * 8;
#pragma unroll
        for (int mt = 0; mt < 2; ++mt) {
            int row = r0 + mt * 16 + lrow;
            if (row >= N_NODES) row = N_NODES - 1;
            a[mt][ks] = *reinterpret_cast<const bf16x8_t*>(&base[(size_t)row * DIM + kk]);
        }
    }

    f32x4_t acc[2][3];
#pragma unroll
    for (int mt = 0; mt < 2; ++mt)
#pragma unroll
        for (int nt = 0; nt < 3; ++nt) acc[mt][nt] = (f32x4_t){0.f, 0.f, 0.f, 0.f};

#pragma unroll
    for (int ks = 0; ks < 8; ++ks) {
#pragma unroll
        for (int nt = 0; nt < 3; ++nt) {
            int n = nt * 16 + lrow;
            unsigned int raddr = ((unsigned int)(n * 512 + ks * 64 + g * 16)) ^ (((unsigned int)(n & 7)) << 4);
            bf16x8_t b = *reinterpret_cast<const bf16x8_t*>(reinterpret_cast<const char*>(wt) + raddr);
            acc[0][nt] = __builtin_amdgcn_mfma_f32_16x16x32_bf16(a[0][ks], b, acc[0][nt], 0, 0, 0);
            acc[1][nt] = __builtin_amdgcn_mfma_f32_16x16x32_bf16(a[1][ks], b, acc[1][nt], 0, 0, 0);
        }
    }

    float bb[3];
#pragma unroll
    for (int nt = 0; nt < 3; ++nt) {
        int col = nt * 16 + lrow;
        bb[nt] = (col < OUTD) ? bias[col] : 0.f;
    }

#pragma unroll
    for (int mt = 0; mt < 2; ++mt) {
#pragma unroll
        for (int j = 0; j < 4; ++j) {
            int row = r0 + mt * 16 + g * 4 + j;
            if (row < N_NODES) {
#pragma unroll
                for (int nt = 0; nt < 3; ++nt) {
                    int col = nt * 16 + lrow;
                    if (col < OUTD)
                        C[(size_t)row * OUTD + col] = acc[mt][nt][j] + bb[nt];
                }
            }
        }
    }
}

// ---------------- launch ----------------

extern "C" void kernel_launch(void* const* d_in, const int* in_sizes, int n_in,
                              void* d_out, int out_size, void* d_ws, size_t ws_size,
                              hipStream_t stream) {
    const float* feat = (const float*)d_in[0];
    const int* src = (const int*)d_in[1];
    const int* dst = (const int*)d_in[2];
    const float* Ws0 = (const float*)d_in[3];
    const float* Wn0 = (const float*)d_in[4];
    const float* g0  = (const float*)d_in[5];
    const float* be0 = (const float*)d_in[6];
    const float* Ws1 = (const float*)d_in[7];
    const float* Wn1 = (const float*)d_in[8];
    const float* g1  = (const float*)d_in[9];
    const float* be1 = (const float*)d_in[10];
    const float* Ws2 = (const float*)d_in[11];
    const float* Wn2 = (const float*)d_in[12];
    const float* b2  = (const float*)d_in[13];
    float* out = (float*)d_out;

    char* ws = (char*)d_ws;
    int*   gcursor = (int*)(ws);                        // 512 B (zeroed)
    float* bn      = (float*)(ws + 512);                // 2048 B (zeroed)
    int*   row_off = (int*)(ws + 2560);                 // 400004 B
    int*   partials= (int*)(ws + 402576);               // 512 B
    uint2* pairs   = (uint2*)(ws + 403200);             // 9633792 B
    int*   csr     = (int*)(ws + 10036992);             // 3200000 B
    int*   deg     = (int*)(ws + 13236992);             // 400000 B
    unsigned short* featb = (unsigned short*)(ws + 13636992);  // 25.6MB
    unsigned short* hnb   = (unsigned short*)(ws + 39236992);  // 25.6MB
    unsigned short* h0b   = (unsigned short*)(ws + 64836992);  // 25.6MB
    unsigned short* WT0   = (unsigned short*)(ws + 90436992);  // 65536
    unsigned short* WT1   = (unsigned short*)(ws + 90502528);  // 65536
    unsigned short* WT2   = (unsigned short*)(ws + 90568064);  // 24576
    unsigned short* h1b   = featb;  // featb dead after layer-0 gemm

    hipMemsetAsync(ws, 0, 2560, stream);

    const int ABK = (N_EDGES + 4095) / 4096;     // 196
    const int AGB = N_NODES / 16;                // 6250 (exact)
    const int MB = (N_NODES + 127) / 128;        // 782
    const int NE = (N_NODES * DIM) / 4 / 256;    // 12500
    const int NB8 = (N_NODES * DIM) / 8 / 256;   // 6250

    bucketA_kernel<<<ABK, 256, 0, stream>>>(src, dst, pairs, gcursor);
    phaseB_deg_kernel<<<NBKT, 256, 0, stream>>>(pairs, gcursor, deg);
    scan_partial_kernel<<<SCAN_NB, 256, 0, stream>>>(deg, partials);
    scan_partials_kernel<<<1, 128, 0, stream>>>(partials);
    scan_final_kernel<<<SCAN_NB, 256, 0, stream>>>(deg, partials, row_off);
    phaseC_fill_kernel<<<NBKT, 256, 0, stream>>>(pairs, gcursor, row_off, csr);

    convert_bf16_kernel<<<NE, 256, 0, stream>>>(feat, featb);
    wt_build_kernel<<<256, 256, 0, stream>>>(Ws0, Wn0, Ws1, Wn1, WT0, WT1);
    wt2_build_kernel<<<48, 256, 0, stream>>>(Ws2, Wn2, WT2);

    // layer 0
    agg_bf16_kernel<<<AGB, 256, 0, stream>>>(featb, row_off, csr, hnb);
    gemm_mfma_kernel<<<MB, 256, 0, stream>>>(featb, hnb, WT0, h0b, bn + 0, bn + 128);
    bn_apply_bf16_kernel<<<NB8, 256, 0, stream>>>(h0b, bn + 0, bn + 128, g0, be0);

    // layer 1
    agg_bf16_kernel<<<AGB, 256, 0, stream>>>(h0b, row_off, csr, hnb);
    gemm_mfma_kernel<<<MB, 256, 0, stream>>>(h0b, hnb, WT1, h1b, bn + 256, bn + 384);
    bn_apply_bf16_kernel<<<NB8, 256, 0, stream>>>(h1b, bn + 256, bn + 384, g1, be1);

    // layer 2
    agg_bf16_kernel<<<AGB, 256, 0, stream>>>(h1b, row_off, csr, hnb);
    gemm_out_mfma_kernel<<<MB, 256, 0, stream>>>(h1b, hnb, WT2, b2, out);
}